// Round 1
// baseline (6406.174 us; speedup 1.0000x reference)
//
#include <hip/hip_runtime.h>

#define NN 100000
#define NE 1600000
#define NG 64

__device__ __forceinline__ bool finitef(float v) {
    return (__float_as_uint(v) & 0x7F800000u) != 0x7F800000u;
}

// Running float-max via sign-split integer atomics.
// Identity/init value: 0xFFFFFFFF (NaN bits) behaves as -inf under both ops.
__device__ __forceinline__ void atomic_fmax(float* addr, float v) {
    if (v >= 0.0f) atomicMax((int*)addr, __float_as_int(v));
    else           atomicMin((unsigned int*)addr, __float_as_uint(v));
}

// ---------------- Layer A: edge MLP 6->32->32, seg-max at dst ----------------
__global__ __launch_bounds__(256) void edge_layerA(
        const float* __restrict__ pos,
        const int* __restrict__ src, const int* __restrict__ dst,
        const float* __restrict__ W1, const float* __restrict__ b1,
        const float* __restrict__ W2, const float* __restrict__ b2,
        float* __restrict__ acc) {
    __shared__ float sW1[6 * 32];
    __shared__ float sW2[32 * 32];
    __shared__ float sb1[32], sb2[32];
    for (int i = threadIdx.x; i < 6 * 32; i += 256) sW1[i] = W1[i];
    for (int i = threadIdx.x; i < 32 * 32; i += 256) sW2[i] = W2[i];
    if (threadIdx.x < 32) { sb1[threadIdx.x] = b1[threadIdx.x]; sb2[threadIdx.x] = b2[threadIdx.x]; }
    __syncthreads();

    int e = blockIdx.x * 256 + threadIdx.x;
    if (e >= NE) return;
    int s = src[e], d = dst[e];
    float ps0 = pos[s * 3 + 0], ps1 = pos[s * 3 + 1], ps2 = pos[s * 3 + 2];
    float pd0 = pos[d * 3 + 0], pd1 = pos[d * 3 + 1], pd2 = pos[d * 3 + 2];
    float ef[6] = {ps0, ps1, ps2, ps0 - pd0, ps1 - pd1, ps2 - pd2};

    float hid[32];
    #pragma unroll
    for (int c = 0; c < 32; ++c) hid[c] = sb1[c];
    #pragma unroll
    for (int k = 0; k < 6; ++k) {
        float x = ef[k];
        #pragma unroll
        for (int c = 0; c < 32; ++c) hid[c] = fmaf(x, sW1[k * 32 + c], hid[c]);
    }
    #pragma unroll
    for (int c = 0; c < 32; ++c) hid[c] = fmaxf(hid[c], 0.0f);

    float* arow = acc + (long long)d * 32;
    for (int c = 0; c < 32; ++c) {          // c rolled (uniform), k unrolled (static reg idx)
        float o = sb2[c];
        #pragma unroll
        for (int k = 0; k < 32; ++k) o = fmaf(hid[k], sW2[k * 32 + c], o);
        atomic_fmax(&arow[c], o);
    }
}

// ---------------- Layer B: edge MLP 35->64->64, seg-max at dst ----------------
__global__ __launch_bounds__(256) void edge_layerB(
        const float* __restrict__ pos, const float* __restrict__ h,
        const int* __restrict__ src, const int* __restrict__ dst,
        const float* __restrict__ W1, const float* __restrict__ b1,
        const float* __restrict__ W2, const float* __restrict__ b2,
        float* __restrict__ acc) {
    __shared__ float sW1[35 * 64];
    __shared__ float sW2[64 * 64];
    __shared__ float sb1[64], sb2[64];
    for (int i = threadIdx.x; i < 35 * 64; i += 256) sW1[i] = W1[i];
    for (int i = threadIdx.x; i < 64 * 64; i += 256) sW2[i] = W2[i];
    if (threadIdx.x < 64) { sb1[threadIdx.x] = b1[threadIdx.x]; sb2[threadIdx.x] = b2[threadIdx.x]; }
    __syncthreads();

    int e = blockIdx.x * 256 + threadIdx.x;
    if (e >= NE) return;
    int s = src[e], d = dst[e];

    float hid[64];
    #pragma unroll
    for (int c = 0; c < 64; ++c) hid[c] = sb1[c];

    const float* hs = h + (long long)s * 32;
    for (int k = 0; k < 32; ++k) {          // k rolled (uniform); global re-load hits L1
        float x = hs[k];
        #pragma unroll
        for (int c = 0; c < 64; ++c) hid[c] = fmaf(x, sW1[k * 64 + c], hid[c]);
    }
    float dx = pos[s * 3 + 0] - pos[d * 3 + 0];
    float dy = pos[s * 3 + 1] - pos[d * 3 + 1];
    float dz = pos[s * 3 + 2] - pos[d * 3 + 2];
    #pragma unroll
    for (int c = 0; c < 64; ++c) hid[c] = fmaf(dx, sW1[32 * 64 + c], hid[c]);
    #pragma unroll
    for (int c = 0; c < 64; ++c) hid[c] = fmaf(dy, sW1[33 * 64 + c], hid[c]);
    #pragma unroll
    for (int c = 0; c < 64; ++c) hid[c] = fmaf(dz, sW1[34 * 64 + c], hid[c]);
    #pragma unroll
    for (int c = 0; c < 64; ++c) hid[c] = fmaxf(hid[c], 0.0f);

    float* arow = acc + (long long)d * 64;
    for (int c = 0; c < 64; ++c) {
        float o = sb2[c];
        #pragma unroll
        for (int k = 0; k < 64; ++k) o = fmaf(hid[k], sW2[k * 64 + c], o);
        atomic_fmax(&arow[c], o);
    }
}

// ---------------- BatchNorm stats (deterministic two-stage) ----------------
template <int C>
__global__ __launch_bounds__(256) void bn_stats(const float* __restrict__ acc,
                                                float* __restrict__ partials) {
    const long long total = (long long)NN * C;
    long long tid = (long long)blockIdx.x * 256 + threadIdx.x;
    const long long stride = (long long)gridDim.x * 256;   // multiple of C
    float s = 0.f, q = 0.f;
    for (long long i = tid; i < total; i += stride) {
        float v = acc[i];
        v = finitef(v) ? v : 0.f;
        s += v;
        q = fmaf(v, v, q);
    }
    __shared__ float ls[256], lq[256];
    ls[threadIdx.x] = s; lq[threadIdx.x] = q;
    __syncthreads();
    #pragma unroll
    for (int off = 128; off >= C; off >>= 1) {
        if (threadIdx.x < off) {
            ls[threadIdx.x] += ls[threadIdx.x + off];
            lq[threadIdx.x] += lq[threadIdx.x + off];
        }
        __syncthreads();
    }
    if (threadIdx.x < C) {
        partials[blockIdx.x * 2 * C + threadIdx.x]     = ls[threadIdx.x];
        partials[blockIdx.x * 2 * C + C + threadIdx.x] = lq[threadIdx.x];
    }
}

template <int C>
__global__ void bn_final(const float* __restrict__ partials, int nblocks,
                         const float* __restrict__ gamma, const float* __restrict__ beta,
                         float* __restrict__ ss) {
    int c = threadIdx.x;
    if (c >= C) return;
    float s = 0.f, q = 0.f;
    for (int b = 0; b < nblocks; ++b) {
        s += partials[b * 2 * C + c];
        q += partials[b * 2 * C + C + c];
    }
    float mu  = s / (float)NN;
    float var = fmaxf(q / (float)NN - mu * mu, 0.f);
    float inv = rsqrtf(var + 1e-5f);
    float sc  = gamma[c] * inv;
    ss[c]     = sc;
    ss[C + c] = fmaf(-mu, sc, beta[c]);
}

// ---------------- apply BN+ReLU for layer A output ----------------
__global__ __launch_bounds__(256) void apply_bn_relu32(const float* __restrict__ acc,
        const float* __restrict__ ss, float* __restrict__ h) {
    int i = blockIdx.x * 256 + threadIdx.x;
    int stride = gridDim.x * 256;
    for (; i < NN * 32; i += stride) {
        float v = acc[i];
        v = finitef(v) ? v : 0.f;
        int c = i & 31;
        h[i] = fmaxf(fmaf(v, ss[c], ss[32 + c]), 0.f);
    }
}

// ---------------- fused BN+ReLU + graph seg-max ----------------
__global__ __launch_bounds__(256) void pool_graph(const float* __restrict__ acc,
        const float* __restrict__ ss, const int* __restrict__ batch,
        float* __restrict__ gacc) {
    int i = blockIdx.x * 256 + threadIdx.x;
    int stride = gridDim.x * 256;
    for (; i < NN * 64; i += stride) {
        float v = acc[i];
        v = finitef(v) ? v : 0.f;
        int c = i & 63;
        v = fmaxf(fmaf(v, ss[c], ss[64 + c]), 0.f);   // >= 0
        int n = i >> 6;
        atomicMax((int*)&gacc[batch[n] * 64 + c], __float_as_int(v));
    }
}

// ---------------- final 64x64x2 GEMM ----------------
__global__ void final_gemm(const float* __restrict__ gacc, const float* __restrict__ Wc,
                           const float* __restrict__ bc, float* __restrict__ out) {
    int t = threadIdx.x;
    if (t >= NG * 2) return;
    int g = t >> 1, o = t & 1;
    float s = bc[o];
    #pragma unroll 8
    for (int k = 0; k < 64; ++k) s = fmaf(gacc[g * 64 + k], Wc[k * 2 + o], s);
    out[t] = s;
}

extern "C" void kernel_launch(void* const* d_in, const int* in_sizes, int n_in,
                              void* d_out, int out_size, void* d_ws, size_t ws_size,
                              hipStream_t stream) {
    const float* pos   = (const float*)d_in[0];
    const int*   ei    = (const int*)d_in[1];
    const int*   batch = (const int*)d_in[2];
    const float* W1a = (const float*)d_in[3];
    const float* b1a = (const float*)d_in[4];
    const float* W2a = (const float*)d_in[5];
    const float* b2a = (const float*)d_in[6];
    const float* g1  = (const float*)d_in[7];
    const float* be1 = (const float*)d_in[8];
    const float* W1b = (const float*)d_in[9];
    const float* b1b = (const float*)d_in[10];
    const float* W2b = (const float*)d_in[11];
    const float* b2b = (const float*)d_in[12];
    const float* g2  = (const float*)d_in[13];
    const float* be2 = (const float*)d_in[14];
    const float* Wc  = (const float*)d_in[15];
    const float* bc  = (const float*)d_in[16];
    const int* srcp = ei;
    const int* dstp = ei + NE;

    float* accA  = (float*)d_ws;                      // NN*32
    float* hbuf  = accA + (size_t)NN * 32;            // NN*32
    float* accB  = hbuf + (size_t)NN * 32;            // NN*64
    float* partA = accB + (size_t)NN * 64;            // 256*64
    float* partB = partA + 256 * 64;                  // 256*128
    float* ssA   = partB + 256 * 128;                 // 64
    float* ssB   = ssA + 64;                          // 128
    float* gacc  = ssB + 128;                         // 64*64

    // init: NaN-bit pattern == identity for atomic_fmax; zeros for graph pool
    hipMemsetAsync(accA, 0xFF, (size_t)NN * 32 * 4, stream);
    hipMemsetAsync(accB, 0xFF, (size_t)NN * 64 * 4, stream);
    hipMemsetAsync(gacc, 0, NG * 64 * 4, stream);

    edge_layerA<<<(NE + 255) / 256, 256, 0, stream>>>(pos, srcp, dstp, W1a, b1a, W2a, b2a, accA);
    bn_stats<32><<<256, 256, 0, stream>>>(accA, partA);
    bn_final<32><<<1, 32, 0, stream>>>(partA, 256, g1, be1, ssA);
    apply_bn_relu32<<<1024, 256, 0, stream>>>(accA, ssA, hbuf);
    edge_layerB<<<(NE + 255) / 256, 256, 0, stream>>>(pos, hbuf, srcp, dstp, W1b, b1b, W2b, b2b, accB);
    bn_stats<64><<<256, 256, 0, stream>>>(accB, partB);
    bn_final<64><<<1, 64, 0, stream>>>(partB, 256, g2, be2, ssB);
    pool_graph<<<2048, 256, 0, stream>>>(accB, ssB, batch, gacc);
    final_gemm<<<1, 128, 0, stream>>>(gacc, Wc, bc, (float*)d_out);
}

// Round 2
// 1243.723 us; speedup vs baseline: 5.1508x; 5.1508x over previous
//
#include <hip/hip_runtime.h>

#define NN 100000
#define NE 1600000
#define NG 64

__device__ __forceinline__ float neg_inf() { return __int_as_float(0xFF800000); }

// readlane: wave-uniform broadcast of lane l's value (l uniform)
__device__ __forceinline__ float rl(float v, int l) {
    return __int_as_float(__builtin_amdgcn_readlane(__float_as_int(v), l));
}

// ---------------- CSR build ----------------
__global__ __launch_bounds__(256) void hist_kernel(const int* __restrict__ dst,
                                                   int* __restrict__ cnt) {
    int e = blockIdx.x * 256 + threadIdx.x;
    if (e < NE) atomicAdd(&cnt[dst[e]], 1);
}

__global__ __launch_bounds__(512) void scan1(const int* __restrict__ cnt,
                                             int* __restrict__ off, int* __restrict__ bsum) {
    __shared__ int ls[512];
    int tid = threadIdx.x;
    int i = blockIdx.x * 512 + tid;
    int v = (i < NN) ? cnt[i] : 0;
    ls[tid] = v;
    __syncthreads();
    for (int o = 1; o < 512; o <<= 1) {
        int t = (tid >= o) ? ls[tid - o] : 0;
        __syncthreads();
        ls[tid] += t;
        __syncthreads();
    }
    if (i < NN) off[i] = ls[tid] - v;       // exclusive
    if (tid == 511) bsum[blockIdx.x] = ls[511];
}

__global__ __launch_bounds__(256) void scan2(int* __restrict__ bsum, int nb) {
    __shared__ int ls[256];
    int tid = threadIdx.x;
    int v = (tid < nb) ? bsum[tid] : 0;
    ls[tid] = v;
    __syncthreads();
    for (int o = 1; o < 256; o <<= 1) {
        int t = (tid >= o) ? ls[tid - o] : 0;
        __syncthreads();
        ls[tid] += t;
        __syncthreads();
    }
    if (tid < nb) bsum[tid] = ls[tid] - v;  // exclusive
}

__global__ __launch_bounds__(512) void scan3(int* __restrict__ off, const int* __restrict__ bsum) {
    int i = blockIdx.x * 512 + threadIdx.x;
    if (i < NN) off[i] += bsum[i >> 9];
}

__global__ __launch_bounds__(256) void scatter_kernel(const int* __restrict__ src,
        const int* __restrict__ dst, int* __restrict__ cursor, int* __restrict__ ssrc) {
    int e = blockIdx.x * 256 + threadIdx.x;
    if (e < NE) {
        int p = atomicAdd(&cursor[dst[e]], 1);
        ssrc[p] = src[e];
    }
}

// ---------------- Layer A: wave-per-node, 2 edges/iter, lane&31 = channel ----------------
__global__ __launch_bounds__(256, 4) void nodeA(
        const float* __restrict__ pos, const int* __restrict__ ssrc,
        const int* __restrict__ off, const int* __restrict__ cnt,
        const float* __restrict__ W1, const float* __restrict__ b1,
        const float* __restrict__ W2, const float* __restrict__ b2,
        float* __restrict__ accA) {
    int wid = (blockIdx.x * 256 + threadIdx.x) >> 6;
    int lane = threadIdx.x & 63;
    if (wid >= NN) return;
    int n = wid;
    int c = lane & 31, half = lane >> 5;

    float w1[6], w2[32];
    #pragma unroll
    for (int m = 0; m < 6; ++m) w1[m] = W1[m * 32 + c];
    #pragma unroll
    for (int k = 0; k < 32; ++k) w2[k] = W2[k * 32 + c];
    float bb1 = b1[c], bb2 = b2[c];
    float pd0 = pos[n * 3 + 0], pd1 = pos[n * 3 + 1], pd2 = pos[n * 3 + 2];

    int o0 = off[n], kn = cnt[n];
    float acc = neg_inf();
    int iters = (kn + 1) >> 1;
    for (int it = 0; it < iters; ++it) {
        int j = 2 * it + half;
        bool act = j < kn;
        int s = ssrc[o0 + (act ? j : 0)];
        float p0 = pos[s * 3 + 0], p1 = pos[s * 3 + 1], p2 = pos[s * 3 + 2];
        float hid = bb1;
        hid = fmaf(p0, w1[0], hid);
        hid = fmaf(p1, w1[1], hid);
        hid = fmaf(p2, w1[2], hid);
        hid = fmaf(p0 - pd0, w1[3], hid);
        hid = fmaf(p1 - pd1, w1[4], hid);
        hid = fmaf(p2 - pd2, w1[5], hid);
        hid = fmaxf(hid, 0.0f);
        float oa = bb2, ob = 0.0f;
        int base = half << 5;
        #pragma unroll
        for (int k = 0; k < 32; k += 2) {
            oa = fmaf(__shfl(hid, base + k, 64),     w2[k],     oa);
            ob = fmaf(__shfl(hid, base + k + 1, 64), w2[k + 1], ob);
        }
        if (act) acc = fmaxf(acc, oa + ob);
    }
    float other = __shfl_xor(acc, 32, 64);
    acc = fmaxf(acc, other);
    if (half == 0) accA[n * 32 + c] = (kn > 0) ? acc : 0.0f;
}

// ---------------- Layer B: wave-per-node, lane = channel (64) ----------------
__global__ __launch_bounds__(256, 2) void nodeB(
        const float* __restrict__ pos, const float* __restrict__ h,
        const int* __restrict__ ssrc, const int* __restrict__ off, const int* __restrict__ cnt,
        const float* __restrict__ W1, const float* __restrict__ b1,
        const float* __restrict__ W2, const float* __restrict__ b2,
        float* __restrict__ accB) {
    int wid = (blockIdx.x * 256 + threadIdx.x) >> 6;
    int lane = threadIdx.x & 63;
    if (wid >= NN) return;
    int n = wid;

    float w1[35], w2[64];
    #pragma unroll
    for (int m = 0; m < 35; ++m) w1[m] = W1[m * 64 + lane];
    #pragma unroll
    for (int k = 0; k < 64; ++k) w2[k] = W2[k * 64 + lane];
    float bb1 = b1[lane], bb2 = b2[lane];
    float pd0 = pos[n * 3 + 0], pd1 = pos[n * 3 + 1], pd2 = pos[n * 3 + 2];

    int o0 = off[n], kn = cnt[n];
    float acc = neg_inf();
    for (int j = 0; j < kn; ++j) {
        int s = ssrc[o0 + j];
        float hv = h[s * 32 + (lane & 31)];           // coalesced; lanes 32-63 duplicate
        float dx = pos[s * 3 + 0] - pd0;
        float dy = pos[s * 3 + 1] - pd1;
        float dz = pos[s * 3 + 2] - pd2;
        float h0 = bb1, h1 = 0.0f;
        #pragma unroll
        for (int m = 0; m < 32; m += 2) {
            h0 = fmaf(rl(hv, m),     w1[m],     h0);
            h1 = fmaf(rl(hv, m + 1), w1[m + 1], h1);
        }
        float hid = h0 + h1;
        hid = fmaf(dx, w1[32], hid);
        hid = fmaf(dy, w1[33], hid);
        hid = fmaf(dz, w1[34], hid);
        hid = fmaxf(hid, 0.0f);
        float oa = bb2, ob = 0.0f;
        #pragma unroll
        for (int k = 0; k < 64; k += 2) {
            oa = fmaf(rl(hid, k),     w2[k],     oa);
            ob = fmaf(rl(hid, k + 1), w2[k + 1], ob);
        }
        acc = fmaxf(acc, oa + ob);
    }
    accB[n * 64 + lane] = (kn > 0) ? acc : 0.0f;
}

// ---------------- BatchNorm stats (deterministic two-stage) ----------------
template <int C>
__global__ __launch_bounds__(256) void bn_stats(const float* __restrict__ acc,
                                                float* __restrict__ partials) {
    const int total = NN * C;
    int tid = blockIdx.x * 256 + threadIdx.x;
    const int stride = gridDim.x * 256;   // multiple of C
    float s = 0.f, q = 0.f;
    for (int i = tid; i < total; i += stride) {
        float v = acc[i];
        s += v;
        q = fmaf(v, v, q);
    }
    __shared__ float ls[256], lq[256];
    ls[threadIdx.x] = s; lq[threadIdx.x] = q;
    __syncthreads();
    #pragma unroll
    for (int o = 128; o >= C; o >>= 1) {
        if (threadIdx.x < o) {
            ls[threadIdx.x] += ls[threadIdx.x + o];
            lq[threadIdx.x] += lq[threadIdx.x + o];
        }
        __syncthreads();
    }
    if (threadIdx.x < C) {
        partials[blockIdx.x * 2 * C + threadIdx.x]     = ls[threadIdx.x];
        partials[blockIdx.x * 2 * C + C + threadIdx.x] = lq[threadIdx.x];
    }
}

template <int C>
__global__ void bn_final(const float* __restrict__ partials, int nblocks,
                         const float* __restrict__ gamma, const float* __restrict__ beta,
                         float* __restrict__ ss) {
    int c = threadIdx.x;
    if (c >= C) return;
    float s = 0.f, q = 0.f;
    for (int b = 0; b < nblocks; ++b) {
        s += partials[b * 2 * C + c];
        q += partials[b * 2 * C + C + c];
    }
    float mu  = s / (float)NN;
    float var = fmaxf(q / (float)NN - mu * mu, 0.f);
    float inv = rsqrtf(var + 1e-5f);
    float sc  = gamma[c] * inv;
    ss[c]     = sc;
    ss[C + c] = fmaf(-mu, sc, beta[c]);
}

__global__ __launch_bounds__(256) void apply_bn_relu32(const float* __restrict__ acc,
        const float* __restrict__ ss, float* __restrict__ h) {
    int i = blockIdx.x * 256 + threadIdx.x;
    int stride = gridDim.x * 256;
    for (; i < NN * 32; i += stride) {
        int c = i & 31;
        h[i] = fmaxf(fmaf(acc[i], ss[c], ss[32 + c]), 0.f);
    }
}

// ---------------- fused BN+ReLU + graph seg-max (run-max, batch sorted) ----------------
__global__ __launch_bounds__(256) void pool_graph(const float* __restrict__ accB,
        const float* __restrict__ ss, const int* __restrict__ batch,
        float* __restrict__ gacc) {
    int c = threadIdx.x & 63;
    int sub = threadIdx.x >> 6;          // wave index in block, 0..3
    int base = blockIdx.x * 256;
    float run = 0.f; int curg = -1;
    for (int nn = sub; nn < 256; nn += 4) {
        int n = base + nn;
        if (n >= NN) break;
        int g = batch[n];
        float v = fmaxf(fmaf(accB[n * 64 + c], ss[c], ss[64 + c]), 0.f);  // >= 0
        if (g != curg) {
            if (curg >= 0) atomicMax((int*)&gacc[curg * 64 + c], __float_as_int(run));
            curg = g; run = v;
        } else {
            run = fmaxf(run, v);
        }
    }
    if (curg >= 0) atomicMax((int*)&gacc[curg * 64 + c], __float_as_int(run));
}

// ---------------- final 64x64x2 GEMM ----------------
__global__ void final_gemm(const float* __restrict__ gacc, const float* __restrict__ Wc,
                           const float* __restrict__ bc, float* __restrict__ out) {
    int t = threadIdx.x;
    if (t >= NG * 2) return;
    int g = t >> 1, o = t & 1;
    float s = bc[o];
    #pragma unroll 8
    for (int k = 0; k < 64; ++k) s = fmaf(gacc[g * 64 + k], Wc[k * 2 + o], s);
    out[t] = s;
}

extern "C" void kernel_launch(void* const* d_in, const int* in_sizes, int n_in,
                              void* d_out, int out_size, void* d_ws, size_t ws_size,
                              hipStream_t stream) {
    const float* pos   = (const float*)d_in[0];
    const int*   ei    = (const int*)d_in[1];
    const int*   batch = (const int*)d_in[2];
    const float* W1a = (const float*)d_in[3];
    const float* b1a = (const float*)d_in[4];
    const float* W2a = (const float*)d_in[5];
    const float* b2a = (const float*)d_in[6];
    const float* g1  = (const float*)d_in[7];
    const float* be1 = (const float*)d_in[8];
    const float* W1b = (const float*)d_in[9];
    const float* b1b = (const float*)d_in[10];
    const float* W2b = (const float*)d_in[11];
    const float* b2b = (const float*)d_in[12];
    const float* g2  = (const float*)d_in[13];
    const float* be2 = (const float*)d_in[14];
    const float* Wc  = (const float*)d_in[15];
    const float* bc  = (const float*)d_in[16];
    const int* srcp = ei;
    const int* dstp = ei + NE;

    char* w = (char*)d_ws;
    int* cnt    = (int*)w;                 w += (size_t)NN * 4;
    int* off    = (int*)w;                 w += (size_t)NN * 4;
    int* cursor = (int*)w;                 w += (size_t)NN * 4;
    int* bsum   = (int*)w;                 w += 256 * 4;
    int* ssrc   = (int*)w;                 w += (size_t)NE * 4;
    float* accA = (float*)w;               w += (size_t)NN * 32 * 4;
    float* hbuf = (float*)w;               w += (size_t)NN * 32 * 4;
    float* accB = (float*)w;               w += (size_t)NN * 64 * 4;
    float* partA = (float*)w;              w += 256 * 64 * 4;
    float* partB = (float*)w;              w += 256 * 128 * 4;
    float* ssA  = (float*)w;               w += 64 * 4;
    float* ssB  = (float*)w;               w += 128 * 4;
    float* gacc = (float*)w;               w += NG * 64 * 4;

    const int NB1 = (NN + 511) / 512;      // 196 scan blocks

    hipMemsetAsync(cnt, 0, (size_t)NN * 4, stream);
    hipMemsetAsync(gacc, 0, NG * 64 * 4, stream);

    // CSR by dst
    hist_kernel<<<(NE + 255) / 256, 256, 0, stream>>>(dstp, cnt);
    scan1<<<NB1, 512, 0, stream>>>(cnt, off, bsum);
    scan2<<<1, 256, 0, stream>>>(bsum, NB1);
    scan3<<<NB1, 512, 0, stream>>>(off, bsum);
    hipMemcpyAsync(cursor, off, (size_t)NN * 4, hipMemcpyDeviceToDevice, stream);
    scatter_kernel<<<(NE + 255) / 256, 256, 0, stream>>>(srcp, dstp, cursor, ssrc);

    // Layer A + BN + ReLU
    nodeA<<<(NN + 3) / 4, 256, 0, stream>>>(pos, ssrc, off, cnt, W1a, b1a, W2a, b2a, accA);
    bn_stats<32><<<256, 256, 0, stream>>>(accA, partA);
    bn_final<32><<<1, 32, 0, stream>>>(partA, 256, g1, be1, ssA);
    apply_bn_relu32<<<1024, 256, 0, stream>>>(accA, ssA, hbuf);

    // Layer B + BN + ReLU fused into pool
    nodeB<<<(NN + 3) / 4, 256, 0, stream>>>(pos, hbuf, ssrc, off, cnt, W1b, b1b, W2b, b2b, accB);
    bn_stats<64><<<256, 256, 0, stream>>>(accB, partB);
    bn_final<64><<<1, 64, 0, stream>>>(partB, 256, g2, be2, ssB);
    pool_graph<<<(NN + 255) / 256, 256, 0, stream>>>(accB, ssB, batch, gacc);
    final_gemm<<<1, 128, 0, stream>>>(gacc, Wc, bc, (float*)d_out);
}

// Round 3
// 860.030 us; speedup vs baseline: 7.4488x; 1.4461x over previous
//
#include <hip/hip_runtime.h>

#define NN 100000
#define NE 1600000
#define NG 64

__device__ __forceinline__ bool finitef(float v) {
    return (__float_as_uint(v) & 0x7F800000u) != 0x7F800000u;
}

// Running float-max via sign-split integer atomics.
// Works with init pattern 0xFFFFFFFF (NaN bits): acts as -inf under both ops.
__device__ __forceinline__ void atomic_fmax(float* addr, float v) {
    if (v >= 0.0f) atomicMax((int*)addr, __float_as_int(v));
    else           atomicMin((unsigned int*)addr, __float_as_uint(v));
}

// ---------------- CSR build ----------------
__global__ __launch_bounds__(256) void hist_kernel(const int* __restrict__ dst,
                                                   int* __restrict__ cnt) {
    int e = blockIdx.x * 256 + threadIdx.x;
    if (e < NE) atomicAdd(&cnt[dst[e]], 1);
}

__global__ __launch_bounds__(512) void scan1(const int* __restrict__ cnt,
                                             int* __restrict__ off, int* __restrict__ bsum) {
    __shared__ int ls[512];
    int tid = threadIdx.x;
    int i = blockIdx.x * 512 + tid;
    int v = (i < NN) ? cnt[i] : 0;
    ls[tid] = v;
    __syncthreads();
    for (int o = 1; o < 512; o <<= 1) {
        int t = (tid >= o) ? ls[tid - o] : 0;
        __syncthreads();
        ls[tid] += t;
        __syncthreads();
    }
    if (i < NN) off[i] = ls[tid] - v;       // exclusive
    if (tid == 511) bsum[blockIdx.x] = ls[511];
}

__global__ __launch_bounds__(256) void scan2(int* __restrict__ bsum, int nb) {
    __shared__ int ls[256];
    int tid = threadIdx.x;
    int v = (tid < nb) ? bsum[tid] : 0;
    ls[tid] = v;
    __syncthreads();
    for (int o = 1; o < 256; o <<= 1) {
        int t = (tid >= o) ? ls[tid - o] : 0;
        __syncthreads();
        ls[tid] += t;
        __syncthreads();
    }
    if (tid < nb) bsum[tid] = ls[tid] - v;  // exclusive
}

__global__ __launch_bounds__(512) void scan3(int* __restrict__ off, const int* __restrict__ bsum) {
    int i = blockIdx.x * 512 + threadIdx.x;
    if (i < NN) off[i] += bsum[i >> 9];
    if (blockIdx.x == 0 && threadIdx.x == 0) off[NN] = NE;
}

// scatter: cnt used as count-down cursor (destroyed; counts recoverable via off[n+1]-off[n])
__global__ __launch_bounds__(256) void scatter_kernel(const int* __restrict__ src,
        const int* __restrict__ dst, int* __restrict__ cnt, const int* __restrict__ off,
        int2* __restrict__ sedge) {
    int e = blockIdx.x * 256 + threadIdx.x;
    if (e < NE) {
        int d = dst[e];
        int q = atomicSub(&cnt[d], 1);
        sedge[off[d] + q - 1] = make_int2(src[e], d);
    }
}

// ---------------- per-node precompute: u = x @ W1[:K] + b1 ----------------
__global__ __launch_bounds__(256) void uA_kernel(const float* __restrict__ pos,
        const float* __restrict__ W1, const float* __restrict__ b1,
        float* __restrict__ uA) {
    __shared__ float sW[3 * 32];
    __shared__ float sb[32];
    if (threadIdx.x < 96) sW[threadIdx.x] = W1[threadIdx.x];
    if (threadIdx.x < 32) sb[threadIdx.x] = b1[threadIdx.x];
    __syncthreads();
    int n = blockIdx.x * 256 + threadIdx.x;
    if (n >= NN) return;
    float p0 = pos[n * 3 + 0], p1 = pos[n * 3 + 1], p2 = pos[n * 3 + 2];
    float a[32];
    #pragma unroll
    for (int c = 0; c < 32; ++c)
        a[c] = fmaf(p2, sW[64 + c], fmaf(p1, sW[32 + c], fmaf(p0, sW[c], sb[c])));
    float4* o = (float4*)(uA + (size_t)n * 32);
    #pragma unroll
    for (int q = 0; q < 8; ++q)
        o[q] = make_float4(a[4 * q], a[4 * q + 1], a[4 * q + 2], a[4 * q + 3]);
}

__global__ __launch_bounds__(256, 3) void uB_kernel(const float* __restrict__ h,
        const float* __restrict__ W1, const float* __restrict__ b1,
        float* __restrict__ uB) {
    __shared__ float sW[32 * 64];
    __shared__ float sb[64];
    for (int i = threadIdx.x; i < 32 * 64; i += 256) sW[i] = W1[i];
    if (threadIdx.x < 64) sb[threadIdx.x] = b1[threadIdx.x];
    __syncthreads();
    int n = blockIdx.x * 256 + threadIdx.x;
    if (n >= NN) return;
    float hr[32];
    const float4* h4 = (const float4*)(h + (size_t)n * 32);
    #pragma unroll
    for (int q = 0; q < 8; ++q) {
        float4 v = h4[q];
        hr[4 * q] = v.x; hr[4 * q + 1] = v.y; hr[4 * q + 2] = v.z; hr[4 * q + 3] = v.w;
    }
    float a[64];
    #pragma unroll
    for (int c = 0; c < 64; ++c) a[c] = sb[c];
    #pragma unroll
    for (int k = 0; k < 32; ++k) {
        float x = hr[k];
        #pragma unroll
        for (int c = 0; c < 64; ++c) a[c] = fmaf(x, sW[k * 64 + c], a[c]);
    }
    float4* o = (float4*)(uB + (size_t)n * 64);
    #pragma unroll
    for (int q = 0; q < 16; ++q)
        o[q] = make_float4(a[4 * q], a[4 * q + 1], a[4 * q + 2], a[4 * q + 3]);
}

// ---------------- Layer A edges ----------------
__global__ __launch_bounds__(256, 4) void edgeA(
        const float* __restrict__ pos, const float* __restrict__ uA,
        const int2* __restrict__ sedge, const int* __restrict__ off,
        const float* __restrict__ W1, const float* __restrict__ W2,
        const float* __restrict__ b2, float* __restrict__ accA) {
    __shared__ float sW2[32 * 32];
    __shared__ float sW1t[3 * 32];
    __shared__ float sb2[32];
    __shared__ int   snode[256];
    __shared__ float sm[256 * 17];
    __shared__ int4  slist[256];
    __shared__ int   nseg;

    const int tid = threadIdx.x;
    const int b0  = blockIdx.x * 256;
    for (int i = tid; i < 32 * 32; i += 256) sW2[i] = W2[i];
    if (tid < 96) sW1t[tid] = W1[3 * 32 + tid];
    if (tid < 32) sb2[tid] = b2[tid];
    if (tid == 0) nseg = 0;
    int2 ed = sedge[b0 + tid];
    int s = ed.x, d = ed.y;
    snode[tid] = d;
    __syncthreads();

    bool flag = (tid == 0) || (snode[tid - 1] != d);
    if (flag) {
        int o0 = off[d], o1 = off[d + 1];
        int lo = max(o0 - b0, 0);
        int hi = min(o1 - b0, 256);
        int interior = (o0 >= b0) && (o1 <= b0 + 256);
        int idx = atomicAdd(&nseg, 1);
        slist[idx] = make_int4(d, lo, hi, interior);
    }

    float dx = pos[s * 3 + 0] - pos[d * 3 + 0];
    float dy = pos[s * 3 + 1] - pos[d * 3 + 1];
    float dz = pos[s * 3 + 2] - pos[d * 3 + 2];
    float hid[32];
    const float4* u4 = (const float4*)(uA + (size_t)s * 32);
    #pragma unroll
    for (int q = 0; q < 8; ++q) {
        float4 v = u4[q];
        hid[4 * q] = v.x; hid[4 * q + 1] = v.y; hid[4 * q + 2] = v.z; hid[4 * q + 3] = v.w;
    }
    #pragma unroll
    for (int c = 0; c < 32; ++c)
        hid[c] = fmaxf(fmaf(dz, sW1t[64 + c], fmaf(dy, sW1t[32 + c], fmaf(dx, sW1t[c], hid[c]))), 0.f);

    for (int cc = 0; cc < 2; ++cc) {
        float m[16];
        #pragma unroll
        for (int j = 0; j < 16; ++j) m[j] = sb2[cc * 16 + j];
        #pragma unroll
        for (int k = 0; k < 32; ++k) {
            float hk = hid[k];
            #pragma unroll
            for (int j = 0; j < 16; ++j)
                m[j] = fmaf(hk, sW2[k * 32 + cc * 16 + j], m[j]);
        }
        __syncthreads();   // prior chunk's reads done; slist/nseg published (cc=0)
        #pragma unroll
        for (int j = 0; j < 16; ++j) sm[tid * 17 + j] = m[j];
        __syncthreads();
        int ns = nseg;
        int j = tid & 15;
        for (int si = tid >> 4; si < ns; si += 16) {
            int4 sg = slist[si];
            float v = sm[sg.y * 17 + j];
            for (int p = sg.y + 1; p < sg.z; ++p) v = fmaxf(v, sm[p * 17 + j]);
            float* addr = &accA[(size_t)sg.x * 32 + cc * 16 + j];
            if (sg.w) *addr = v;
            else atomic_fmax(addr, v);
        }
    }
}

// ---------------- Layer B edges ----------------
__global__ __launch_bounds__(256, 3) void edgeB(
        const float* __restrict__ pos, const float* __restrict__ uB,
        const int2* __restrict__ sedge, const int* __restrict__ off,
        const float* __restrict__ W1, const float* __restrict__ W2,
        const float* __restrict__ b2, float* __restrict__ accB) {
    __shared__ float sW2[64 * 64];
    __shared__ float sW1t[3 * 64];
    __shared__ float sb2[64];
    __shared__ int   snode[256];
    __shared__ float sm[256 * 17];
    __shared__ int4  slist[256];
    __shared__ int   nseg;

    const int tid = threadIdx.x;
    const int b0  = blockIdx.x * 256;
    for (int i = tid; i < 64 * 64; i += 256) sW2[i] = W2[i];
    if (tid < 192) sW1t[tid] = W1[32 * 64 + tid];
    if (tid < 64) sb2[tid] = b2[tid];
    if (tid == 0) nseg = 0;
    int2 ed = sedge[b0 + tid];
    int s = ed.x, d = ed.y;
    snode[tid] = d;
    __syncthreads();

    bool flag = (tid == 0) || (snode[tid - 1] != d);
    if (flag) {
        int o0 = off[d], o1 = off[d + 1];
        int lo = max(o0 - b0, 0);
        int hi = min(o1 - b0, 256);
        int interior = (o0 >= b0) && (o1 <= b0 + 256);
        int idx = atomicAdd(&nseg, 1);
        slist[idx] = make_int4(d, lo, hi, interior);
    }

    float dx = pos[s * 3 + 0] - pos[d * 3 + 0];
    float dy = pos[s * 3 + 1] - pos[d * 3 + 1];
    float dz = pos[s * 3 + 2] - pos[d * 3 + 2];
    float hid[64];
    const float4* u4 = (const float4*)(uB + (size_t)s * 64);
    #pragma unroll
    for (int q = 0; q < 16; ++q) {
        float4 v = u4[q];
        hid[4 * q] = v.x; hid[4 * q + 1] = v.y; hid[4 * q + 2] = v.z; hid[4 * q + 3] = v.w;
    }
    #pragma unroll
    for (int c = 0; c < 64; ++c)
        hid[c] = fmaxf(fmaf(dz, sW1t[128 + c], fmaf(dy, sW1t[64 + c], fmaf(dx, sW1t[c], hid[c]))), 0.f);

    for (int cc = 0; cc < 4; ++cc) {
        float m[16];
        #pragma unroll
        for (int j = 0; j < 16; ++j) m[j] = sb2[cc * 16 + j];
        #pragma unroll
        for (int k = 0; k < 64; ++k) {
            float hk = hid[k];
            #pragma unroll
            for (int j = 0; j < 16; ++j)
                m[j] = fmaf(hk, sW2[k * 64 + cc * 16 + j], m[j]);
        }
        __syncthreads();
        #pragma unroll
        for (int j = 0; j < 16; ++j) sm[tid * 17 + j] = m[j];
        __syncthreads();
        int ns = nseg;
        int j = tid & 15;
        for (int si = tid >> 4; si < ns; si += 16) {
            int4 sg = slist[si];
            float v = sm[sg.y * 17 + j];
            for (int p = sg.y + 1; p < sg.z; ++p) v = fmaxf(v, sm[p * 17 + j]);
            float* addr = &accB[(size_t)sg.x * 64 + cc * 16 + j];
            if (sg.w) *addr = v;
            else atomic_fmax(addr, v);
        }
    }
}

// ---------------- BatchNorm stats (deterministic two-stage) ----------------
template <int C>
__global__ __launch_bounds__(256) void bn_stats(const float* __restrict__ acc,
                                                float* __restrict__ partials) {
    const int total = NN * C;
    int tid = blockIdx.x * 256 + threadIdx.x;
    const int stride = gridDim.x * 256;
    float s = 0.f, q = 0.f;
    for (int i = tid; i < total; i += stride) {
        float v = acc[i];
        v = finitef(v) ? v : 0.f;
        s += v;
        q = fmaf(v, v, q);
    }
    __shared__ float ls[256], lq[256];
    ls[threadIdx.x] = s; lq[threadIdx.x] = q;
    __syncthreads();
    #pragma unroll
    for (int o = 128; o >= C; o >>= 1) {
        if (threadIdx.x < o) {
            ls[threadIdx.x] += ls[threadIdx.x + o];
            lq[threadIdx.x] += lq[threadIdx.x + o];
        }
        __syncthreads();
    }
    if (threadIdx.x < C) {
        partials[blockIdx.x * 2 * C + threadIdx.x]     = ls[threadIdx.x];
        partials[blockIdx.x * 2 * C + C + threadIdx.x] = lq[threadIdx.x];
    }
}

template <int C>
__global__ void bn_final(const float* __restrict__ partials, int nblocks,
                         const float* __restrict__ gamma, const float* __restrict__ beta,
                         float* __restrict__ ss) {
    int c = threadIdx.x;
    if (c >= C) return;
    float s = 0.f, q = 0.f;
    for (int b = 0; b < nblocks; ++b) {
        s += partials[b * 2 * C + c];
        q += partials[b * 2 * C + C + c];
    }
    float mu  = s / (float)NN;
    float var = fmaxf(q / (float)NN - mu * mu, 0.f);
    float inv = rsqrtf(var + 1e-5f);
    float sc  = gamma[c] * inv;
    ss[c]     = sc;
    ss[C + c] = fmaf(-mu, sc, beta[c]);
}

__global__ __launch_bounds__(256) void apply_bn_relu32(const float* __restrict__ acc,
        const float* __restrict__ ss, float* __restrict__ h) {
    int i = blockIdx.x * 256 + threadIdx.x;
    int stride = gridDim.x * 256;
    for (; i < NN * 32; i += stride) {
        float v = acc[i];
        v = finitef(v) ? v : 0.f;
        int c = i & 31;
        h[i] = fmaxf(fmaf(v, ss[c], ss[32 + c]), 0.f);
    }
}

// ---------------- fused BN+ReLU + graph seg-max ----------------
__global__ __launch_bounds__(256) void pool_graph(const float* __restrict__ accB,
        const float* __restrict__ ss, const int* __restrict__ batch,
        float* __restrict__ gacc) {
    int c = threadIdx.x & 63;
    int sub = threadIdx.x >> 6;
    int base = blockIdx.x * 256;
    float run = 0.f; int curg = -1;
    for (int nn = sub; nn < 256; nn += 4) {
        int n = base + nn;
        if (n >= NN) break;
        int g = batch[n];
        float v = accB[n * 64 + c];
        v = finitef(v) ? v : 0.f;
        v = fmaxf(fmaf(v, ss[c], ss[64 + c]), 0.f);
        if (g != curg) {
            if (curg >= 0) atomicMax((int*)&gacc[curg * 64 + c], __float_as_int(run));
            curg = g; run = v;
        } else {
            run = fmaxf(run, v);
        }
    }
    if (curg >= 0) atomicMax((int*)&gacc[curg * 64 + c], __float_as_int(run));
}

// ---------------- final 64x64x2 GEMM ----------------
__global__ void final_gemm(const float* __restrict__ gacc, const float* __restrict__ Wc,
                           const float* __restrict__ bc, float* __restrict__ out) {
    int t = threadIdx.x;
    if (t >= NG * 2) return;
    int g = t >> 1, o = t & 1;
    float s = bc[o];
    #pragma unroll 8
    for (int k = 0; k < 64; ++k) s = fmaf(gacc[g * 64 + k], Wc[k * 2 + o], s);
    out[t] = s;
}

extern "C" void kernel_launch(void* const* d_in, const int* in_sizes, int n_in,
                              void* d_out, int out_size, void* d_ws, size_t ws_size,
                              hipStream_t stream) {
    const float* pos   = (const float*)d_in[0];
    const int*   ei    = (const int*)d_in[1];
    const int*   batch = (const int*)d_in[2];
    const float* W1a = (const float*)d_in[3];
    const float* b1a = (const float*)d_in[4];
    const float* W2a = (const float*)d_in[5];
    const float* b2a = (const float*)d_in[6];
    const float* g1  = (const float*)d_in[7];
    const float* be1 = (const float*)d_in[8];
    const float* W1b = (const float*)d_in[9];
    const float* b1b = (const float*)d_in[10];
    const float* W2b = (const float*)d_in[11];
    const float* b2b = (const float*)d_in[12];
    const float* g2  = (const float*)d_in[13];
    const float* be2 = (const float*)d_in[14];
    const float* Wc  = (const float*)d_in[15];
    const float* bc  = (const float*)d_in[16];
    const int* srcp = ei;
    const int* dstp = ei + NE;

    char* w = (char*)d_ws;
    int*   cnt   = (int*)w;     w += (size_t)NN * 4;
    int*   off   = (int*)w;     w += (size_t)(NN + 2) * 4;   // NN+1 used, pad to 8B
    int*   bsum  = (int*)w;     w += 256 * 4;
    int2*  sedge = (int2*)w;    w += (size_t)NE * 8;
    float* u     = (float*)w;   w += (size_t)NN * 64 * 4;    // uA[NN][32] then uB[NN][64]
    float* hbuf  = (float*)w;   w += (size_t)NN * 32 * 4;
    float* X     = (float*)w;   w += (size_t)NN * 64 * 4;    // accA then accB
    float* partA = (float*)w;   w += 256 * 64 * 4;
    float* partB = (float*)w;   w += 256 * 128 * 4;
    float* ssA   = (float*)w;   w += 64 * 4;
    float* ssB   = (float*)w;   w += 128 * 4;
    float* gacc  = (float*)w;   w += NG * 64 * 4;

    const int NB1 = (NN + 511) / 512;
    const int EB  = NE / 256;   // 6250, exact

    hipMemsetAsync(cnt, 0, (size_t)NN * 4, stream);
    hipMemsetAsync(gacc, 0, NG * 64 * 4, stream);
    hipMemsetAsync(X, 0xFF, (size_t)NN * 32 * 4, stream);   // accA NaN-init

    // CSR by dst
    hist_kernel<<<(NE + 255) / 256, 256, 0, stream>>>(dstp, cnt);
    scan1<<<NB1, 512, 0, stream>>>(cnt, off, bsum);
    scan2<<<1, 256, 0, stream>>>(bsum, NB1);
    scan3<<<NB1, 512, 0, stream>>>(off, bsum);
    scatter_kernel<<<(NE + 255) / 256, 256, 0, stream>>>(srcp, dstp, cnt, off, sedge);

    // Layer A
    uA_kernel<<<(NN + 255) / 256, 256, 0, stream>>>(pos, W1a, b1a, u);
    edgeA<<<EB, 256, 0, stream>>>(pos, u, sedge, off, W1a, W2a, b2a, X);
    bn_stats<32><<<256, 256, 0, stream>>>(X, partA);
    bn_final<32><<<1, 32, 0, stream>>>(partA, 256, g1, be1, ssA);
    apply_bn_relu32<<<1024, 256, 0, stream>>>(X, ssA, hbuf);

    // Layer B
    hipMemsetAsync(X, 0xFF, (size_t)NN * 64 * 4, stream);   // accB NaN-init
    uB_kernel<<<(NN + 255) / 256, 256, 0, stream>>>(hbuf, W1b, b1b, u);
    edgeB<<<EB, 256, 0, stream>>>(pos, u, sedge, off, W1b, W2b, b2b, X);
    bn_stats<64><<<256, 256, 0, stream>>>(X, partB);
    bn_final<64><<<1, 64, 0, stream>>>(partB, 256, g2, be2, ssB);
    pool_graph<<<(NN + 255) / 256, 256, 0, stream>>>(X, ssB, batch, gacc);
    final_gemm<<<1, 128, 0, stream>>>(gacc, Wc, bc, (float*)d_out);
}

// Round 4
// 627.888 us; speedup vs baseline: 10.2027x; 1.3697x over previous
//
#include <hip/hip_runtime.h>

#define NN 100000
#define NE 1600000
#define NG 64

typedef __attribute__((ext_vector_type(8))) short bf16x8;
typedef __attribute__((ext_vector_type(4))) float f32x4;

__device__ __forceinline__ bool finitef(float v) {
    return (__float_as_uint(v) & 0x7F800000u) != 0x7F800000u;
}

__device__ __forceinline__ unsigned short f2bf(float f) {   // RNE
    unsigned int u = __float_as_uint(f);
    u += 0x7fffu + ((u >> 16) & 1u);
    return (unsigned short)(u >> 16);
}
__device__ __forceinline__ float bf2f(unsigned short s) {
    return __uint_as_float(((unsigned int)s) << 16);
}
__device__ __forceinline__ unsigned int pk2(float lo, float hi) {
    return (unsigned int)f2bf(lo) | ((unsigned int)f2bf(hi) << 16);
}

// Running float-max via sign-split integer atomics (init pattern 0xFFFFFFFF = -inf-like).
__device__ __forceinline__ void atomic_fmax(float* addr, float v) {
    if (v >= 0.0f) atomicMax((int*)addr, __float_as_int(v));
    else           atomicMin((unsigned int*)addr, __float_as_uint(v));
}

// ---------------- CSR build ----------------
__global__ __launch_bounds__(256) void hist_kernel(const int* __restrict__ dst,
                                                   int* __restrict__ cnt) {
    int e = blockIdx.x * 256 + threadIdx.x;
    if (e < NE) atomicAdd(&cnt[dst[e]], 1);
}

__global__ __launch_bounds__(512) void scan1(const int* __restrict__ cnt,
                                             int* __restrict__ off, int* __restrict__ bsum) {
    __shared__ int ls[512];
    int tid = threadIdx.x;
    int i = blockIdx.x * 512 + tid;
    int v = (i < NN) ? cnt[i] : 0;
    ls[tid] = v;
    __syncthreads();
    for (int o = 1; o < 512; o <<= 1) {
        int t = (tid >= o) ? ls[tid - o] : 0;
        __syncthreads();
        ls[tid] += t;
        __syncthreads();
    }
    if (i < NN) off[i] = ls[tid] - v;
    if (tid == 511) bsum[blockIdx.x] = ls[511];
}

__global__ __launch_bounds__(256) void scan2(int* __restrict__ bsum, int nb) {
    __shared__ int ls[256];
    int tid = threadIdx.x;
    int v = (tid < nb) ? bsum[tid] : 0;
    ls[tid] = v;
    __syncthreads();
    for (int o = 1; o < 256; o <<= 1) {
        int t = (tid >= o) ? ls[tid - o] : 0;
        __syncthreads();
        ls[tid] += t;
        __syncthreads();
    }
    if (tid < nb) bsum[tid] = ls[tid] - v;
}

__global__ __launch_bounds__(512) void scan3(int* __restrict__ off, const int* __restrict__ bsum) {
    int i = blockIdx.x * 512 + threadIdx.x;
    if (i < NN) off[i] += bsum[i >> 9];
    if (blockIdx.x == 0 && threadIdx.x == 0) off[NN] = NE;
}

__global__ __launch_bounds__(256) void scatter_kernel(const int* __restrict__ src,
        const int* __restrict__ dst, int* __restrict__ cnt, const int* __restrict__ off,
        int2* __restrict__ sedge) {
    int e = blockIdx.x * 256 + threadIdx.x;
    if (e < NE) {
        int d = dst[e];
        int q = atomicSub(&cnt[d], 1);
        sedge[off[d] + q - 1] = make_int2(src[e], d);
    }
}

// ---------------- per-node precompute: u = x @ W1[:K] + b1 (bf16 output) ----------------
__global__ __launch_bounds__(256) void uA_kernel(const float* __restrict__ pos,
        const float* __restrict__ W1, const float* __restrict__ b1,
        unsigned short* __restrict__ uA) {
    __shared__ float sW[3 * 32];
    __shared__ float sb[32];
    if (threadIdx.x < 96) sW[threadIdx.x] = W1[threadIdx.x];
    if (threadIdx.x < 32) sb[threadIdx.x] = b1[threadIdx.x];
    __syncthreads();
    int n = blockIdx.x * 256 + threadIdx.x;
    if (n >= NN) return;
    float p0 = pos[n * 3 + 0], p1 = pos[n * 3 + 1], p2 = pos[n * 3 + 2];
    float a[32];
    #pragma unroll
    for (int c = 0; c < 32; ++c)
        a[c] = fmaf(p2, sW[64 + c], fmaf(p1, sW[32 + c], fmaf(p0, sW[c], sb[c])));
    uint4* o = (uint4*)(uA + (size_t)n * 32);
    #pragma unroll
    for (int q = 0; q < 4; ++q)
        o[q] = make_uint4(pk2(a[8*q], a[8*q+1]), pk2(a[8*q+2], a[8*q+3]),
                          pk2(a[8*q+4], a[8*q+5]), pk2(a[8*q+6], a[8*q+7]));
}

__global__ __launch_bounds__(256, 3) void uB_kernel(const float* __restrict__ h,
        const float* __restrict__ W1, const float* __restrict__ b1,
        unsigned short* __restrict__ uB) {
    __shared__ float sW[32 * 64];
    __shared__ float sb[64];
    for (int i = threadIdx.x; i < 32 * 64; i += 256) sW[i] = W1[i];
    if (threadIdx.x < 64) sb[threadIdx.x] = b1[threadIdx.x];
    __syncthreads();
    int n = blockIdx.x * 256 + threadIdx.x;
    if (n >= NN) return;
    float hr[32];
    const float4* h4 = (const float4*)(h + (size_t)n * 32);
    #pragma unroll
    for (int q = 0; q < 8; ++q) {
        float4 v = h4[q];
        hr[4*q] = v.x; hr[4*q+1] = v.y; hr[4*q+2] = v.z; hr[4*q+3] = v.w;
    }
    float a[64];
    #pragma unroll
    for (int c = 0; c < 64; ++c) a[c] = sb[c];
    #pragma unroll
    for (int k = 0; k < 32; ++k) {
        float x = hr[k];
        #pragma unroll
        for (int c = 0; c < 64; ++c) a[c] = fmaf(x, sW[k * 64 + c], a[c]);
    }
    uint4* o = (uint4*)(uB + (size_t)n * 64);
    #pragma unroll
    for (int q = 0; q < 8; ++q)
        o[q] = make_uint4(pk2(a[8*q], a[8*q+1]), pk2(a[8*q+2], a[8*q+3]),
                          pk2(a[8*q+4], a[8*q+5]), pk2(a[8*q+6], a[8*q+7]));
}

// ---------------- Layer A edges: MFMA 16x16x32, K=32, 32 out channels ----------------
__global__ __launch_bounds__(256, 3) void edgeA(
        const float* __restrict__ pos, const unsigned short* __restrict__ uA,
        const int2* __restrict__ sedge, const int* __restrict__ off,
        const float* __restrict__ W1, const float* __restrict__ W2,
        const float* __restrict__ b2, float* __restrict__ accA) {
    __shared__ short w2f[2 * 64 * 8];        // [t][lane][j] B-fragments, bf16
    __shared__ int   snode[256];
    __shared__ float sm[256 * 17];
    __shared__ int4  slist[256];
    __shared__ int   nseg;

    const int tid = threadIdx.x;
    const int b0  = blockIdx.x * 256;
    const int lane = tid & 63, wv = tid >> 6;
    const int kg = (lane >> 4);              // k-group 0..3

    // B-fragment fill: element (t,lane,j) = W2[(lane>>4)*8+j][ (lane&15)+16t ]
    #pragma unroll
    for (int ii = 0; ii < 4; ++ii) {
        int i = tid + ii * 256;
        int j = i & 7, ln = (i >> 3) & 63, t = (i >> 9) & 1;
        int k = ((ln >> 4) & 3) * 8 + j, col = (ln & 15) + 16 * t;
        w2f[i] = (short)f2bf(W2[k * 32 + col]);
    }
    if (tid == 0) nseg = 0;
    int2 ed0 = sedge[b0 + tid];
    snode[tid] = ed0.y;
    __syncthreads();

    bool flag = (tid == 0) || (snode[tid - 1] != ed0.y);
    if (flag) {
        int d = ed0.y;
        int o0 = off[d], o1 = off[d + 1];
        int lo = max(o0 - b0, 0);
        int hi = min(o1 - b0, 256);
        int interior = (o0 >= b0) && (o1 <= b0 + 256);
        int idx = atomicAdd(&nseg, 1);
        slist[idx] = make_int4(d, lo, hi, interior);
    }

    // W1 dpos rows into registers (lane-sliced)
    float w1t[3][8];
    #pragma unroll
    for (int r = 0; r < 3; ++r) {
        float4 q0 = *(const float4*)&W1[(3 + r) * 32 + kg * 8];
        float4 q1 = *(const float4*)&W1[(3 + r) * 32 + kg * 8 + 4];
        w1t[r][0]=q0.x; w1t[r][1]=q0.y; w1t[r][2]=q0.z; w1t[r][3]=q0.w;
        w1t[r][4]=q1.x; w1t[r][5]=q1.y; w1t[r][6]=q1.z; w1t[r][7]=q1.w;
    }
    float b2v[2];
    #pragma unroll
    for (int t = 0; t < 2; ++t) b2v[t] = b2[(lane & 15) + 16 * t];

    // A fragments: 4 groups of 16 edges; lane holds edge (lane&15), k-slice kg*8..+7
    bf16x8 af[4];
    #pragma unroll
    for (int g = 0; g < 4; ++g) {
        int E = wv * 64 + g * 16 + (lane & 15);
        int2 ed = sedge[b0 + E];
        int s = ed.x, d = ed.y;
        float dx = pos[s*3+0] - pos[d*3+0];
        float dy = pos[s*3+1] - pos[d*3+1];
        float dz = pos[s*3+2] - pos[d*3+2];
        uint4 q = *(const uint4*)&uA[(size_t)s * 32 + kg * 8];
        unsigned int qq[4] = {q.x, q.y, q.z, q.w};
        #pragma unroll
        for (int p = 0; p < 4; ++p) {
            #pragma unroll
            for (int hl = 0; hl < 2; ++hl) {
                int j = 2 * p + hl;
                float uv = bf2f(hl ? (unsigned short)(qq[p] >> 16) : (unsigned short)(qq[p] & 0xffff));
                float hv = uv + dx * w1t[0][j] + dy * w1t[1][j] + dz * w1t[2][j];
                af[g][j] = (short)f2bf(fmaxf(hv, 0.f));
            }
        }
    }

    #pragma unroll
    for (int t = 0; t < 2; ++t) {
        bf16x8 bf = *(const bf16x8*)&w2f[(t * 64 + lane) * 8];
        f32x4 acc[4];
        #pragma unroll
        for (int g = 0; g < 4; ++g) {
            f32x4 c = {b2v[t], b2v[t], b2v[t], b2v[t]};
            acc[g] = __builtin_amdgcn_mfma_f32_16x16x32_bf16(af[g], bf, c, 0, 0, 0);
        }
        __syncthreads();
        #pragma unroll
        for (int g = 0; g < 4; ++g) {
            int eb = wv * 64 + g * 16 + (lane >> 4) * 4;
            #pragma unroll
            for (int r = 0; r < 4; ++r)
                sm[(eb + r) * 17 + (lane & 15)] = acc[g][r];
        }
        __syncthreads();
        int ns = nseg;
        int j = tid & 15;
        for (int si = tid >> 4; si < ns; si += 16) {
            int4 sg = slist[si];
            float v = sm[sg.y * 17 + j];
            for (int p = sg.y + 1; p < sg.z; ++p) v = fmaxf(v, sm[p * 17 + j]);
            float* addr = &accA[(size_t)sg.x * 32 + t * 16 + j];
            if (sg.w) *addr = v;
            else atomic_fmax(addr, v);
        }
    }
}

// ---------------- Layer B edges: MFMA 16x16x32, K=64, 64 out channels ----------------
__global__ __launch_bounds__(256, 3) void edgeB(
        const float* __restrict__ pos, const unsigned short* __restrict__ uB,
        const int2* __restrict__ sedge, const int* __restrict__ off,
        const float* __restrict__ W1, const float* __restrict__ W2,
        const float* __restrict__ b2, float* __restrict__ accB) {
    __shared__ short w2f[2 * 4 * 64 * 8];    // [ks][t][lane][j] B-fragments, bf16
    __shared__ int   snode[256];
    __shared__ float sm[256 * 17];
    __shared__ int4  slist[256];
    __shared__ int   nseg;

    const int tid = threadIdx.x;
    const int b0  = blockIdx.x * 256;
    const int lane = tid & 63, wv = tid >> 6;
    const int kg = (lane >> 4);

    #pragma unroll
    for (int ii = 0; ii < 16; ++ii) {
        int i = tid + ii * 256;
        int j = i & 7, ln = (i >> 3) & 63, t = (i >> 9) & 3, ks = (i >> 11) & 1;
        int k = ks * 32 + ((ln >> 4) & 3) * 8 + j, col = (ln & 15) + 16 * t;
        w2f[i] = (short)f2bf(W2[k * 64 + col]);
    }
    if (tid == 0) nseg = 0;
    int2 ed0 = sedge[b0 + tid];
    snode[tid] = ed0.y;
    __syncthreads();

    bool flag = (tid == 0) || (snode[tid - 1] != ed0.y);
    if (flag) {
        int d = ed0.y;
        int o0 = off[d], o1 = off[d + 1];
        int lo = max(o0 - b0, 0);
        int hi = min(o1 - b0, 256);
        int interior = (o0 >= b0) && (o1 <= b0 + 256);
        int idx = atomicAdd(&nseg, 1);
        slist[idx] = make_int4(d, lo, hi, interior);
    }

    float w1t[3][2][8];
    #pragma unroll
    for (int r = 0; r < 3; ++r)
        #pragma unroll
        for (int ks = 0; ks < 2; ++ks) {
            float4 q0 = *(const float4*)&W1[(32 + r) * 64 + ks * 32 + kg * 8];
            float4 q1 = *(const float4*)&W1[(32 + r) * 64 + ks * 32 + kg * 8 + 4];
            w1t[r][ks][0]=q0.x; w1t[r][ks][1]=q0.y; w1t[r][ks][2]=q0.z; w1t[r][ks][3]=q0.w;
            w1t[r][ks][4]=q1.x; w1t[r][ks][5]=q1.y; w1t[r][ks][6]=q1.z; w1t[r][ks][7]=q1.w;
        }
    float b2v[4];
    #pragma unroll
    for (int t = 0; t < 4; ++t) b2v[t] = b2[(lane & 15) + 16 * t];

    bf16x8 af[4][2];
    #pragma unroll
    for (int g = 0; g < 4; ++g) {
        int E = wv * 64 + g * 16 + (lane & 15);
        int2 ed = sedge[b0 + E];
        int s = ed.x, d = ed.y;
        float dx = pos[s*3+0] - pos[d*3+0];
        float dy = pos[s*3+1] - pos[d*3+1];
        float dz = pos[s*3+2] - pos[d*3+2];
        #pragma unroll
        for (int ks = 0; ks < 2; ++ks) {
            uint4 q = *(const uint4*)&uB[(size_t)s * 64 + ks * 32 + kg * 8];
            unsigned int qq[4] = {q.x, q.y, q.z, q.w};
            #pragma unroll
            for (int p = 0; p < 4; ++p) {
                #pragma unroll
                for (int hl = 0; hl < 2; ++hl) {
                    int j = 2 * p + hl;
                    float uv = bf2f(hl ? (unsigned short)(qq[p] >> 16) : (unsigned short)(qq[p] & 0xffff));
                    float hv = uv + dx * w1t[0][ks][j] + dy * w1t[1][ks][j] + dz * w1t[2][ks][j];
                    af[g][ks][j] = (short)f2bf(fmaxf(hv, 0.f));
                }
            }
        }
    }

    #pragma unroll
    for (int t = 0; t < 4; ++t) {
        bf16x8 bf0 = *(const bf16x8*)&w2f[((0 * 4 + t) * 64 + lane) * 8];
        bf16x8 bf1 = *(const bf16x8*)&w2f[((1 * 4 + t) * 64 + lane) * 8];
        f32x4 acc[4];
        #pragma unroll
        for (int g = 0; g < 4; ++g) {
            f32x4 c = {b2v[t], b2v[t], b2v[t], b2v[t]};
            c = __builtin_amdgcn_mfma_f32_16x16x32_bf16(af[g][0], bf0, c, 0, 0, 0);
            acc[g] = __builtin_amdgcn_mfma_f32_16x16x32_bf16(af[g][1], bf1, c, 0, 0, 0);
        }
        __syncthreads();
        #pragma unroll
        for (int g = 0; g < 4; ++g) {
            int eb = wv * 64 + g * 16 + (lane >> 4) * 4;
            #pragma unroll
            for (int r = 0; r < 4; ++r)
                sm[(eb + r) * 17 + (lane & 15)] = acc[g][r];
        }
        __syncthreads();
        int ns = nseg;
        int j = tid & 15;
        for (int si = tid >> 4; si < ns; si += 16) {
            int4 sg = slist[si];
            float v = sm[sg.y * 17 + j];
            for (int p = sg.y + 1; p < sg.z; ++p) v = fmaxf(v, sm[p * 17 + j]);
            float* addr = &accB[(size_t)sg.x * 64 + t * 16 + j];
            if (sg.w) *addr = v;
            else atomic_fmax(addr, v);
        }
    }
}

// ---------------- BatchNorm stats (deterministic two-stage) ----------------
template <int C>
__global__ __launch_bounds__(256) void bn_stats(const float* __restrict__ acc,
                                                float* __restrict__ partials) {
    const int total = NN * C;
    int tid = blockIdx.x * 256 + threadIdx.x;
    const int stride = gridDim.x * 256;
    float s = 0.f, q = 0.f;
    for (int i = tid; i < total; i += stride) {
        float v = acc[i];
        v = finitef(v) ? v : 0.f;
        s += v;
        q = fmaf(v, v, q);
    }
    __shared__ float ls[256], lq[256];
    ls[threadIdx.x] = s; lq[threadIdx.x] = q;
    __syncthreads();
    #pragma unroll
    for (int o = 128; o >= C; o >>= 1) {
        if (threadIdx.x < o) {
            ls[threadIdx.x] += ls[threadIdx.x + o];
            lq[threadIdx.x] += lq[threadIdx.x + o];
        }
        __syncthreads();
    }
    if (threadIdx.x < C) {
        partials[blockIdx.x * 2 * C + threadIdx.x]     = ls[threadIdx.x];
        partials[blockIdx.x * 2 * C + C + threadIdx.x] = lq[threadIdx.x];
    }
}

template <int C>
__global__ void bn_final(const float* __restrict__ partials, int nblocks,
                         const float* __restrict__ gamma, const float* __restrict__ beta,
                         float* __restrict__ ss) {
    int c = threadIdx.x;
    if (c >= C) return;
    float s = 0.f, q = 0.f;
    for (int b = 0; b < nblocks; ++b) {
        s += partials[b * 2 * C + c];
        q += partials[b * 2 * C + C + c];
    }
    float mu  = s / (float)NN;
    float var = fmaxf(q / (float)NN - mu * mu, 0.f);
    float inv = rsqrtf(var + 1e-5f);
    float sc  = gamma[c] * inv;
    ss[c]     = sc;
    ss[C + c] = fmaf(-mu, sc, beta[c]);
}

__global__ __launch_bounds__(256) void apply_bn_relu32(const float* __restrict__ acc,
        const float* __restrict__ ss, float* __restrict__ h) {
    int i = blockIdx.x * 256 + threadIdx.x;
    int stride = gridDim.x * 256;
    for (; i < NN * 32; i += stride) {
        float v = acc[i];
        v = finitef(v) ? v : 0.f;
        int c = i & 31;
        h[i] = fmaxf(fmaf(v, ss[c], ss[32 + c]), 0.f);
    }
}

// ---------------- fused BN+ReLU + graph seg-max ----------------
__global__ __launch_bounds__(256) void pool_graph(const float* __restrict__ accB,
        const float* __restrict__ ss, const int* __restrict__ batch,
        float* __restrict__ gacc) {
    int c = threadIdx.x & 63;
    int sub = threadIdx.x >> 6;
    int base = blockIdx.x * 256;
    float run = 0.f; int curg = -1;
    for (int nn = sub; nn < 256; nn += 4) {
        int n = base + nn;
        if (n >= NN) break;
        int g = batch[n];
        float v = accB[n * 64 + c];
        v = finitef(v) ? v : 0.f;
        v = fmaxf(fmaf(v, ss[c], ss[64 + c]), 0.f);
        if (g != curg) {
            if (curg >= 0) atomicMax((int*)&gacc[curg * 64 + c], __float_as_int(run));
            curg = g; run = v;
        } else {
            run = fmaxf(run, v);
        }
    }
    if (curg >= 0) atomicMax((int*)&gacc[curg * 64 + c], __float_as_int(run));
}

// ---------------- final 64x64x2 GEMM ----------------
__global__ void final_gemm(const float* __restrict__ gacc, const float* __restrict__ Wc,
                           const float* __restrict__ bc, float* __restrict__ out) {
    int t = threadIdx.x;
    if (t >= NG * 2) return;
    int g = t >> 1, o = t & 1;
    float s = bc[o];
    #pragma unroll 8
    for (int k = 0; k < 64; ++k) s = fmaf(gacc[g * 64 + k], Wc[k * 2 + o], s);
    out[t] = s;
}

extern "C" void kernel_launch(void* const* d_in, const int* in_sizes, int n_in,
                              void* d_out, int out_size, void* d_ws, size_t ws_size,
                              hipStream_t stream) {
    const float* pos   = (const float*)d_in[0];
    const int*   ei    = (const int*)d_in[1];
    const int*   batch = (const int*)d_in[2];
    const float* W1a = (const float*)d_in[3];
    const float* b1a = (const float*)d_in[4];
    const float* W2a = (const float*)d_in[5];
    const float* b2a = (const float*)d_in[6];
    const float* g1  = (const float*)d_in[7];
    const float* be1 = (const float*)d_in[8];
    const float* W1b = (const float*)d_in[9];
    const float* b1b = (const float*)d_in[10];
    const float* W2b = (const float*)d_in[11];
    const float* b2b = (const float*)d_in[12];
    const float* g2  = (const float*)d_in[13];
    const float* be2 = (const float*)d_in[14];
    const float* Wc  = (const float*)d_in[15];
    const float* bc  = (const float*)d_in[16];
    const int* srcp = ei;
    const int* dstp = ei + NE;

    char* base = (char*)d_ws;
    size_t ofs = 0;
    auto alloc = [&](size_t bytes) { char* p = base + ofs; ofs = (ofs + bytes + 255) & ~(size_t)255; return p; };
    int*   cnt   = (int*)alloc((size_t)NN * 4);
    int*   off   = (int*)alloc((size_t)(NN + 1) * 4);
    int*   bsum  = (int*)alloc(1024);
    int2*  sedge = (int2*)alloc((size_t)NE * 8);
    unsigned short* u = (unsigned short*)alloc((size_t)NN * 64 * 2);  // uA[NN][32] / uB[NN][64] bf16
    float* hbuf  = (float*)alloc((size_t)NN * 32 * 4);
    float* X     = (float*)alloc((size_t)NN * 64 * 4);                // accA then accB
    float* partA = (float*)alloc(256 * 64 * 4);
    float* partB = (float*)alloc(256 * 128 * 4);
    float* ssA   = (float*)alloc(64 * 4);
    float* ssB   = (float*)alloc(128 * 4);
    float* gacc  = (float*)alloc(NG * 64 * 4);

    const int NB1 = (NN + 511) / 512;
    const int EB  = NE / 256;   // exact

    hipMemsetAsync(cnt, 0, (size_t)NN * 4, stream);
    hipMemsetAsync(gacc, 0, NG * 64 * 4, stream);
    hipMemsetAsync(X, 0xFF, (size_t)NN * 32 * 4, stream);   // accA NaN-init

    hist_kernel<<<(NE + 255) / 256, 256, 0, stream>>>(dstp, cnt);
    scan1<<<NB1, 512, 0, stream>>>(cnt, off, bsum);
    scan2<<<1, 256, 0, stream>>>(bsum, NB1);
    scan3<<<NB1, 512, 0, stream>>>(off, bsum);
    scatter_kernel<<<(NE + 255) / 256, 256, 0, stream>>>(srcp, dstp, cnt, off, sedge);

    uA_kernel<<<(NN + 255) / 256, 256, 0, stream>>>(pos, W1a, b1a, u);
    edgeA<<<EB, 256, 0, stream>>>(pos, u, sedge, off, W1a, W2a, b2a, X);
    bn_stats<32><<<256, 256, 0, stream>>>(X, partA);
    bn_final<32><<<1, 32, 0, stream>>>(partA, 256, g1, be1, ssA);
    apply_bn_relu32<<<1024, 256, 0, stream>>>(X, ssA, hbuf);

    hipMemsetAsync(X, 0xFF, (size_t)NN * 64 * 4, stream);   // accB NaN-init
    uB_kernel<<<(NN + 255) / 256, 256, 0, stream>>>(hbuf, W1b, b1b, u);
    edgeB<<<EB, 256, 0, stream>>>(pos, u, sedge, off, W1b, W2b, b2b, X);
    bn_stats<64><<<256, 256, 0, stream>>>(X, partB);
    bn_final<64><<<1, 64, 0, stream>>>(partB, 256, g2, be2, ssB);
    pool_graph<<<(NN + 255) / 256, 256, 0, stream>>>(X, ssB, batch, gacc);
    final_gemm<<<1, 128, 0, stream>>>(gacc, Wc, bc, (float*)d_out);
}

// Round 5
// 570.242 us; speedup vs baseline: 11.2341x; 1.1011x over previous
//
#include <hip/hip_runtime.h>

#define NN 100000
#define NE 1600000
#define NG 64

typedef __attribute__((ext_vector_type(8))) short bf16x8;
typedef __attribute__((ext_vector_type(4))) float f32x4;

union AFrag { bf16x8 v; uint4 u; };

__device__ __forceinline__ bool finitef(float v) {
    return (__float_as_uint(v) & 0x7F800000u) != 0x7F800000u;
}
__device__ __forceinline__ unsigned short f2bf(float f) {   // RNE, used only in cold W2 pack
    unsigned int u = __float_as_uint(f);
    u += 0x7fffu + ((u >> 16) & 1u);
    return (unsigned short)(u >> 16);
}
// hardware packed f32->bf16 (RNE), 2 values / inst
__device__ __forceinline__ unsigned int cvtpk(float lo, float hi) {
    unsigned int r;
    asm("v_cvt_pk_bf16_f32 %0, %1, %2" : "=v"(r) : "v"(lo), "v"(hi));
    return r;
}
// bf16 pair unpack (1 inst each)
__device__ __forceinline__ float bflo(unsigned int q) { return __uint_as_float(q << 16); }
__device__ __forceinline__ float bfhi(unsigned int q) { return __uint_as_float(q & 0xffff0000u); }

// Running float-max via sign-split integer atomics (init pattern 0xFFFFFFFF = -inf-like).
__device__ __forceinline__ void atomic_fmax(float* addr, float v) {
    if (v >= 0.0f) atomicMax((int*)addr, __float_as_int(v));
    else           atomicMin((unsigned int*)addr, __float_as_uint(v));
}

// ---------------- CSR build ----------------
__global__ __launch_bounds__(256) void hist_kernel(const int* __restrict__ dst,
                                                   int* __restrict__ cnt) {
    int e = blockIdx.x * 256 + threadIdx.x;
    if (e < NE) atomicAdd(&cnt[dst[e]], 1);
}

__global__ __launch_bounds__(512) void scan1(const int* __restrict__ cnt,
                                             int* __restrict__ off, int* __restrict__ bsum) {
    __shared__ int ls[512];
    int tid = threadIdx.x;
    int i = blockIdx.x * 512 + tid;
    int v = (i < NN) ? cnt[i] : 0;
    ls[tid] = v;
    __syncthreads();
    for (int o = 1; o < 512; o <<= 1) {
        int t = (tid >= o) ? ls[tid - o] : 0;
        __syncthreads();
        ls[tid] += t;
        __syncthreads();
    }
    if (i < NN) off[i] = ls[tid] - v;
    if (tid == 511) bsum[blockIdx.x] = ls[511];
}

__global__ __launch_bounds__(256) void scan2(int* __restrict__ bsum, int nb) {
    __shared__ int ls[256];
    int tid = threadIdx.x;
    int v = (tid < nb) ? bsum[tid] : 0;
    ls[tid] = v;
    __syncthreads();
    for (int o = 1; o < 256; o <<= 1) {
        int t = (tid >= o) ? ls[tid - o] : 0;
        __syncthreads();
        ls[tid] += t;
        __syncthreads();
    }
    if (tid < nb) bsum[tid] = ls[tid] - v;
}

__global__ __launch_bounds__(512) void scan3(int* __restrict__ off, const int* __restrict__ bsum) {
    int i = blockIdx.x * 512 + threadIdx.x;
    if (i < NN) off[i] += bsum[i >> 9];
    if (blockIdx.x == 0 && threadIdx.x == 0) off[NN] = NE;
}

__global__ __launch_bounds__(256) void scatter_kernel(const int* __restrict__ src,
        const int* __restrict__ dst, int* __restrict__ cnt, const int* __restrict__ off,
        int2* __restrict__ sedge) {
    int e = blockIdx.x * 256 + threadIdx.x;
    if (e < NE) {
        int d = dst[e];
        int q = atomicSub(&cnt[d], 1);
        sedge[off[d] + q - 1] = make_int2(src[e], d);
    }
}

// ---------------- layer A node tables: P = pos@(W1h+W1t)+b1, Q = pos@W1t (bf16) ----------------
__global__ __launch_bounds__(256) void uA_kernel(const float* __restrict__ pos,
        const float* __restrict__ W1, const float* __restrict__ b1,
        unsigned short* __restrict__ PA, unsigned short* __restrict__ QA) {
    __shared__ float sWp[96], sWq[96], sb[32];
    if (threadIdx.x < 96) {
        float wt = W1[96 + threadIdx.x];
        sWq[threadIdx.x] = wt;
        sWp[threadIdx.x] = W1[threadIdx.x] + wt;
    }
    if (threadIdx.x < 32) sb[threadIdx.x] = b1[threadIdx.x];
    __syncthreads();
    int n = blockIdx.x * 256 + threadIdx.x;
    if (n >= NN) return;
    float p0 = pos[n * 3 + 0], p1 = pos[n * 3 + 1], p2 = pos[n * 3 + 2];
    float P[32], Q[32];
    #pragma unroll
    for (int c = 0; c < 32; ++c) {
        P[c] = fmaf(p2, sWp[64 + c], fmaf(p1, sWp[32 + c], fmaf(p0, sWp[c], sb[c])));
        Q[c] = fmaf(p2, sWq[64 + c], fmaf(p1, sWq[32 + c], p0 * sWq[c]));
    }
    uint4* po = (uint4*)(PA + (size_t)n * 32);
    uint4* qo = (uint4*)(QA + (size_t)n * 32);
    #pragma unroll
    for (int q = 0; q < 4; ++q) {
        po[q] = make_uint4(cvtpk(P[8*q],P[8*q+1]), cvtpk(P[8*q+2],P[8*q+3]),
                           cvtpk(P[8*q+4],P[8*q+5]), cvtpk(P[8*q+6],P[8*q+7]));
        qo[q] = make_uint4(cvtpk(Q[8*q],Q[8*q+1]), cvtpk(Q[8*q+2],Q[8*q+3]),
                           cvtpk(Q[8*q+4],Q[8*q+5]), cvtpk(Q[8*q+6],Q[8*q+7]));
    }
}

// ---------------- layer B node tables (BN+ReLU fused in): ----------------
// h = relu(BN(accA)); P = h@W1b[0:32] + pos@W1b[32:35] + b1; Q = pos@W1b[32:35]
__global__ __launch_bounds__(256) void uB_kernel(const float* __restrict__ accA,
        const float* __restrict__ ssA, const float* __restrict__ pos,
        const float* __restrict__ W1, const float* __restrict__ b1,
        unsigned short* __restrict__ PB, unsigned short* __restrict__ QB) {
    __shared__ float sW[32 * 64];
    __shared__ float sWt[3 * 64];
    __shared__ float sb[64];
    for (int i = threadIdx.x; i < 32 * 64; i += 256) sW[i] = W1[i];
    if (threadIdx.x < 192) sWt[threadIdx.x] = W1[32 * 64 + threadIdx.x];
    if (threadIdx.x < 64) sb[threadIdx.x] = b1[threadIdx.x];
    __syncthreads();
    int n = blockIdx.x * 256 + threadIdx.x;
    if (n >= NN) return;
    float h[32];
    const float4* a4 = (const float4*)(accA + (size_t)n * 32);
    #pragma unroll
    for (int q = 0; q < 8; ++q) {
        float4 v = a4[q];
        float vv[4] = {v.x, v.y, v.z, v.w};
        #pragma unroll
        for (int r = 0; r < 4; ++r) {
            int c = 4 * q + r;
            float x = finitef(vv[r]) ? vv[r] : 0.f;
            h[c] = fmaxf(fmaf(x, ssA[c], ssA[32 + c]), 0.f);
        }
    }
    float p0 = pos[n * 3 + 0], p1 = pos[n * 3 + 1], p2 = pos[n * 3 + 2];
    float Q[64], P[64];
    #pragma unroll
    for (int c = 0; c < 64; ++c) {
        Q[c] = fmaf(p2, sWt[128 + c], fmaf(p1, sWt[64 + c], p0 * sWt[c]));
        P[c] = Q[c] + sb[c];
    }
    #pragma unroll
    for (int k = 0; k < 32; ++k) {
        float x = h[k];
        #pragma unroll
        for (int c = 0; c < 64; ++c) P[c] = fmaf(x, sW[k * 64 + c], P[c]);
    }
    uint4* po = (uint4*)(PB + (size_t)n * 64);
    uint4* qo = (uint4*)(QB + (size_t)n * 64);
    #pragma unroll
    for (int q = 0; q < 8; ++q) {
        po[q] = make_uint4(cvtpk(P[8*q],P[8*q+1]), cvtpk(P[8*q+2],P[8*q+3]),
                           cvtpk(P[8*q+4],P[8*q+5]), cvtpk(P[8*q+6],P[8*q+7]));
        qo[q] = make_uint4(cvtpk(Q[8*q],Q[8*q+1]), cvtpk(Q[8*q+2],Q[8*q+3]),
                           cvtpk(Q[8*q+4],Q[8*q+5]), cvtpk(Q[8*q+6],Q[8*q+7]));
    }
}

// ---------------- Layer A edges: hid = relu(P[s]-Q[d]); MFMA 16x16x32; seg-max ----------------
__global__ __launch_bounds__(256, 4) void edgeA(
        const unsigned short* __restrict__ PA, const unsigned short* __restrict__ QA,
        const int2* __restrict__ sedge, const int* __restrict__ off,
        const float* __restrict__ W2, const float* __restrict__ b2,
        float* __restrict__ accA) {
    __shared__ __align__(16) short w2f[2 * 64 * 8];
    __shared__ int2  sed[256];
    __shared__ float sm[256 * 18];
    __shared__ int4  slist[256];
    __shared__ int   nseg;

    const int tid = threadIdx.x;
    const int b0  = blockIdx.x * 256;
    const int lane = tid & 63, wv = tid >> 6;
    const int kg = (lane >> 4);

    #pragma unroll
    for (int ii = 0; ii < 4; ++ii) {
        int i = tid + ii * 256;
        int j = i & 7, ln = (i >> 3) & 63, t = (i >> 9) & 1;
        int k = ((ln >> 4) & 3) * 8 + j, col = (ln & 15) + 16 * t;
        w2f[i] = (short)f2bf(W2[k * 32 + col]);
    }
    if (tid == 0) nseg = 0;
    sed[tid] = sedge[b0 + tid];
    __syncthreads();

    int d0 = sed[tid].y;
    bool flag = (tid == 0) || (sed[tid - 1].y != d0);
    if (flag) {
        int o0 = off[d0], o1 = off[d0 + 1];
        int lo = max(o0 - b0, 0);
        int hi = min(o1 - b0, 256);
        int interior = (o0 >= b0) && (o1 <= b0 + 256);
        int idx = atomicAdd(&nseg, 1);
        slist[idx] = make_int4(d0, lo, hi, interior);
    }

    float b2v[2];
    #pragma unroll
    for (int t = 0; t < 2; ++t) b2v[t] = b2[(lane & 15) + 16 * t];

    AFrag af[4];
    #pragma unroll
    for (int g = 0; g < 4; ++g) {
        int E = wv * 64 + g * 16 + (lane & 15);
        int s = sed[E].x, dd = sed[E].y;
        uint4 Pq = *(const uint4*)&PA[(size_t)s * 32 + kg * 8];
        uint4 Qq = *(const uint4*)&QA[(size_t)dd * 32 + kg * 8];
        unsigned int pu[4] = {Pq.x, Pq.y, Pq.z, Pq.w};
        unsigned int qu[4] = {Qq.x, Qq.y, Qq.z, Qq.w};
        unsigned int outw[4];
        #pragma unroll
        for (int p = 0; p < 4; ++p) {
            float vlo = fmaxf(bflo(pu[p]) - bflo(qu[p]), 0.f);
            float vhi = fmaxf(bfhi(pu[p]) - bfhi(qu[p]), 0.f);
            outw[p] = cvtpk(vlo, vhi);
        }
        af[g].u = make_uint4(outw[0], outw[1], outw[2], outw[3]);
    }

    #pragma unroll
    for (int t = 0; t < 2; ++t) {
        bf16x8 bfr = *(const bf16x8*)&w2f[(t * 64 + lane) * 8];
        f32x4 acc[4];
        #pragma unroll
        for (int g = 0; g < 4; ++g) {
            f32x4 c = {b2v[t], b2v[t], b2v[t], b2v[t]};
            acc[g] = __builtin_amdgcn_mfma_f32_16x16x32_bf16(af[g].v, bfr, c, 0, 0, 0);
        }
        __syncthreads();
        #pragma unroll
        for (int g = 0; g < 4; ++g) {
            int eb = wv * 64 + g * 16 + (lane >> 4) * 4;
            #pragma unroll
            for (int r = 0; r < 4; ++r)
                sm[(eb + r) * 18 + (lane & 15)] = acc[g][r];
        }
        __syncthreads();
        int ns = nseg;
        int j = tid & 15;
        for (int si = tid >> 4; si < ns; si += 16) {
            int4 sg = slist[si];
            float v = sm[sg.y * 18 + j];
            for (int p = sg.y + 1; p < sg.z; ++p) v = fmaxf(v, sm[p * 18 + j]);
            float* addr = &accA[(size_t)sg.x * 32 + t * 16 + j];
            if (sg.w) *addr = v;
            else atomic_fmax(addr, v);
        }
    }
}

// ---------------- Layer B edges: hid = relu(P[s]-Q[d]); MFMA 16x16x32 x2K; seg-max ----------------
__global__ __launch_bounds__(256, 4) void edgeB(
        const unsigned short* __restrict__ PB, const unsigned short* __restrict__ QB,
        const int2* __restrict__ sedge, const int* __restrict__ off,
        const float* __restrict__ W2, const float* __restrict__ b2,
        float* __restrict__ accB) {
    __shared__ __align__(16) short w2f[2 * 4 * 64 * 8];
    __shared__ int2  sed[256];
    __shared__ float sm[256 * 18];
    __shared__ int4  slist[256];
    __shared__ int   nseg;

    const int tid = threadIdx.x;
    const int b0  = blockIdx.x * 256;
    const int lane = tid & 63, wv = tid >> 6;
    const int kg = (lane >> 4);

    #pragma unroll
    for (int ii = 0; ii < 16; ++ii) {
        int i = tid + ii * 256;
        int j = i & 7, ln = (i >> 3) & 63, t = (i >> 9) & 3, ks = (i >> 11) & 1;
        int k = ks * 32 + ((ln >> 4) & 3) * 8 + j, col = (ln & 15) + 16 * t;
        w2f[i] = (short)f2bf(W2[k * 64 + col]);
    }
    if (tid == 0) nseg = 0;
    sed[tid] = sedge[b0 + tid];
    __syncthreads();

    int d0 = sed[tid].y;
    bool flag = (tid == 0) || (sed[tid - 1].y != d0);
    if (flag) {
        int o0 = off[d0], o1 = off[d0 + 1];
        int lo = max(o0 - b0, 0);
        int hi = min(o1 - b0, 256);
        int interior = (o0 >= b0) && (o1 <= b0 + 256);
        int idx = atomicAdd(&nseg, 1);
        slist[idx] = make_int4(d0, lo, hi, interior);
    }

    float b2v[4];
    #pragma unroll
    for (int t = 0; t < 4; ++t) b2v[t] = b2[(lane & 15) + 16 * t];

    AFrag af[4][2];
    #pragma unroll
    for (int g = 0; g < 4; ++g) {
        int E = wv * 64 + g * 16 + (lane & 15);
        int s = sed[E].x, dd = sed[E].y;
        #pragma unroll
        for (int ks = 0; ks < 2; ++ks) {
            uint4 Pq = *(const uint4*)&PB[(size_t)s * 64 + ks * 32 + kg * 8];
            uint4 Qq = *(const uint4*)&QB[(size_t)dd * 64 + ks * 32 + kg * 8];
            unsigned int pu[4] = {Pq.x, Pq.y, Pq.z, Pq.w};
            unsigned int qu[4] = {Qq.x, Qq.y, Qq.z, Qq.w};
            unsigned int outw[4];
            #pragma unroll
            for (int p = 0; p < 4; ++p) {
                float vlo = fmaxf(bflo(pu[p]) - bflo(qu[p]), 0.f);
                float vhi = fmaxf(bfhi(pu[p]) - bfhi(qu[p]), 0.f);
                outw[p] = cvtpk(vlo, vhi);
            }
            af[g][ks].u = make_uint4(outw[0], outw[1], outw[2], outw[3]);
        }
    }

    #pragma unroll
    for (int t = 0; t < 4; ++t) {
        bf16x8 bf0 = *(const bf16x8*)&w2f[((0 * 4 + t) * 64 + lane) * 8];
        bf16x8 bf1 = *(const bf16x8*)&w2f[((1 * 4 + t) * 64 + lane) * 8];
        f32x4 acc[4];
        #pragma unroll
        for (int g = 0; g < 4; ++g) {
            f32x4 c = {b2v[t], b2v[t], b2v[t], b2v[t]};
            c = __builtin_amdgcn_mfma_f32_16x16x32_bf16(af[g][0].v, bf0, c, 0, 0, 0);
            acc[g] = __builtin_amdgcn_mfma_f32_16x16x32_bf16(af[g][1].v, bf1, c, 0, 0, 0);
        }
        __syncthreads();
        #pragma unroll
        for (int g = 0; g < 4; ++g) {
            int eb = wv * 64 + g * 16 + (lane >> 4) * 4;
            #pragma unroll
            for (int r = 0; r < 4; ++r)
                sm[(eb + r) * 18 + (lane & 15)] = acc[g][r];
        }
        __syncthreads();
        int ns = nseg;
        int j = tid & 15;
        for (int si = tid >> 4; si < ns; si += 16) {
            int4 sg = slist[si];
            float v = sm[sg.y * 18 + j];
            for (int p = sg.y + 1; p < sg.z; ++p) v = fmaxf(v, sm[p * 18 + j]);
            float* addr = &accB[(size_t)sg.x * 64 + t * 16 + j];
            if (sg.w) *addr = v;
            else atomic_fmax(addr, v);
        }
    }
}

// ---------------- BatchNorm stats (deterministic two-stage) ----------------
template <int C>
__global__ __launch_bounds__(256) void bn_stats(const float* __restrict__ acc,
                                                float* __restrict__ partials) {
    const int total = NN * C;
    int tid = blockIdx.x * 256 + threadIdx.x;
    const int stride = gridDim.x * 256;
    float s = 0.f, q = 0.f;
    for (int i = tid; i < total; i += stride) {
        float v = acc[i];
        v = finitef(v) ? v : 0.f;
        s += v;
        q = fmaf(v, v, q);
    }
    __shared__ float ls[256], lq[256];
    ls[threadIdx.x] = s; lq[threadIdx.x] = q;
    __syncthreads();
    #pragma unroll
    for (int o = 128; o >= C; o >>= 1) {
        if (threadIdx.x < o) {
            ls[threadIdx.x] += ls[threadIdx.x + o];
            lq[threadIdx.x] += lq[threadIdx.x + o];
        }
        __syncthreads();
    }
    if (threadIdx.x < C) {
        partials[blockIdx.x * 2 * C + threadIdx.x]     = ls[threadIdx.x];
        partials[blockIdx.x * 2 * C + C + threadIdx.x] = lq[threadIdx.x];
    }
}

template <int C>
__global__ void bn_final(const float* __restrict__ partials, int nblocks,
                         const float* __restrict__ gamma, const float* __restrict__ beta,
                         float* __restrict__ ss) {
    int c = threadIdx.x;
    if (c >= C) return;
    float s = 0.f, q = 0.f;
    for (int b = 0; b < nblocks; ++b) {
        s += partials[b * 2 * C + c];
        q += partials[b * 2 * C + C + c];
    }
    float mu  = s / (float)NN;
    float var = fmaxf(q / (float)NN - mu * mu, 0.f);
    float inv = rsqrtf(var + 1e-5f);
    float sc  = gamma[c] * inv;
    ss[c]     = sc;
    ss[C + c] = fmaf(-mu, sc, beta[c]);
}

// ---------------- fused BN+ReLU + graph seg-max ----------------
__global__ __launch_bounds__(256) void pool_graph(const float* __restrict__ accB,
        const float* __restrict__ ss, const int* __restrict__ batch,
        float* __restrict__ gacc) {
    int c = threadIdx.x & 63;
    int sub = threadIdx.x >> 6;
    int base = blockIdx.x * 256;
    float run = 0.f; int curg = -1;
    for (int nn = sub; nn < 256; nn += 4) {
        int n = base + nn;
        if (n >= NN) break;
        int g = batch[n];
        float v = accB[n * 64 + c];
        v = finitef(v) ? v : 0.f;
        v = fmaxf(fmaf(v, ss[c], ss[64 + c]), 0.f);
        if (g != curg) {
            if (curg >= 0) atomicMax((int*)&gacc[curg * 64 + c], __float_as_int(run));
            curg = g; run = v;
        } else {
            run = fmaxf(run, v);
        }
    }
    if (curg >= 0) atomicMax((int*)&gacc[curg * 64 + c], __float_as_int(run));
}

// ---------------- final 64x64x2 GEMM ----------------
__global__ void final_gemm(const float* __restrict__ gacc, const float* __restrict__ Wc,
                           const float* __restrict__ bc, float* __restrict__ out) {
    int t = threadIdx.x;
    if (t >= NG * 2) return;
    int g = t >> 1, o = t & 1;
    float s = bc[o];
    #pragma unroll 8
    for (int k = 0; k < 64; ++k) s = fmaf(gacc[g * 64 + k], Wc[k * 2 + o], s);
    out[t] = s;
}

extern "C" void kernel_launch(void* const* d_in, const int* in_sizes, int n_in,
                              void* d_out, int out_size, void* d_ws, size_t ws_size,
                              hipStream_t stream) {
    const float* pos   = (const float*)d_in[0];
    const int*   ei    = (const int*)d_in[1];
    const int*   batch = (const int*)d_in[2];
    const float* W1a = (const float*)d_in[3];
    const float* b1a = (const float*)d_in[4];
    const float* W2a = (const float*)d_in[5];
    const float* b2a = (const float*)d_in[6];
    const float* g1  = (const float*)d_in[7];
    const float* be1 = (const float*)d_in[8];
    const float* W1b = (const float*)d_in[9];
    const float* b1b = (const float*)d_in[10];
    const float* W2b = (const float*)d_in[11];
    const float* b2b = (const float*)d_in[12];
    const float* g2  = (const float*)d_in[13];
    const float* be2 = (const float*)d_in[14];
    const float* Wc  = (const float*)d_in[15];
    const float* bc  = (const float*)d_in[16];
    const int* srcp = ei;
    const int* dstp = ei + NE;

    char* base = (char*)d_ws;
    size_t ofs = 0;
    auto alloc = [&](size_t bytes) { char* p = base + ofs; ofs = (ofs + bytes + 255) & ~(size_t)255; return p; };
    int*   cnt   = (int*)alloc((size_t)NN * 4);
    int*   off   = (int*)alloc((size_t)(NN + 1) * 4);
    int*   bsum  = (int*)alloc(1024);
    int2*  sedge = (int2*)alloc((size_t)NE * 8);
    unsigned short* PA = (unsigned short*)alloc((size_t)NN * 32 * 2);   // 6.4 MB (256-divisible)
    unsigned short* QA = (unsigned short*)alloc((size_t)NN * 32 * 2);   // 6.4 MB, contiguous after PA
    unsigned short* PB = PA;                                            // alias: PB spans PA+QA (12.8 MB); edgeA done before uB writes
    unsigned short* QB = (unsigned short*)alloc((size_t)NN * 64 * 2);   // 12.8 MB
    float* X     = (float*)alloc((size_t)NN * 64 * 4);                  // accA then accB
    float* partA = (float*)alloc(256 * 64 * 4);
    float* partB = (float*)alloc(256 * 128 * 4);
    float* ssA   = (float*)alloc(64 * 4);
    float* ssB   = (float*)alloc(128 * 4);
    float* gacc  = (float*)alloc(NG * 64 * 4);

    const int NB1 = (NN + 511) / 512;
    const int EB  = NE / 256;   // exact

    hipMemsetAsync(cnt, 0, (size_t)NN * 4, stream);
    hipMemsetAsync(gacc, 0, NG * 64 * 4, stream);
    hipMemsetAsync(X, 0xFF, (size_t)NN * 32 * 4, stream);   // accA NaN-init

    hist_kernel<<<(NE + 255) / 256, 256, 0, stream>>>(dstp, cnt);
    scan1<<<NB1, 512, 0, stream>>>(cnt, off, bsum);
    scan2<<<1, 256, 0, stream>>>(bsum, NB1);
    scan3<<<NB1, 512, 0, stream>>>(off, bsum);
    scatter_kernel<<<(NE + 255) / 256, 256, 0, stream>>>(srcp, dstp, cnt, off, sedge);

    uA_kernel<<<(NN + 255) / 256, 256, 0, stream>>>(pos, W1a, b1a, PA, QA);
    edgeA<<<EB, 256, 0, stream>>>(PA, QA, sedge, off, W2a, b2a, X);
    bn_stats<32><<<256, 256, 0, stream>>>(X, partA);
    bn_final<32><<<1, 32, 0, stream>>>(partA, 256, g1, be1, ssA);

    uB_kernel<<<(NN + 255) / 256, 256, 0, stream>>>(X, ssA, pos, W1b, b1b, PB, QB);
    hipMemsetAsync(X, 0xFF, (size_t)NN * 64 * 4, stream);   // accB NaN-init
    edgeB<<<EB, 256, 0, stream>>>(PB, QB, sedge, off, W2b, b2b, X);
    bn_stats<64><<<256, 256, 0, stream>>>(X, partB);
    bn_final<64><<<1, 64, 0, stream>>>(partB, 256, g2, be2, ssB);
    pool_graph<<<(NN + 255) / 256, 256, 0, stream>>>(X, ssB, batch, gacc);
    final_gemm<<<1, 128, 0, stream>>>(gacc, Wc, bc, (float*)d_out);
}

// Round 6
// 455.176 us; speedup vs baseline: 14.0740x; 1.2528x over previous
//
#include <hip/hip_runtime.h>

#define NN 100000
#define NE 1600000
#define NG 64
#define NBUK 782          // dst>>7 buckets (128 nodes each)
#define NBLK1 391         // ceil(NE/4096)
#define EPB 4096          // edges per pass-1 block
#define CAP2 4096         // pass-2 LDS edge capacity (mean 2048, ~45 sigma margin)

typedef __attribute__((ext_vector_type(8))) short bf16x8;
typedef __attribute__((ext_vector_type(4))) float f32x4;

union AFrag { bf16x8 v; uint4 u; };

__device__ __forceinline__ bool finitef(float v) {
    return (__float_as_uint(v) & 0x7F800000u) != 0x7F800000u;
}
__device__ __forceinline__ unsigned short f2bf(float f) {   // RNE, cold paths only
    unsigned int u = __float_as_uint(f);
    u += 0x7fffu + ((u >> 16) & 1u);
    return (unsigned short)(u >> 16);
}
__device__ __forceinline__ unsigned int cvtpk(float lo, float hi) {
    unsigned int r;
    asm("v_cvt_pk_bf16_f32 %0, %1, %2" : "=v"(r) : "v"(lo), "v"(hi));
    return r;
}
__device__ __forceinline__ float bflo(unsigned int q) { return __uint_as_float(q << 16); }
__device__ __forceinline__ float bfhi(unsigned int q) { return __uint_as_float(q & 0xffff0000u); }

// Running float-max via sign-split integer atomics (init pattern 0xFFFFFFFF acts as -inf).
__device__ __forceinline__ void atomic_fmax(float* addr, float v) {
    if (v >= 0.0f) atomicMax((int*)addr, __float_as_int(v));
    else           atomicMin((unsigned int*)addr, __float_as_uint(v));
}

// ---------------- CSR build: atomic-free bucket sort ----------------
__global__ __launch_bounds__(256) void p1count(const int* __restrict__ dst,
                                               int* __restrict__ gmat) {
    __shared__ int h[NBUK];
    int tid = threadIdx.x;
    for (int i = tid; i < NBUK; i += 256) h[i] = 0;
    __syncthreads();
    int e0 = blockIdx.x * EPB;
    #pragma unroll
    for (int i = 0; i < 16; ++i) {
        int e = e0 + tid + i * 256;
        if (e < NE) atomicAdd(&h[dst[e] >> 7], 1);
    }
    __syncthreads();
    for (int i = tid; i < NBUK; i += 256) gmat[blockIdx.x * NBUK + i] = h[i];
}

__global__ __launch_bounds__(512) void scanA(int* __restrict__ gmat, int* __restrict__ tot) {
    __shared__ int ls[512];
    int b = blockIdx.x, tid = threadIdx.x;
    int v = (tid < NBLK1) ? gmat[tid * NBUK + b] : 0;
    ls[tid] = v;
    __syncthreads();
    for (int o = 1; o < 512; o <<= 1) {
        int t = (tid >= o) ? ls[tid - o] : 0;
        __syncthreads();
        ls[tid] += t;
        __syncthreads();
    }
    if (tid < NBLK1) gmat[tid * NBUK + b] = ls[tid] - v;   // exclusive over blocks
    if (tid == 511) tot[b] = ls[511];
}

__global__ __launch_bounds__(1024) void scanB(const int* __restrict__ tot,
        int* __restrict__ base, int* __restrict__ off,
        unsigned int* __restrict__ gmax, unsigned int* __restrict__ gneg) {
    __shared__ int ls[1024];
    int tid = threadIdx.x;
    int v = (tid < NBUK) ? tot[tid] : 0;
    ls[tid] = v;
    __syncthreads();
    for (int o = 1; o < 1024; o <<= 1) {
        int t = (tid >= o) ? ls[tid - o] : 0;
        __syncthreads();
        ls[tid] += t;
        __syncthreads();
    }
    if (tid < NBUK) base[tid] = ls[tid] - v;
    if (tid == 1023) { base[NBUK] = ls[1023]; off[NN] = NE; }
    for (int i = tid; i < NG * 64; i += 1024) { gmax[i] = 0xFFFFFFFFu; gneg[i] = 0xFFFFFFFFu; }
}

__global__ __launch_bounds__(256) void p1scatter(const int* __restrict__ src,
        const int* __restrict__ dst, const int* __restrict__ gmat,
        const int* __restrict__ base, int2* __restrict__ tmp) {
    __shared__ int cur[NBUK];
    int tid = threadIdx.x;
    for (int i = tid; i < NBUK; i += 256) cur[i] = base[i] + gmat[blockIdx.x * NBUK + i];
    __syncthreads();
    int e0 = blockIdx.x * EPB;
    #pragma unroll
    for (int i = 0; i < 16; ++i) {
        int e = e0 + tid + i * 256;
        if (e < NE) {
            int d = dst[e];
            int p = atomicAdd(&cur[d >> 7], 1);
            tmp[p] = make_int2(src[e], d);
        }
    }
}

__global__ __launch_bounds__(256) void p2sort(const int2* __restrict__ tmp,
        const int* __restrict__ base, int2* __restrict__ sedge, int* __restrict__ off) {
    __shared__ int2 earr[CAP2];
    __shared__ int nh[128], np[128], ncur[128];
    int b = blockIdx.x, tid = threadIdx.x;
    int bs = base[b], be = base[b + 1];
    int cnt = min(be - bs, CAP2);
    int nb0 = b << 7;
    if (tid < 128) nh[tid] = 0;
    __syncthreads();
    for (int i = tid; i < cnt; i += 256) {
        int2 ed = tmp[bs + i];
        earr[i] = ed;
        atomicAdd(&nh[ed.y - nb0], 1);
    }
    __syncthreads();
    if (tid < 128) np[tid] = nh[tid];
    __syncthreads();
    for (int o = 1; o < 128; o <<= 1) {
        int t = 0;
        if (tid < 128 && tid >= o) t = np[tid - o];
        __syncthreads();
        if (tid < 128) np[tid] += t;
        __syncthreads();
    }
    if (tid < 128) {
        int ex = np[tid] - nh[tid];          // exclusive prefix
        ncur[tid] = ex;
        int n = nb0 + tid;
        if (n < NN) off[n] = bs + ex;
    }
    __syncthreads();
    for (int i = tid; i < cnt; i += 256) {
        int2 ed = earr[i];
        int p = atomicAdd(&ncur[ed.y - nb0], 1);
        sedge[bs + p] = ed;
    }
}

// ---------------- layer A node tables: P = pos@(W1h+W1t)+b1, Q = pos@W1t (bf16) ----------------
__global__ __launch_bounds__(256) void uA_kernel(const float* __restrict__ pos,
        const float* __restrict__ W1, const float* __restrict__ b1,
        unsigned short* __restrict__ PA, unsigned short* __restrict__ QA) {
    __shared__ float sWp[96], sWq[96], sb[32];
    if (threadIdx.x < 96) {
        float wt = W1[96 + threadIdx.x];
        sWq[threadIdx.x] = wt;
        sWp[threadIdx.x] = W1[threadIdx.x] + wt;
    }
    if (threadIdx.x < 32) sb[threadIdx.x] = b1[threadIdx.x];
    __syncthreads();
    int n = blockIdx.x * 256 + threadIdx.x;
    if (n >= NN) return;
    float p0 = pos[n * 3 + 0], p1 = pos[n * 3 + 1], p2 = pos[n * 3 + 2];
    float P[32], Q[32];
    #pragma unroll
    for (int c = 0; c < 32; ++c) {
        P[c] = fmaf(p2, sWp[64 + c], fmaf(p1, sWp[32 + c], fmaf(p0, sWp[c], sb[c])));
        Q[c] = fmaf(p2, sWq[64 + c], fmaf(p1, sWq[32 + c], p0 * sWq[c]));
    }
    uint4* po = (uint4*)(PA + (size_t)n * 32);
    uint4* qo = (uint4*)(QA + (size_t)n * 32);
    #pragma unroll
    for (int q = 0; q < 4; ++q) {
        po[q] = make_uint4(cvtpk(P[8*q],P[8*q+1]), cvtpk(P[8*q+2],P[8*q+3]),
                           cvtpk(P[8*q+4],P[8*q+5]), cvtpk(P[8*q+6],P[8*q+7]));
        qo[q] = make_uint4(cvtpk(Q[8*q],Q[8*q+1]), cvtpk(Q[8*q+2],Q[8*q+3]),
                           cvtpk(Q[8*q+4],Q[8*q+5]), cvtpk(Q[8*q+6],Q[8*q+7]));
    }
}

// ---------------- layer B node tables (BN+ReLU fused in) ----------------
__global__ __launch_bounds__(256) void uB_kernel(const float* __restrict__ accA,
        const float* __restrict__ ssA, const float* __restrict__ pos,
        const float* __restrict__ W1, const float* __restrict__ b1,
        unsigned short* __restrict__ PB, unsigned short* __restrict__ QB) {
    __shared__ float sW[32 * 64];
    __shared__ float sWt[3 * 64];
    __shared__ float sb[64];
    for (int i = threadIdx.x; i < 32 * 64; i += 256) sW[i] = W1[i];
    if (threadIdx.x < 192) sWt[threadIdx.x] = W1[32 * 64 + threadIdx.x];
    if (threadIdx.x < 64) sb[threadIdx.x] = b1[threadIdx.x];
    __syncthreads();
    int n = blockIdx.x * 256 + threadIdx.x;
    if (n >= NN) return;
    float h[32];
    const float4* a4 = (const float4*)(accA + (size_t)n * 32);
    #pragma unroll
    for (int q = 0; q < 8; ++q) {
        float4 v = a4[q];
        float vv[4] = {v.x, v.y, v.z, v.w};
        #pragma unroll
        for (int r = 0; r < 4; ++r) {
            int c = 4 * q + r;
            float x = finitef(vv[r]) ? vv[r] : 0.f;
            h[c] = fmaxf(fmaf(x, ssA[c], ssA[32 + c]), 0.f);
        }
    }
    float p0 = pos[n * 3 + 0], p1 = pos[n * 3 + 1], p2 = pos[n * 3 + 2];
    float Q[64], P[64];
    #pragma unroll
    for (int c = 0; c < 64; ++c) {
        Q[c] = fmaf(p2, sWt[128 + c], fmaf(p1, sWt[64 + c], p0 * sWt[c]));
        P[c] = Q[c] + sb[c];
    }
    #pragma unroll
    for (int k = 0; k < 32; ++k) {
        float x = h[k];
        #pragma unroll
        for (int c = 0; c < 64; ++c) P[c] = fmaf(x, sW[k * 64 + c], P[c]);
    }
    uint4* po = (uint4*)(PB + (size_t)n * 64);
    uint4* qo = (uint4*)(QB + (size_t)n * 64);
    #pragma unroll
    for (int q = 0; q < 8; ++q) {
        po[q] = make_uint4(cvtpk(P[8*q],P[8*q+1]), cvtpk(P[8*q+2],P[8*q+3]),
                           cvtpk(P[8*q+4],P[8*q+5]), cvtpk(P[8*q+6],P[8*q+7]));
        qo[q] = make_uint4(cvtpk(Q[8*q],Q[8*q+1]), cvtpk(Q[8*q+2],Q[8*q+3]),
                           cvtpk(Q[8*q+4],Q[8*q+5]), cvtpk(Q[8*q+6],Q[8*q+7]));
    }
}

// ---------------- Layer A edges: hid = relu(P[s]-Q[d]); MFMA 16x16x32; seg-max ----------------
__global__ __launch_bounds__(256, 4) void edgeA(
        const unsigned short* __restrict__ PA, const unsigned short* __restrict__ QA,
        const int2* __restrict__ sedge, const int* __restrict__ off,
        const float* __restrict__ W2, const float* __restrict__ b2,
        float* __restrict__ accA) {
    __shared__ __align__(16) short w2f[2 * 64 * 8];
    __shared__ int2  sed[256];
    __shared__ float sm[256 * 18];
    __shared__ int4  slist[256];
    __shared__ int   nseg;

    const int tid = threadIdx.x;
    const int b0  = blockIdx.x * 256;
    const int lane = tid & 63, wv = tid >> 6;
    const int kg = (lane >> 4);

    #pragma unroll
    for (int ii = 0; ii < 4; ++ii) {
        int i = tid + ii * 256;
        int j = i & 7, ln = (i >> 3) & 63, t = (i >> 9) & 1;
        int k = ((ln >> 4) & 3) * 8 + j, col = (ln & 15) + 16 * t;
        w2f[i] = (short)f2bf(W2[k * 32 + col]);
    }
    if (tid == 0) nseg = 0;
    sed[tid] = sedge[b0 + tid];
    __syncthreads();

    int d0 = sed[tid].y;
    bool flag = (tid == 0) || (sed[tid - 1].y != d0);
    if (flag) {
        int o0 = off[d0], o1 = off[d0 + 1];
        int lo = max(o0 - b0, 0);
        int hi = min(o1 - b0, 256);
        int interior = (o0 >= b0) && (o1 <= b0 + 256);
        int idx = atomicAdd(&nseg, 1);
        slist[idx] = make_int4(d0, lo, hi, interior);
    }

    float b2v[2];
    #pragma unroll
    for (int t = 0; t < 2; ++t) b2v[t] = b2[(lane & 15) + 16 * t];

    AFrag af[4];
    #pragma unroll
    for (int g = 0; g < 4; ++g) {
        int E = wv * 64 + g * 16 + (lane & 15);
        int s = sed[E].x, dd = sed[E].y;
        uint4 Pq = *(const uint4*)&PA[(size_t)s * 32 + kg * 8];
        uint4 Qq = *(const uint4*)&QA[(size_t)dd * 32 + kg * 8];
        unsigned int pu[4] = {Pq.x, Pq.y, Pq.z, Pq.w};
        unsigned int qu[4] = {Qq.x, Qq.y, Qq.z, Qq.w};
        unsigned int outw[4];
        #pragma unroll
        for (int p = 0; p < 4; ++p) {
            float vlo = fmaxf(bflo(pu[p]) - bflo(qu[p]), 0.f);
            float vhi = fmaxf(bfhi(pu[p]) - bfhi(qu[p]), 0.f);
            outw[p] = cvtpk(vlo, vhi);
        }
        af[g].u = make_uint4(outw[0], outw[1], outw[2], outw[3]);
    }

    #pragma unroll
    for (int t = 0; t < 2; ++t) {
        bf16x8 bfr = *(const bf16x8*)&w2f[(t * 64 + lane) * 8];
        f32x4 acc[4];
        #pragma unroll
        for (int g = 0; g < 4; ++g) {
            f32x4 c = {b2v[t], b2v[t], b2v[t], b2v[t]};
            acc[g] = __builtin_amdgcn_mfma_f32_16x16x32_bf16(af[g].v, bfr, c, 0, 0, 0);
        }
        __syncthreads();
        #pragma unroll
        for (int g = 0; g < 4; ++g) {
            int eb = wv * 64 + g * 16 + (lane >> 4) * 4;
            #pragma unroll
            for (int r = 0; r < 4; ++r)
                sm[(eb + r) * 18 + (lane & 15)] = acc[g][r];
        }
        __syncthreads();
        int ns = nseg;
        int j = tid & 15;
        for (int si = tid >> 4; si < ns; si += 16) {
            int4 sg = slist[si];
            float v = sm[sg.y * 18 + j];
            for (int p = sg.y + 1; p < sg.z; ++p) v = fmaxf(v, sm[p * 18 + j]);
            float* addr = &accA[(size_t)sg.x * 32 + t * 16 + j];
            if (sg.w) *addr = v;
            else atomic_fmax(addr, v);
        }
    }
}

// ---------------- Layer B edges: hid = relu(P[s]-Q[d]); MFMA 16x16x32 x2K; seg-max ----------------
__global__ __launch_bounds__(256, 4) void edgeB(
        const unsigned short* __restrict__ PB, const unsigned short* __restrict__ QB,
        const int2* __restrict__ sedge, const int* __restrict__ off,
        const float* __restrict__ W2, const float* __restrict__ b2,
        float* __restrict__ accB) {
    __shared__ __align__(16) short w2f[2 * 4 * 64 * 8];
    __shared__ int2  sed[256];
    __shared__ float sm[256 * 18];
    __shared__ int4  slist[256];
    __shared__ int   nseg;

    const int tid = threadIdx.x;
    const int b0  = blockIdx.x * 256;
    const int lane = tid & 63, wv = tid >> 6;
    const int kg = (lane >> 4);

    #pragma unroll
    for (int ii = 0; ii < 16; ++ii) {
        int i = tid + ii * 256;
        int j = i & 7, ln = (i >> 3) & 63, t = (i >> 9) & 3, ks = (i >> 11) & 1;
        int k = ks * 32 + ((ln >> 4) & 3) * 8 + j, col = (ln & 15) + 16 * t;
        w2f[i] = (short)f2bf(W2[k * 64 + col]);
    }
    if (tid == 0) nseg = 0;
    sed[tid] = sedge[b0 + tid];
    __syncthreads();

    int d0 = sed[tid].y;
    bool flag = (tid == 0) || (sed[tid - 1].y != d0);
    if (flag) {
        int o0 = off[d0], o1 = off[d0 + 1];
        int lo = max(o0 - b0, 0);
        int hi = min(o1 - b0, 256);
        int interior = (o0 >= b0) && (o1 <= b0 + 256);
        int idx = atomicAdd(&nseg, 1);
        slist[idx] = make_int4(d0, lo, hi, interior);
    }

    float b2v[4];
    #pragma unroll
    for (int t = 0; t < 4; ++t) b2v[t] = b2[(lane & 15) + 16 * t];

    AFrag af[4][2];
    #pragma unroll
    for (int g = 0; g < 4; ++g) {
        int E = wv * 64 + g * 16 + (lane & 15);
        int s = sed[E].x, dd = sed[E].y;
        #pragma unroll
        for (int ks = 0; ks < 2; ++ks) {
            uint4 Pq = *(const uint4*)&PB[(size_t)s * 64 + ks * 32 + kg * 8];
            uint4 Qq = *(const uint4*)&QB[(size_t)dd * 64 + ks * 32 + kg * 8];
            unsigned int pu[4] = {Pq.x, Pq.y, Pq.z, Pq.w};
            unsigned int qu[4] = {Qq.x, Qq.y, Qq.z, Qq.w};
            unsigned int outw[4];
            #pragma unroll
            for (int p = 0; p < 4; ++p) {
                float vlo = fmaxf(bflo(pu[p]) - bflo(qu[p]), 0.f);
                float vhi = fmaxf(bfhi(pu[p]) - bfhi(qu[p]), 0.f);
                outw[p] = cvtpk(vlo, vhi);
            }
            af[g][ks].u = make_uint4(outw[0], outw[1], outw[2], outw[3]);
        }
    }

    #pragma unroll
    for (int t = 0; t < 4; ++t) {
        bf16x8 bf0 = *(const bf16x8*)&w2f[((0 * 4 + t) * 64 + lane) * 8];
        bf16x8 bf1 = *(const bf16x8*)&w2f[((1 * 4 + t) * 64 + lane) * 8];
        f32x4 acc[4];
        #pragma unroll
        for (int g = 0; g < 4; ++g) {
            f32x4 c = {b2v[t], b2v[t], b2v[t], b2v[t]};
            c = __builtin_amdgcn_mfma_f32_16x16x32_bf16(af[g][0].v, bf0, c, 0, 0, 0);
            acc[g] = __builtin_amdgcn_mfma_f32_16x16x32_bf16(af[g][1].v, bf1, c, 0, 0, 0);
        }
        __syncthreads();
        #pragma unroll
        for (int g = 0; g < 4; ++g) {
            int eb = wv * 64 + g * 16 + (lane >> 4) * 4;
            #pragma unroll
            for (int r = 0; r < 4; ++r)
                sm[(eb + r) * 18 + (lane & 15)] = acc[g][r];
        }
        __syncthreads();
        int ns = nseg;
        int j = tid & 15;
        for (int si = tid >> 4; si < ns; si += 16) {
            int4 sg = slist[si];
            float v = sm[sg.y * 18 + j];
            for (int p = sg.y + 1; p < sg.z; ++p) v = fmaxf(v, sm[p * 18 + j]);
            float* addr = &accB[(size_t)sg.x * 64 + t * 16 + j];
            if (sg.w) *addr = v;
            else atomic_fmax(addr, v);
        }
    }
}

// ---------------- BatchNorm stats layer A (deterministic two-stage) ----------------
template <int C>
__global__ __launch_bounds__(256) void bn_stats(const float* __restrict__ acc,
                                                float* __restrict__ partials) {
    const int total = NN * C;
    int tid = blockIdx.x * 256 + threadIdx.x;
    const int stride = gridDim.x * 256;
    float s = 0.f, q = 0.f;
    for (int i = tid; i < total; i += stride) {
        float v = acc[i];
        v = finitef(v) ? v : 0.f;
        s += v;
        q = fmaf(v, v, q);
    }
    __shared__ float ls[256], lq[256];
    ls[threadIdx.x] = s; lq[threadIdx.x] = q;
    __syncthreads();
    #pragma unroll
    for (int o = 128; o >= C; o >>= 1) {
        if (threadIdx.x < o) {
            ls[threadIdx.x] += ls[threadIdx.x + o];
            lq[threadIdx.x] += lq[threadIdx.x + o];
        }
        __syncthreads();
    }
    if (threadIdx.x < C) {
        partials[blockIdx.x * 2 * C + threadIdx.x]     = ls[threadIdx.x];
        partials[blockIdx.x * 2 * C + C + threadIdx.x] = lq[threadIdx.x];
    }
}

template <int C>
__global__ void bn_final(const float* __restrict__ partials, int nblocks,
                         const float* __restrict__ gamma, const float* __restrict__ beta,
                         float* __restrict__ ss) {
    int c = threadIdx.x;
    if (c >= C) return;
    float s = 0.f, q = 0.f;
    for (int b = 0; b < nblocks; ++b) {
        s += partials[b * 2 * C + c];
        q += partials[b * 2 * C + C + c];
    }
    float mu  = s / (float)NN;
    float var = fmaxf(q / (float)NN - mu * mu, 0.f);
    float inv = rsqrtf(var + 1e-5f);
    float sc  = gamma[c] * inv;
    ss[c]     = sc;
    ss[C + c] = fmaf(-mu, sc, beta[c]);
}

// ---------------- fused BN-stats(64) + graph raw max/-min pool ----------------
__global__ __launch_bounds__(256) void stats_pool(const float* __restrict__ X,
        const int* __restrict__ batch, float* __restrict__ partials,
        float* __restrict__ gmax, float* __restrict__ gneg) {
    int tid = threadIdx.x;
    int c = tid & 63, sub = tid >> 6;
    int base0 = blockIdx.x * 256;
    float s = 0.f, q = 0.f;
    float rmax = 0.f, rneg = 0.f; int curg = -1;
    for (int nn = sub; nn < 256; nn += 4) {
        int n = base0 + nn;
        if (n >= NN) break;
        float v = X[(size_t)n * 64 + c];
        v = finitef(v) ? v : 0.f;
        s += v; q = fmaf(v, v, q);
        int g = batch[n];
        if (g != curg) {
            if (curg >= 0) {
                atomic_fmax(&gmax[curg * 64 + c], rmax);
                atomic_fmax(&gneg[curg * 64 + c], rneg);
            }
            curg = g; rmax = v; rneg = -v;
        } else {
            rmax = fmaxf(rmax, v); rneg = fmaxf(rneg, -v);
        }
    }
    if (curg >= 0) {
        atomic_fmax(&gmax[curg * 64 + c], rmax);
        atomic_fmax(&gneg[curg * 64 + c], rneg);
    }
    __shared__ float ls[256], lq[256];
    ls[tid] = s; lq[tid] = q;
    __syncthreads();
    if (tid < 128) { ls[tid] += ls[tid + 128]; lq[tid] += lq[tid + 128]; }
    __syncthreads();
    if (tid < 64) {
        ls[tid] += ls[tid + 64]; lq[tid] += lq[tid + 64];
        partials[blockIdx.x * 128 + tid]      = ls[tid];
        partials[blockIdx.x * 128 + 64 + tid] = lq[tid];
    }
}

// ---------------- final: apply BN affine+relu to pooled extrema, then 64x64x2 GEMM ----------------
__global__ void final_gemm(const float* __restrict__ gmax, const float* __restrict__ gneg,
                           const float* __restrict__ ss, const float* __restrict__ Wc,
                           const float* __restrict__ bc, float* __restrict__ out) {
    int t = threadIdx.x;
    if (t >= NG * 2) return;
    int g = t >> 1, o = t & 1;
    float s = bc[o];
    for (int k = 0; k < 64; ++k) {
        float sc = ss[k], sh = ss[64 + k];
        float xm = gmax[g * 64 + k], xn = gneg[g * 64 + k];
        float x = (sc >= 0.f) ? xm : -xn;
        float v = finitef(x) ? fmaxf(fmaf(sc, x, sh), 0.f) : 0.f;   // empty graph -> 0
        s = fmaf(v, Wc[k * 2 + o], s);
    }
    out[t] = s;
}

extern "C" void kernel_launch(void* const* d_in, const int* in_sizes, int n_in,
                              void* d_out, int out_size, void* d_ws, size_t ws_size,
                              hipStream_t stream) {
    const float* pos   = (const float*)d_in[0];
    const int*   ei    = (const int*)d_in[1];
    const int*   batch = (const int*)d_in[2];
    const float* W1a = (const float*)d_in[3];
    const float* b1a = (const float*)d_in[4];
    const float* W2a = (const float*)d_in[5];
    const float* b2a = (const float*)d_in[6];
    const float* g1  = (const float*)d_in[7];
    const float* be1 = (const float*)d_in[8];
    const float* W1b = (const float*)d_in[9];
    const float* b1b = (const float*)d_in[10];
    const float* W2b = (const float*)d_in[11];
    const float* b2b = (const float*)d_in[12];
    const float* g2  = (const float*)d_in[13];
    const float* be2 = (const float*)d_in[14];
    const float* Wc  = (const float*)d_in[15];
    const float* bc  = (const float*)d_in[16];
    const int* srcp = ei;
    const int* dstp = ei + NE;

    char* base_p = (char*)d_ws;
    size_t ofs = 0;
    auto alloc = [&](size_t bytes) { char* p = base_p + ofs; ofs = (ofs + bytes + 255) & ~(size_t)255; return p; };
    int*   gmat  = (int*)alloc((size_t)NBLK1 * NBUK * 4);            // 1.22 MB
    int*   tot   = (int*)alloc(NBUK * 4);
    int*   bbase = (int*)alloc((NBUK + 1) * 4);
    int*   off   = (int*)alloc((size_t)(NN + 1) * 4);
    int2*  sedge = (int2*)alloc((size_t)NE * 8);                     // 12.8 MB
    int2*  stmp  = (int2*)alloc((size_t)NE * 8);                     // 12.8 MB, dead after p2sort
    unsigned short* PA = (unsigned short*)alloc((size_t)NN * 32 * 2);
    unsigned short* QA = (unsigned short*)alloc((size_t)NN * 32 * 2);
    unsigned short* PB = PA;                                          // spans PA+QA (12.8 MB)
    unsigned short* QB = (unsigned short*)stmp;                       // alias dead stmp (12.8 MB)
    float* X     = (float*)alloc((size_t)NN * 64 * 4);               // accA then accB
    float* partA = (float*)alloc(256 * 64 * 4);
    float* partB = (float*)alloc((size_t)NBLK1 * 128 * 4);
    float* ssA   = (float*)alloc(64 * 4);
    float* ssB   = (float*)alloc(128 * 4);
    float* gmax  = (float*)alloc(NG * 64 * 4);
    float* gneg  = (float*)alloc(NG * 64 * 4);

    const int EB = NE / 256;   // 6250, exact

    hipMemsetAsync(X, 0xFF, (size_t)NN * 32 * 4, stream);   // accA NaN-init

    // CSR build (atomic-free bucket sort); also inits gmax/gneg and off[NN]
    p1count<<<NBLK1, 256, 0, stream>>>(dstp, gmat);
    scanA<<<NBUK, 512, 0, stream>>>(gmat, tot);
    scanB<<<1, 1024, 0, stream>>>(tot, bbase, off, (unsigned int*)gmax, (unsigned int*)gneg);
    p1scatter<<<NBLK1, 256, 0, stream>>>(srcp, dstp, gmat, bbase, stmp);
    p2sort<<<NBUK, 256, 0, stream>>>(stmp, bbase, sedge, off);

    // Layer A
    uA_kernel<<<(NN + 255) / 256, 256, 0, stream>>>(pos, W1a, b1a, PA, QA);
    edgeA<<<EB, 256, 0, stream>>>(PA, QA, sedge, off, W2a, b2a, X);
    bn_stats<32><<<256, 256, 0, stream>>>(X, partA);
    bn_final<32><<<1, 32, 0, stream>>>(partA, 256, g1, be1, ssA);

    // Layer B (uB consumes stmp region as QB only after p2sort is done with it)
    uB_kernel<<<(NN + 255) / 256, 256, 0, stream>>>(X, ssA, pos, W1b, b1b, PB, QB);
    hipMemsetAsync(X, 0xFF, (size_t)NN * 64 * 4, stream);   // accB NaN-init
    edgeB<<<EB, 256, 0, stream>>>(PB, QB, sedge, off, W2b, b2b, X);
    stats_pool<<<(NN + 255) / 256, 256, 0, stream>>>(X, batch, partB, gmax, gneg);
    bn_final<64><<<1, 64, 0, stream>>>(partB, NBLK1, g2, be2, ssB);
    final_gemm<<<1, 128, 0, stream>>>(gmax, gneg, ssB, Wc, bc, (float*)d_out);
}

// Round 7
// 410.119 us; speedup vs baseline: 15.6203x; 1.1099x over previous
//
#include <hip/hip_runtime.h>

#define NN 100000
#define NE 1600000
#define NG 64
#define NBUK 782          // dst>>7 buckets (128 nodes each)
#define NBLK1 391         // ceil(NE/4096)
#define EPB 4096          // edges per pass-1 block
#define CAP2 4096         // pass-2 LDS edge capacity

typedef __attribute__((ext_vector_type(8))) short bf16x8;
typedef __attribute__((ext_vector_type(4))) float f32x4;

union AFrag { bf16x8 v; uint4 u; };

__device__ __forceinline__ bool finitef(float v) {
    return (__float_as_uint(v) & 0x7F800000u) != 0x7F800000u;
}
__device__ __forceinline__ unsigned short f2bf(float f) {   // RNE, cold paths only
    unsigned int u = __float_as_uint(f);
    u += 0x7fffu + ((u >> 16) & 1u);
    return (unsigned short)(u >> 16);
}
__device__ __forceinline__ unsigned int cvtpk(float lo, float hi) {
    unsigned int r;
    asm("v_cvt_pk_bf16_f32 %0, %1, %2" : "=v"(r) : "v"(lo), "v"(hi));
    return r;
}
__device__ __forceinline__ float bflo(unsigned int q) { return __uint_as_float(q << 16); }
__device__ __forceinline__ float bfhi(unsigned int q) { return __uint_as_float(q & 0xffff0000u); }

// Order-preserving float<->uint bijection: max(float) == atomicMax(uint), identity = 0.
// dec(0) = NaN (no-edge marker), handled downstream by finitef -> 0.
__device__ __forceinline__ unsigned int enc(float f) {
    unsigned int u = __float_as_uint(f);
    return (u & 0x80000000u) ? ~u : (u | 0x80000000u);
}
__device__ __forceinline__ float dec(unsigned int k) {
    unsigned int u = (k & 0x80000000u) ? (k ^ 0x80000000u) : ~k;
    return __uint_as_float(u);
}

// ---------------- CSR build: atomic-free bucket sort ----------------
__global__ __launch_bounds__(256) void p1count(const int* __restrict__ dst,
                                               int* __restrict__ gmat) {
    __shared__ int h[NBUK];
    int tid = threadIdx.x;
    for (int i = tid; i < NBUK; i += 256) h[i] = 0;
    __syncthreads();
    int e0 = blockIdx.x * EPB;
    #pragma unroll
    for (int i = 0; i < 16; ++i) {
        int e = e0 + tid + i * 256;
        if (e < NE) atomicAdd(&h[dst[e] >> 7], 1);
    }
    __syncthreads();
    for (int i = tid; i < NBUK; i += 256) gmat[blockIdx.x * NBUK + i] = h[i];
}

__global__ __launch_bounds__(512) void scanA(int* __restrict__ gmat, int* __restrict__ tot) {
    __shared__ int ls[512];
    int b = blockIdx.x, tid = threadIdx.x;
    int v = (tid < NBLK1) ? gmat[tid * NBUK + b] : 0;
    ls[tid] = v;
    __syncthreads();
    for (int o = 1; o < 512; o <<= 1) {
        int t = (tid >= o) ? ls[tid - o] : 0;
        __syncthreads();
        ls[tid] += t;
        __syncthreads();
    }
    if (tid < NBLK1) gmat[tid * NBUK + b] = ls[tid] - v;   // exclusive over blocks
    if (tid == 511) tot[b] = ls[511];
}

__global__ __launch_bounds__(1024) void scanB(const int* __restrict__ tot,
        int* __restrict__ base, int* __restrict__ off,
        unsigned int* __restrict__ gmax, unsigned int* __restrict__ gneg) {
    __shared__ int ls[1024];
    int tid = threadIdx.x;
    int v = (tid < NBUK) ? tot[tid] : 0;
    ls[tid] = v;
    __syncthreads();
    for (int o = 1; o < 1024; o <<= 1) {
        int t = (tid >= o) ? ls[tid - o] : 0;
        __syncthreads();
        ls[tid] += t;
        __syncthreads();
    }
    if (tid < NBUK) base[tid] = ls[tid] - v;
    if (tid == 1023) { base[NBUK] = ls[1023]; off[NN] = NE; }
    for (int i = tid; i < NG * 64; i += 1024) { gmax[i] = 0u; gneg[i] = 0u; }
}

__global__ __launch_bounds__(256) void p1scatter(const int* __restrict__ src,
        const int* __restrict__ dst, const int* __restrict__ gmat,
        const int* __restrict__ base, int2* __restrict__ tmp) {
    __shared__ int cur[NBUK];
    int tid = threadIdx.x;
    for (int i = tid; i < NBUK; i += 256) cur[i] = base[i] + gmat[blockIdx.x * NBUK + i];
    __syncthreads();
    int e0 = blockIdx.x * EPB;
    #pragma unroll
    for (int i = 0; i < 16; ++i) {
        int e = e0 + tid + i * 256;
        if (e < NE) {
            int d = dst[e];
            int p = atomicAdd(&cur[d >> 7], 1);
            tmp[p] = make_int2(src[e], d);
        }
    }
}

__global__ __launch_bounds__(256) void p2sort(const int2* __restrict__ tmp,
        const int* __restrict__ base, int2* __restrict__ sedge, int* __restrict__ off) {
    __shared__ int2 earr[CAP2];
    __shared__ int nh[128], np[128], ncur[128];
    int b = blockIdx.x, tid = threadIdx.x;
    int bs = base[b], be = base[b + 1];
    int cnt = min(be - bs, CAP2);
    int nb0 = b << 7;
    if (tid < 128) nh[tid] = 0;
    __syncthreads();
    for (int i = tid; i < cnt; i += 256) {
        int2 ed = tmp[bs + i];
        earr[i] = ed;
        atomicAdd(&nh[ed.y - nb0], 1);
    }
    __syncthreads();
    if (tid < 128) np[tid] = nh[tid];
    __syncthreads();
    for (int o = 1; o < 128; o <<= 1) {
        int t = 0;
        if (tid < 128 && tid >= o) t = np[tid - o];
        __syncthreads();
        if (tid < 128) np[tid] += t;
        __syncthreads();
    }
    if (tid < 128) {
        int ex = np[tid] - nh[tid];
        ncur[tid] = ex;
        int n = nb0 + tid;
        if (n < NN) off[n] = bs + ex;
    }
    __syncthreads();
    for (int i = tid; i < cnt; i += 256) {
        int2 ed = earr[i];
        int p = atomicAdd(&ncur[ed.y - nb0], 1);
        sedge[bs + p] = ed;
    }
}

// ---------------- layer A node tables: P = pos@(W1h+W1t)+b1, Q = pos@W1t (bf16) ----------------
__global__ __launch_bounds__(256) void uA_kernel(const float* __restrict__ pos,
        const float* __restrict__ W1, const float* __restrict__ b1,
        unsigned short* __restrict__ PA, unsigned short* __restrict__ QA) {
    __shared__ float sWp[96], sWq[96], sb[32];
    if (threadIdx.x < 96) {
        float wt = W1[96 + threadIdx.x];
        sWq[threadIdx.x] = wt;
        sWp[threadIdx.x] = W1[threadIdx.x] + wt;
    }
    if (threadIdx.x < 32) sb[threadIdx.x] = b1[threadIdx.x];
    __syncthreads();
    int n = blockIdx.x * 256 + threadIdx.x;
    if (n >= NN) return;
    float p0 = pos[n * 3 + 0], p1 = pos[n * 3 + 1], p2 = pos[n * 3 + 2];
    float P[32], Q[32];
    #pragma unroll
    for (int c = 0; c < 32; ++c) {
        P[c] = fmaf(p2, sWp[64 + c], fmaf(p1, sWp[32 + c], fmaf(p0, sWp[c], sb[c])));
        Q[c] = fmaf(p2, sWq[64 + c], fmaf(p1, sWq[32 + c], p0 * sWq[c]));
    }
    uint4* po = (uint4*)(PA + (size_t)n * 32);
    uint4* qo = (uint4*)(QA + (size_t)n * 32);
    #pragma unroll
    for (int q = 0; q < 4; ++q) {
        po[q] = make_uint4(cvtpk(P[8*q],P[8*q+1]), cvtpk(P[8*q+2],P[8*q+3]),
                           cvtpk(P[8*q+4],P[8*q+5]), cvtpk(P[8*q+6],P[8*q+7]));
        qo[q] = make_uint4(cvtpk(Q[8*q],Q[8*q+1]), cvtpk(Q[8*q+2],Q[8*q+3]),
                           cvtpk(Q[8*q+4],Q[8*q+5]), cvtpk(Q[8*q+6],Q[8*q+7]));
    }
}

// ---------------- layer B node tables (BN+ReLU fused in; accA is encoded uints) ----------------
__global__ __launch_bounds__(256) void uB_kernel(const unsigned int* __restrict__ accA,
        const float* __restrict__ ssA, const float* __restrict__ pos,
        const float* __restrict__ W1, const float* __restrict__ b1,
        unsigned short* __restrict__ PB, unsigned short* __restrict__ QB) {
    __shared__ float sW[32 * 64];
    __shared__ float sWt[3 * 64];
    __shared__ float sb[64];
    for (int i = threadIdx.x; i < 32 * 64; i += 256) sW[i] = W1[i];
    if (threadIdx.x < 192) sWt[threadIdx.x] = W1[32 * 64 + threadIdx.x];
    if (threadIdx.x < 64) sb[threadIdx.x] = b1[threadIdx.x];
    __syncthreads();
    int n = blockIdx.x * 256 + threadIdx.x;
    if (n >= NN) return;
    float h[32];
    const uint4* a4 = (const uint4*)(accA + (size_t)n * 32);
    #pragma unroll
    for (int q = 0; q < 8; ++q) {
        uint4 v = a4[q];
        unsigned int vv[4] = {v.x, v.y, v.z, v.w};
        #pragma unroll
        for (int r = 0; r < 4; ++r) {
            int c = 4 * q + r;
            float x = dec(vv[r]);
            x = finitef(x) ? x : 0.f;
            h[c] = fmaxf(fmaf(x, ssA[c], ssA[32 + c]), 0.f);
        }
    }
    float p0 = pos[n * 3 + 0], p1 = pos[n * 3 + 1], p2 = pos[n * 3 + 2];
    float Q[64], P[64];
    #pragma unroll
    for (int c = 0; c < 64; ++c) {
        Q[c] = fmaf(p2, sWt[128 + c], fmaf(p1, sWt[64 + c], p0 * sWt[c]));
        P[c] = Q[c] + sb[c];
    }
    #pragma unroll
    for (int k = 0; k < 32; ++k) {
        float x = h[k];
        #pragma unroll
        for (int c = 0; c < 64; ++c) P[c] = fmaf(x, sW[k * 64 + c], P[c]);
    }
    uint4* po = (uint4*)(PB + (size_t)n * 64);
    uint4* qo = (uint4*)(QB + (size_t)n * 64);
    #pragma unroll
    for (int q = 0; q < 8; ++q) {
        po[q] = make_uint4(cvtpk(P[8*q],P[8*q+1]), cvtpk(P[8*q+2],P[8*q+3]),
                           cvtpk(P[8*q+4],P[8*q+5]), cvtpk(P[8*q+6],P[8*q+7]));
        qo[q] = make_uint4(cvtpk(Q[8*q],Q[8*q+1]), cvtpk(Q[8*q+2],Q[8*q+3]),
                           cvtpk(Q[8*q+4],Q[8*q+5]), cvtpk(Q[8*q+6],Q[8*q+7]));
    }
}

// ---------------- Layer A edges: MFMA + register quad-max + LDS-atomic seg-max ----------------
__global__ __launch_bounds__(256, 4) void edgeA(
        const unsigned short* __restrict__ PA, const unsigned short* __restrict__ QA,
        const int2* __restrict__ sedge, const int* __restrict__ off,
        const float* __restrict__ W2, const float* __restrict__ b2,
        unsigned int* __restrict__ accA) {
    __shared__ __align__(16) short w2f[2 * 64 * 8];
    __shared__ int2   sed[256];
    __shared__ uchar4 srow4[64];
    __shared__ int    slist[256];
    __shared__ unsigned int nm[64 * 32];
    __shared__ int    wsum[4];

    const int tid = threadIdx.x;
    const int b0  = blockIdx.x * 256;
    const int lane = tid & 63, wv = tid >> 6;
    const int kg = (lane >> 4);
    unsigned char* srow = (unsigned char*)srow4;

    #pragma unroll
    for (int ii = 0; ii < 4; ++ii) {
        int i = tid + ii * 256;
        int j = i & 7, ln = (i >> 3) & 63, t = (i >> 9) & 1;
        int k = ((ln >> 4) & 3) * 8 + j, col = (ln & 15) + 16 * t;
        w2f[i] = (short)f2bf(W2[k * 32 + col]);
    }
    sed[tid] = sedge[b0 + tid];
    __syncthreads();

    int d0 = sed[tid].y;
    bool flag = (tid == 0) || (sed[tid - 1].y != d0);
    unsigned long long mb = __ballot(flag);
    if (lane == 0) wsum[wv] = __popcll(mb);
    int incl = __popcll(mb & ((~0ull) >> (63 - lane)));
    __syncthreads();
    int w0 = wsum[0], w1 = wsum[1], w2s = wsum[2], w3 = wsum[3];
    int pre = (wv > 0 ? w0 : 0) + (wv > 1 ? w1 : 0) + (wv > 2 ? w2s : 0);
    int nseg = w0 + w1 + w2s + w3;
    int seg = pre + incl - 1;
    srow[tid] = (unsigned char)seg;
    if (flag) {
        int o0 = off[d0], o1 = off[d0 + 1];
        int interior = (o0 >= b0) && (o1 <= b0 + 256);
        slist[seg] = d0 | (interior ? (int)0x80000000 : 0);
    }
    int zc = min(nseg, 64) * 32;
    for (int i = tid; i < zc; i += 256) nm[i] = 0;
    __syncthreads();

    float b2v[2];
    #pragma unroll
    for (int t = 0; t < 2; ++t) b2v[t] = b2[(lane & 15) + 16 * t];

    AFrag af[4];
    #pragma unroll
    for (int g = 0; g < 4; ++g) {
        int E = wv * 64 + g * 16 + (lane & 15);
        int s = sed[E].x, dd = sed[E].y;
        uint4 Pq = *(const uint4*)&PA[(size_t)s * 32 + kg * 8];
        uint4 Qq = *(const uint4*)&QA[(size_t)dd * 32 + kg * 8];
        unsigned int pu[4] = {Pq.x, Pq.y, Pq.z, Pq.w};
        unsigned int qu[4] = {Qq.x, Qq.y, Qq.z, Qq.w};
        unsigned int outw[4];
        #pragma unroll
        for (int p = 0; p < 4; ++p) {
            float vlo = fmaxf(bflo(pu[p]) - bflo(qu[p]), 0.f);
            float vhi = fmaxf(bfhi(pu[p]) - bfhi(qu[p]), 0.f);
            outw[p] = cvtpk(vlo, vhi);
        }
        af[g].u = make_uint4(outw[0], outw[1], outw[2], outw[3]);
    }

    #pragma unroll
    for (int t = 0; t < 2; ++t) {
        bf16x8 bfr = *(const bf16x8*)&w2f[(t * 64 + lane) * 8];
        f32x4 acc[4];
        #pragma unroll
        for (int g = 0; g < 4; ++g) {
            f32x4 c = {b2v[t], b2v[t], b2v[t], b2v[t]};
            acc[g] = __builtin_amdgcn_mfma_f32_16x16x32_bf16(af[g].v, bfr, c, 0, 0, 0);
        }
        int ch = t * 16 + (lane & 15);
        #pragma unroll
        for (int g = 0; g < 4; ++g) {
            int eb = wv * 64 + g * 16 + kg * 4;
            uchar4 s4 = srow4[eb >> 2];
            unsigned char ss[4] = {s4.x, s4.y, s4.z, s4.w};
            if (ss[0] == ss[3]) {
                float m = fmaxf(fmaxf(acc[g][0], acc[g][1]), fmaxf(acc[g][2], acc[g][3]));
                unsigned int k = enc(m);
                if (ss[0] < 64) atomicMax(&nm[(int)ss[0] * 32 + ch], k);
                else atomicMax(&accA[(size_t)(slist[ss[0]] & 0x7fffffff) * 32 + ch], k);
            } else {
                #pragma unroll
                for (int r = 0; r < 4; ++r) {
                    unsigned int k = enc(acc[g][r]);
                    if (ss[r] < 64) atomicMax(&nm[(int)ss[r] * 32 + ch], k);
                    else atomicMax(&accA[(size_t)(slist[ss[r]] & 0x7fffffff) * 32 + ch], k);
                }
            }
        }
    }

    __syncthreads();
    int tot = min(nseg, 64) * 32;
    for (int i = tid; i < tot; i += 256) {
        int si = i >> 5, c = i & 31;
        unsigned int k = nm[i];
        int nd = slist[si];
        unsigned int* addr = &accA[(size_t)(nd & 0x7fffffff) * 32 + c];
        if (nd < 0) *addr = k;          // interior: exclusive owner, plain store
        else atomicMax(addr, k);        // boundary: merge across blocks
    }
}

// ---------------- Layer B edges: same structure, 64 channels, K=64 ----------------
__global__ __launch_bounds__(256, 4) void edgeB(
        const unsigned short* __restrict__ PB, const unsigned short* __restrict__ QB,
        const int2* __restrict__ sedge, const int* __restrict__ off,
        const float* __restrict__ W2, const float* __restrict__ b2,
        unsigned int* __restrict__ accB) {
    __shared__ __align__(16) short w2f[2 * 4 * 64 * 8];
    __shared__ int2   sed[256];
    __shared__ uchar4 srow4[64];
    __shared__ int    slist[256];
    __shared__ unsigned int nm[64 * 64];
    __shared__ int    wsum[4];

    const int tid = threadIdx.x;
    const int b0  = blockIdx.x * 256;
    const int lane = tid & 63, wv = tid >> 6;
    const int kg = (lane >> 4);
    unsigned char* srow = (unsigned char*)srow4;

    #pragma unroll
    for (int ii = 0; ii < 16; ++ii) {
        int i = tid + ii * 256;
        int j = i & 7, ln = (i >> 3) & 63, t = (i >> 9) & 3, ks = (i >> 11) & 1;
        int k = ks * 32 + ((ln >> 4) & 3) * 8 + j, col = (ln & 15) + 16 * t;
        w2f[i] = (short)f2bf(W2[k * 64 + col]);
    }
    sed[tid] = sedge[b0 + tid];
    __syncthreads();

    int d0 = sed[tid].y;
    bool flag = (tid == 0) || (sed[tid - 1].y != d0);
    unsigned long long mb = __ballot(flag);
    if (lane == 0) wsum[wv] = __popcll(mb);
    int incl = __popcll(mb & ((~0ull) >> (63 - lane)));
    __syncthreads();
    int w0 = wsum[0], w1 = wsum[1], w2s = wsum[2], w3 = wsum[3];
    int pre = (wv > 0 ? w0 : 0) + (wv > 1 ? w1 : 0) + (wv > 2 ? w2s : 0);
    int nseg = w0 + w1 + w2s + w3;
    int seg = pre + incl - 1;
    srow[tid] = (unsigned char)seg;
    if (flag) {
        int o0 = off[d0], o1 = off[d0 + 1];
        int interior = (o0 >= b0) && (o1 <= b0 + 256);
        slist[seg] = d0 | (interior ? (int)0x80000000 : 0);
    }
    int zc = min(nseg, 64) * 64;
    for (int i = tid; i < zc; i += 256) nm[i] = 0;
    __syncthreads();

    float b2v[4];
    #pragma unroll
    for (int t = 0; t < 4; ++t) b2v[t] = b2[(lane & 15) + 16 * t];

    AFrag af[4][2];
    #pragma unroll
    for (int g = 0; g < 4; ++g) {
        int E = wv * 64 + g * 16 + (lane & 15);
        int s = sed[E].x, dd = sed[E].y;
        #pragma unroll
        for (int ks = 0; ks < 2; ++ks) {
            uint4 Pq = *(const uint4*)&PB[(size_t)s * 64 + ks * 32 + kg * 8];
            uint4 Qq = *(const uint4*)&QB[(size_t)dd * 64 + ks * 32 + kg * 8];
            unsigned int pu[4] = {Pq.x, Pq.y, Pq.z, Pq.w};
            unsigned int qu[4] = {Qq.x, Qq.y, Qq.z, Qq.w};
            unsigned int outw[4];
            #pragma unroll
            for (int p = 0; p < 4; ++p) {
                float vlo = fmaxf(bflo(pu[p]) - bflo(qu[p]), 0.f);
                float vhi = fmaxf(bfhi(pu[p]) - bfhi(qu[p]), 0.f);
                outw[p] = cvtpk(vlo, vhi);
            }
            af[g][ks].u = make_uint4(outw[0], outw[1], outw[2], outw[3]);
        }
    }

    #pragma unroll
    for (int t = 0; t < 4; ++t) {
        bf16x8 bf0 = *(const bf16x8*)&w2f[((0 * 4 + t) * 64 + lane) * 8];
        bf16x8 bf1 = *(const bf16x8*)&w2f[((1 * 4 + t) * 64 + lane) * 8];
        f32x4 acc[4];
        #pragma unroll
        for (int g = 0; g < 4; ++g) {
            f32x4 c = {b2v[t], b2v[t], b2v[t], b2v[t]};
            c = __builtin_amdgcn_mfma_f32_16x16x32_bf16(af[g][0].v, bf0, c, 0, 0, 0);
            acc[g] = __builtin_amdgcn_mfma_f32_16x16x32_bf16(af[g][1].v, bf1, c, 0, 0, 0);
        }
        int ch = t * 16 + (lane & 15);
        #pragma unroll
        for (int g = 0; g < 4; ++g) {
            int eb = wv * 64 + g * 16 + kg * 4;
            uchar4 s4 = srow4[eb >> 2];
            unsigned char ss[4] = {s4.x, s4.y, s4.z, s4.w};
            if (ss[0] == ss[3]) {
                float m = fmaxf(fmaxf(acc[g][0], acc[g][1]), fmaxf(acc[g][2], acc[g][3]));
                unsigned int k = enc(m);
                if (ss[0] < 64) atomicMax(&nm[(int)ss[0] * 64 + ch], k);
                else atomicMax(&accB[(size_t)(slist[ss[0]] & 0x7fffffff) * 64 + ch], k);
            } else {
                #pragma unroll
                for (int r = 0; r < 4; ++r) {
                    unsigned int k = enc(acc[g][r]);
                    if (ss[r] < 64) atomicMax(&nm[(int)ss[r] * 64 + ch], k);
                    else atomicMax(&accB[(size_t)(slist[ss[r]] & 0x7fffffff) * 64 + ch], k);
                }
            }
        }
    }

    __syncthreads();
    int tot = min(nseg, 64) * 64;
    for (int i = tid; i < tot; i += 256) {
        int si = i >> 6, c = i & 63;
        unsigned int k = nm[i];
        int nd = slist[si];
        unsigned int* addr = &accB[(size_t)(nd & 0x7fffffff) * 64 + c];
        if (nd < 0) *addr = k;
        else atomicMax(addr, k);
    }
}

// ---------------- BatchNorm stats layer A (reads encoded accA) ----------------
template <int C>
__global__ __launch_bounds__(256) void bn_stats(const unsigned int* __restrict__ acc,
                                                float* __restrict__ partials) {
    const int total = NN * C;
    int tid = blockIdx.x * 256 + threadIdx.x;
    const int stride = gridDim.x * 256;
    float s = 0.f, q = 0.f;
    for (int i = tid; i < total; i += stride) {
        float v = dec(acc[i]);
        v = finitef(v) ? v : 0.f;
        s += v;
        q = fmaf(v, v, q);
    }
    __shared__ float ls[256], lq[256];
    ls[threadIdx.x] = s; lq[threadIdx.x] = q;
    __syncthreads();
    #pragma unroll
    for (int o = 128; o >= C; o >>= 1) {
        if (threadIdx.x < o) {
            ls[threadIdx.x] += ls[threadIdx.x + o];
            lq[threadIdx.x] += lq[threadIdx.x + o];
        }
        __syncthreads();
    }
    if (threadIdx.x < C) {
        partials[blockIdx.x * 2 * C + threadIdx.x]     = ls[threadIdx.x];
        partials[blockIdx.x * 2 * C + C + threadIdx.x] = lq[threadIdx.x];
    }
}

template <int C>
__global__ void bn_final(const float* __restrict__ partials, int nblocks,
                         const float* __restrict__ gamma, const float* __restrict__ beta,
                         float* __restrict__ ss) {
    int c = threadIdx.x;
    if (c >= C) return;
    float s = 0.f, q = 0.f;
    for (int b = 0; b < nblocks; ++b) {
        s += partials[b * 2 * C + c];
        q += partials[b * 2 * C + C + c];
    }
    float mu  = s / (float)NN;
    float var = fmaxf(q / (float)NN - mu * mu, 0.f);
    float inv = rsqrtf(var + 1e-5f);
    float sc  = gamma[c] * inv;
    ss[c]     = sc;
    ss[C + c] = fmaf(-mu, sc, beta[c]);
}

// ---------------- fused BN-stats(64) + graph raw max/-min pool (encoded in/out) ----------------
__global__ __launch_bounds__(256) void stats_pool(const unsigned int* __restrict__ X,
        const int* __restrict__ batch, float* __restrict__ partials,
        unsigned int* __restrict__ gmax, unsigned int* __restrict__ gneg) {
    int tid = threadIdx.x;
    int c = tid & 63, sub = tid >> 6;
    int base0 = blockIdx.x * 256;
    float s = 0.f, q = 0.f;
    float rmax = 0.f, rneg = 0.f; int curg = -1;
    for (int nn = sub; nn < 256; nn += 4) {
        int n = base0 + nn;
        if (n >= NN) break;
        float v = dec(X[(size_t)n * 64 + c]);
        v = finitef(v) ? v : 0.f;
        s += v; q = fmaf(v, v, q);
        int g = batch[n];
        if (g != curg) {
            if (curg >= 0) {
                atomicMax(&gmax[curg * 64 + c], enc(rmax));
                atomicMax(&gneg[curg * 64 + c], enc(rneg));
            }
            curg = g; rmax = v; rneg = -v;
        } else {
            rmax = fmaxf(rmax, v); rneg = fmaxf(rneg, -v);
        }
    }
    if (curg >= 0) {
        atomicMax(&gmax[curg * 64 + c], enc(rmax));
        atomicMax(&gneg[curg * 64 + c], enc(rneg));
    }
    __shared__ float ls[256], lq[256];
    ls[tid] = s; lq[tid] = q;
    __syncthreads();
    if (tid < 128) { ls[tid] += ls[tid + 128]; lq[tid] += lq[tid + 128]; }
    __syncthreads();
    if (tid < 64) {
        ls[tid] += ls[tid + 64]; lq[tid] += lq[tid + 64];
        partials[blockIdx.x * 128 + tid]      = ls[tid];
        partials[blockIdx.x * 128 + 64 + tid] = lq[tid];
    }
}

// ---------------- final: BN affine+relu on pooled extrema, then 64x64x2 GEMM ----------------
__global__ void final_gemm(const unsigned int* __restrict__ gmax,
                           const unsigned int* __restrict__ gneg,
                           const float* __restrict__ ss, const float* __restrict__ Wc,
                           const float* __restrict__ bc, float* __restrict__ out) {
    int t = threadIdx.x;
    if (t >= NG * 2) return;
    int g = t >> 1, o = t & 1;
    float s = bc[o];
    for (int k = 0; k < 64; ++k) {
        float sc = ss[k], sh = ss[64 + k];
        float xm = dec(gmax[g * 64 + k]), xn = dec(gneg[g * 64 + k]);
        float x = (sc >= 0.f) ? xm : -xn;
        float v = finitef(x) ? fmaxf(fmaf(sc, x, sh), 0.f) : 0.f;   // empty graph -> 0
        s = fmaf(v, Wc[k * 2 + o], s);
    }
    out[t] = s;
}

extern "C" void kernel_launch(void* const* d_in, const int* in_sizes, int n_in,
                              void* d_out, int out_size, void* d_ws, size_t ws_size,
                              hipStream_t stream) {
    const float* pos   = (const float*)d_in[0];
    const int*   ei    = (const int*)d_in[1];
    const int*   batch = (const int*)d_in[2];
    const float* W1a = (const float*)d_in[3];
    const float* b1a = (const float*)d_in[4];
    const float* W2a = (const float*)d_in[5];
    const float* b2a = (const float*)d_in[6];
    const float* g1  = (const float*)d_in[7];
    const float* be1 = (const float*)d_in[8];
    const float* W1b = (const float*)d_in[9];
    const float* b1b = (const float*)d_in[10];
    const float* W2b = (const float*)d_in[11];
    const float* b2b = (const float*)d_in[12];
    const float* g2  = (const float*)d_in[13];
    const float* be2 = (const float*)d_in[14];
    const float* Wc  = (const float*)d_in[15];
    const float* bc  = (const float*)d_in[16];
    const int* srcp = ei;
    const int* dstp = ei + NE;

    char* base_p = (char*)d_ws;
    size_t ofs = 0;
    auto alloc = [&](size_t bytes) { char* p = base_p + ofs; ofs = (ofs + bytes + 255) & ~(size_t)255; return p; };
    int*   gmat  = (int*)alloc((size_t)NBLK1 * NBUK * 4);
    int*   tot   = (int*)alloc(NBUK * 4);
    int*   bbase = (int*)alloc((NBUK + 1) * 4);
    int*   off   = (int*)alloc((size_t)(NN + 1) * 4);
    int2*  sedge = (int2*)alloc((size_t)NE * 8);
    int2*  stmp  = (int2*)alloc((size_t)NE * 8);                     // dead after p2sort
    unsigned short* PA = (unsigned short*)alloc((size_t)NN * 32 * 2);
    unsigned short* QA = (unsigned short*)alloc((size_t)NN * 32 * 2);
    unsigned short* PB = PA;                                          // spans PA+QA
    unsigned short* QB = (unsigned short*)stmp;                       // aliases dead stmp
    unsigned int* X   = (unsigned int*)alloc((size_t)NN * 64 * 4);   // encoded accA then accB
    float* partA = (float*)alloc(256 * 64 * 4);
    float* partB = (float*)alloc((size_t)NBLK1 * 128 * 4);
    float* ssA   = (float*)alloc(64 * 4);
    float* ssB   = (float*)alloc(128 * 4);
    unsigned int* gmax = (unsigned int*)alloc(NG * 64 * 4);
    unsigned int* gneg = (unsigned int*)alloc(NG * 64 * 4);

    const int EB = NE / 256;   // 6250, exact

    hipMemsetAsync(X, 0x00, (size_t)NN * 32 * 4, stream);   // accA identity (enc: 0 = -inf)

    // CSR build (atomic-free bucket sort); also inits gmax/gneg and off[NN]
    p1count<<<NBLK1, 256, 0, stream>>>(dstp, gmat);
    scanA<<<NBUK, 512, 0, stream>>>(gmat, tot);
    scanB<<<1, 1024, 0, stream>>>(tot, bbase, off, gmax, gneg);
    p1scatter<<<NBLK1, 256, 0, stream>>>(srcp, dstp, gmat, bbase, stmp);
    p2sort<<<NBUK, 256, 0, stream>>>(stmp, bbase, sedge, off);

    // Layer A
    uA_kernel<<<(NN + 255) / 256, 256, 0, stream>>>(pos, W1a, b1a, PA, QA);
    edgeA<<<EB, 256, 0, stream>>>(PA, QA, sedge, off, W2a, b2a, X);
    bn_stats<32><<<256, 256, 0, stream>>>(X, partA);
    bn_final<32><<<1, 32, 0, stream>>>(partA, 256, g1, be1, ssA);

    // Layer B
    uB_kernel<<<(NN + 255) / 256, 256, 0, stream>>>(X, ssA, pos, W1b, b1b, PB, QB);
    hipMemsetAsync(X, 0x00, (size_t)NN * 64 * 4, stream);   // accB identity
    edgeB<<<EB, 256, 0, stream>>>(PB, QB, sedge, off, W2b, b2b, X);
    stats_pool<<<(NN + 255) / 256, 256, 0, stream>>>(X, batch, partB, gmax, gneg);
    bn_final<64><<<1, 64, 0, stream>>>(partB, NBLK1, g2, be2, ssB);
    final_gemm<<<1, 128, 0, stream>>>(gmax, gneg, ssB, Wc, bc, (float*)d_out);
}

// Round 8
// 262.666 us; speedup vs baseline: 24.3890x; 1.5614x over previous
//
#include <hip/hip_runtime.h>

#define NN 100000
#define NE 1600000
#define NG 64
#define NBUK 782          // dst>>7 buckets (128 nodes each)
#define NBLK1 391         // ceil(NE/4096)
#define EPB 4096          // edges per pass-1 block
#define CAP2 4096         // pass-2 LDS edge capacity

typedef __attribute__((ext_vector_type(8))) short bf16x8;
typedef __attribute__((ext_vector_type(4))) float f32x4;

union AFrag { bf16x8 v; uint4 u; };

__device__ __forceinline__ bool finitef(float v) {
    return (__float_as_uint(v) & 0x7F800000u) != 0x7F800000u;
}
__device__ __forceinline__ unsigned short f2bf(float f) {   // RNE, cold paths only
    unsigned int u = __float_as_uint(f);
    u += 0x7fffu + ((u >> 16) & 1u);
    return (unsigned short)(u >> 16);
}
__device__ __forceinline__ unsigned int cvtpk(float lo, float hi) {
    unsigned int r;
    asm("v_cvt_pk_bf16_f32 %0, %1, %2" : "=v"(r) : "v"(lo), "v"(hi));
    return r;
}
__device__ __forceinline__ float bflo(unsigned int q) { return __uint_as_float(q << 16); }
__device__ __forceinline__ float bfhi(unsigned int q) { return __uint_as_float(q & 0xffff0000u); }

// Order-preserving float<->uint bijection: max(float) == atomicMax(uint), identity = 0.
// dec(0) = NaN (no-edge marker), handled downstream by finitef -> 0.
__device__ __forceinline__ unsigned int enc(float f) {
    unsigned int u = __float_as_uint(f);
    return (u & 0x80000000u) ? ~u : (u | 0x80000000u);
}
__device__ __forceinline__ float dec(unsigned int k) {
    unsigned int u = (k & 0x80000000u) ? (k ^ 0x80000000u) : ~k;
    return __uint_as_float(u);
}

// ---------------- CSR build: atomic-free bucket sort ----------------
__global__ __launch_bounds__(256) void p1count(const int* __restrict__ dst,
                                               int* __restrict__ gmat) {
    __shared__ int h[NBUK];
    int tid = threadIdx.x;
    for (int i = tid; i < NBUK; i += 256) h[i] = 0;
    __syncthreads();
    int e0 = blockIdx.x * EPB;
    #pragma unroll
    for (int i = 0; i < 16; ++i) {
        int e = e0 + tid + i * 256;
        if (e < NE) atomicAdd(&h[dst[e] >> 7], 1);
    }
    __syncthreads();
    for (int i = tid; i < NBUK; i += 256) gmat[blockIdx.x * NBUK + i] = h[i];
}

__global__ __launch_bounds__(512) void scanA(int* __restrict__ gmat, int* __restrict__ tot) {
    __shared__ int ls[512];
    int b = blockIdx.x, tid = threadIdx.x;
    int v = (tid < NBLK1) ? gmat[tid * NBUK + b] : 0;
    ls[tid] = v;
    __syncthreads();
    for (int o = 1; o < 512; o <<= 1) {
        int t = (tid >= o) ? ls[tid - o] : 0;
        __syncthreads();
        ls[tid] += t;
        __syncthreads();
    }
    if (tid < NBLK1) gmat[tid * NBUK + b] = ls[tid] - v;   // exclusive over blocks
    if (tid == 511) tot[b] = ls[511];
}

__global__ __launch_bounds__(1024) void scanB(const int* __restrict__ tot,
        int* __restrict__ base, int* __restrict__ off,
        unsigned int* __restrict__ gmax, unsigned int* __restrict__ gneg) {
    __shared__ int ls[1024];
    int tid = threadIdx.x;
    int v = (tid < NBUK) ? tot[tid] : 0;
    ls[tid] = v;
    __syncthreads();
    for (int o = 1; o < 1024; o <<= 1) {
        int t = (tid >= o) ? ls[tid - o] : 0;
        __syncthreads();
        ls[tid] += t;
        __syncthreads();
    }
    if (tid < NBUK) base[tid] = ls[tid] - v;
    if (tid == 1023) { base[NBUK] = ls[1023]; off[NN] = NE; }
    for (int i = tid; i < NG * 64; i += 1024) { gmax[i] = 0u; gneg[i] = 0u; }
}

__global__ __launch_bounds__(256) void p1scatter(const int* __restrict__ src,
        const int* __restrict__ dst, const int* __restrict__ gmat,
        const int* __restrict__ base, int2* __restrict__ tmp) {
    __shared__ int cur[NBUK];
    int tid = threadIdx.x;
    for (int i = tid; i < NBUK; i += 256) cur[i] = base[i] + gmat[blockIdx.x * NBUK + i];
    __syncthreads();
    int e0 = blockIdx.x * EPB;
    #pragma unroll
    for (int i = 0; i < 16; ++i) {
        int e = e0 + tid + i * 256;
        if (e < NE) {
            int d = dst[e];
            int p = atomicAdd(&cur[d >> 7], 1);
            tmp[p] = make_int2(src[e], d);
        }
    }
}

__global__ __launch_bounds__(256) void p2sort(const int2* __restrict__ tmp,
        const int* __restrict__ base, int2* __restrict__ sedge, int* __restrict__ off) {
    __shared__ int2 earr[CAP2];
    __shared__ int nh[128], np[128], ncur[128];
    int b = blockIdx.x, tid = threadIdx.x;
    int bs = base[b], be = base[b + 1];
    int cnt = min(be - bs, CAP2);
    int nb0 = b << 7;
    if (tid < 128) nh[tid] = 0;
    __syncthreads();
    for (int i = tid; i < cnt; i += 256) {
        int2 ed = tmp[bs + i];
        earr[i] = ed;
        atomicAdd(&nh[ed.y - nb0], 1);
    }
    __syncthreads();
    if (tid < 128) np[tid] = nh[tid];
    __syncthreads();
    for (int o = 1; o < 128; o <<= 1) {
        int t = 0;
        if (tid < 128 && tid >= o) t = np[tid - o];
        __syncthreads();
        if (tid < 128) np[tid] += t;
        __syncthreads();
    }
    if (tid < 128) {
        int ex = np[tid] - nh[tid];
        ncur[tid] = ex;
        int n = nb0 + tid;
        if (n < NN) off[n] = bs + ex;
    }
    __syncthreads();
    for (int i = tid; i < cnt; i += 256) {
        int2 ed = earr[i];
        int p = atomicAdd(&ncur[ed.y - nb0], 1);
        sedge[bs + p] = ed;
    }
}

// ---------------- layer A node tables: P = pos@(W1h+W1t)+b1, Q = pos@W1t (bf16) ----------------
__global__ __launch_bounds__(256) void uA_kernel(const float* __restrict__ pos,
        const float* __restrict__ W1, const float* __restrict__ b1,
        unsigned short* __restrict__ PA, unsigned short* __restrict__ QA) {
    __shared__ float sWp[96], sWq[96], sb[32];
    if (threadIdx.x < 96) {
        float wt = W1[96 + threadIdx.x];
        sWq[threadIdx.x] = wt;
        sWp[threadIdx.x] = W1[threadIdx.x] + wt;
    }
    if (threadIdx.x < 32) sb[threadIdx.x] = b1[threadIdx.x];
    __syncthreads();
    int n = blockIdx.x * 256 + threadIdx.x;
    if (n >= NN) return;
    float p0 = pos[n * 3 + 0], p1 = pos[n * 3 + 1], p2 = pos[n * 3 + 2];
    float P[32], Q[32];
    #pragma unroll
    for (int c = 0; c < 32; ++c) {
        P[c] = fmaf(p2, sWp[64 + c], fmaf(p1, sWp[32 + c], fmaf(p0, sWp[c], sb[c])));
        Q[c] = fmaf(p2, sWq[64 + c], fmaf(p1, sWq[32 + c], p0 * sWq[c]));
    }
    uint4* po = (uint4*)(PA + (size_t)n * 32);
    uint4* qo = (uint4*)(QA + (size_t)n * 32);
    #pragma unroll
    for (int q = 0; q < 4; ++q) {
        po[q] = make_uint4(cvtpk(P[8*q],P[8*q+1]), cvtpk(P[8*q+2],P[8*q+3]),
                           cvtpk(P[8*q+4],P[8*q+5]), cvtpk(P[8*q+6],P[8*q+7]));
        qo[q] = make_uint4(cvtpk(Q[8*q],Q[8*q+1]), cvtpk(Q[8*q+2],Q[8*q+3]),
                           cvtpk(Q[8*q+4],Q[8*q+5]), cvtpk(Q[8*q+6],Q[8*q+7]));
    }
}

// ---------------- layer B node tables (BN+ReLU fused in; accA is encoded uints) ----------------
__global__ __launch_bounds__(256) void uB_kernel(const unsigned int* __restrict__ accA,
        const float* __restrict__ ssA, const float* __restrict__ pos,
        const float* __restrict__ W1, const float* __restrict__ b1,
        unsigned short* __restrict__ PB, unsigned short* __restrict__ QB) {
    __shared__ float sW[32 * 64];
    __shared__ float sWt[3 * 64];
    __shared__ float sb[64];
    for (int i = threadIdx.x; i < 32 * 64; i += 256) sW[i] = W1[i];
    if (threadIdx.x < 192) sWt[threadIdx.x] = W1[32 * 64 + threadIdx.x];
    if (threadIdx.x < 64) sb[threadIdx.x] = b1[threadIdx.x];
    __syncthreads();
    int n = blockIdx.x * 256 + threadIdx.x;
    if (n >= NN) return;
    float h[32];
    const uint4* a4 = (const uint4*)(accA + (size_t)n * 32);
    #pragma unroll
    for (int q = 0; q < 8; ++q) {
        uint4 v = a4[q];
        unsigned int vv[4] = {v.x, v.y, v.z, v.w};
        #pragma unroll
        for (int r = 0; r < 4; ++r) {
            int c = 4 * q + r;
            float x = dec(vv[r]);
            x = finitef(x) ? x : 0.f;
            h[c] = fmaxf(fmaf(x, ssA[c], ssA[32 + c]), 0.f);
        }
    }
    float p0 = pos[n * 3 + 0], p1 = pos[n * 3 + 1], p2 = pos[n * 3 + 2];
    float Q[64], P[64];
    #pragma unroll
    for (int c = 0; c < 64; ++c) {
        Q[c] = fmaf(p2, sWt[128 + c], fmaf(p1, sWt[64 + c], p0 * sWt[c]));
        P[c] = Q[c] + sb[c];
    }
    #pragma unroll
    for (int k = 0; k < 32; ++k) {
        float x = h[k];
        #pragma unroll
        for (int c = 0; c < 64; ++c) P[c] = fmaf(x, sW[k * 64 + c], P[c]);
    }
    uint4* po = (uint4*)(PB + (size_t)n * 64);
    uint4* qo = (uint4*)(QB + (size_t)n * 64);
    #pragma unroll
    for (int q = 0; q < 8; ++q) {
        po[q] = make_uint4(cvtpk(P[8*q],P[8*q+1]), cvtpk(P[8*q+2],P[8*q+3]),
                           cvtpk(P[8*q+4],P[8*q+5]), cvtpk(P[8*q+6],P[8*q+7]));
        qo[q] = make_uint4(cvtpk(Q[8*q],Q[8*q+1]), cvtpk(Q[8*q+2],Q[8*q+3]),
                           cvtpk(Q[8*q+4],Q[8*q+5]), cvtpk(Q[8*q+6],Q[8*q+7]));
    }
}

// ---------------- Layer A edges: MFMA + register quad-max + LDS-atomic seg-max ----------------
__global__ __launch_bounds__(256, 4) void edgeA(
        const unsigned short* __restrict__ PA, const unsigned short* __restrict__ QA,
        const int2* __restrict__ sedge, const int* __restrict__ off,
        const float* __restrict__ W2, const float* __restrict__ b2,
        unsigned int* __restrict__ accA) {
    __shared__ __align__(16) short w2f[2 * 64 * 8];
    __shared__ int2   sed[256];
    __shared__ uchar4 srow4[64];
    __shared__ int    slist[256];
    __shared__ unsigned int nm[64 * 32];
    __shared__ int    wsum[4];

    const int tid = threadIdx.x;
    const int b0  = blockIdx.x * 256;
    const int lane = tid & 63, wv = tid >> 6;
    const int kg = (lane >> 4);
    unsigned char* srow = (unsigned char*)srow4;

    #pragma unroll
    for (int ii = 0; ii < 4; ++ii) {
        int i = tid + ii * 256;
        int j = i & 7, ln = (i >> 3) & 63, t = (i >> 9) & 1;
        int k = ((ln >> 4) & 3) * 8 + j, col = (ln & 15) + 16 * t;
        w2f[i] = (short)f2bf(W2[k * 32 + col]);
    }
    sed[tid] = sedge[b0 + tid];
    __syncthreads();

    int d0 = sed[tid].y;
    bool flag = (tid == 0) || (sed[tid - 1].y != d0);
    unsigned long long mb = __ballot(flag);
    if (lane == 0) wsum[wv] = __popcll(mb);
    int incl = __popcll(mb & ((~0ull) >> (63 - lane)));
    __syncthreads();
    int w0 = wsum[0], w1 = wsum[1], w2s = wsum[2], w3 = wsum[3];
    int pre = (wv > 0 ? w0 : 0) + (wv > 1 ? w1 : 0) + (wv > 2 ? w2s : 0);
    int nseg = w0 + w1 + w2s + w3;
    int seg = pre + incl - 1;
    srow[tid] = (unsigned char)seg;
    if (flag) {
        int o0 = off[d0], o1 = off[d0 + 1];
        int interior = (o0 >= b0) && (o1 <= b0 + 256);
        slist[seg] = d0 | (interior ? (int)0x80000000 : 0);
    }
    int zc = min(nseg, 64) * 32;
    for (int i = tid; i < zc; i += 256) nm[i] = 0;
    __syncthreads();

    float b2v[2];
    #pragma unroll
    for (int t = 0; t < 2; ++t) b2v[t] = b2[(lane & 15) + 16 * t];

    AFrag af[4];
    #pragma unroll
    for (int g = 0; g < 4; ++g) {
        int E = wv * 64 + g * 16 + (lane & 15);
        int s = sed[E].x, dd = sed[E].y;
        uint4 Pq = *(const uint4*)&PA[(size_t)s * 32 + kg * 8];
        uint4 Qq = *(const uint4*)&QA[(size_t)dd * 32 + kg * 8];
        unsigned int pu[4] = {Pq.x, Pq.y, Pq.z, Pq.w};
        unsigned int qu[4] = {Qq.x, Qq.y, Qq.z, Qq.w};
        unsigned int outw[4];
        #pragma unroll
        for (int p = 0; p < 4; ++p) {
            float vlo = fmaxf(bflo(pu[p]) - bflo(qu[p]), 0.f);
            float vhi = fmaxf(bfhi(pu[p]) - bfhi(qu[p]), 0.f);
            outw[p] = cvtpk(vlo, vhi);
        }
        af[g].u = make_uint4(outw[0], outw[1], outw[2], outw[3]);
    }

    #pragma unroll
    for (int t = 0; t < 2; ++t) {
        bf16x8 bfr = *(const bf16x8*)&w2f[(t * 64 + lane) * 8];
        f32x4 acc[4];
        #pragma unroll
        for (int g = 0; g < 4; ++g) {
            f32x4 c = {b2v[t], b2v[t], b2v[t], b2v[t]};
            acc[g] = __builtin_amdgcn_mfma_f32_16x16x32_bf16(af[g].v, bfr, c, 0, 0, 0);
        }
        int ch = t * 16 + (lane & 15);
        #pragma unroll
        for (int g = 0; g < 4; ++g) {
            int eb = wv * 64 + g * 16 + kg * 4;
            uchar4 s4 = srow4[eb >> 2];
            unsigned char ss[4] = {s4.x, s4.y, s4.z, s4.w};
            if (ss[0] == ss[3]) {
                float m = fmaxf(fmaxf(acc[g][0], acc[g][1]), fmaxf(acc[g][2], acc[g][3]));
                unsigned int k = enc(m);
                if (ss[0] < 64) atomicMax(&nm[(int)ss[0] * 32 + ch], k);
                else atomicMax(&accA[(size_t)(slist[ss[0]] & 0x7fffffff) * 32 + ch], k);
            } else {
                #pragma unroll
                for (int r = 0; r < 4; ++r) {
                    unsigned int k = enc(acc[g][r]);
                    if (ss[r] < 64) atomicMax(&nm[(int)ss[r] * 32 + ch], k);
                    else atomicMax(&accA[(size_t)(slist[ss[r]] & 0x7fffffff) * 32 + ch], k);
                }
            }
        }
    }

    __syncthreads();
    int tot = min(nseg, 64) * 32;
    for (int i = tid; i < tot; i += 256) {
        int si = i >> 5, c = i & 31;
        unsigned int k = nm[i];
        int nd = slist[si];
        unsigned int* addr = &accA[(size_t)(nd & 0x7fffffff) * 32 + c];
        if (nd < 0) *addr = k;          // interior: exclusive owner, plain store
        else atomicMax(addr, k);        // boundary: merge across blocks
    }
}

// ---------------- Layer B edges: same structure, 64 channels, K=64 ----------------
__global__ __launch_bounds__(256, 4) void edgeB(
        const unsigned short* __restrict__ PB, const unsigned short* __restrict__ QB,
        const int2* __restrict__ sedge, const int* __restrict__ off,
        const float* __restrict__ W2, const float* __restrict__ b2,
        unsigned int* __restrict__ accB) {
    __shared__ __align__(16) short w2f[2 * 4 * 64 * 8];
    __shared__ int2   sed[256];
    __shared__ uchar4 srow4[64];
    __shared__ int    slist[256];
    __shared__ unsigned int nm[64 * 64];
    __shared__ int    wsum[4];

    const int tid = threadIdx.x;
    const int b0  = blockIdx.x * 256;
    const int lane = tid & 63, wv = tid >> 6;
    const int kg = (lane >> 4);
    unsigned char* srow = (unsigned char*)srow4;

    #pragma unroll
    for (int ii = 0; ii < 16; ++ii) {
        int i = tid + ii * 256;
        int j = i & 7, ln = (i >> 3) & 63, t = (i >> 9) & 3, ks = (i >> 11) & 1;
        int k = ks * 32 + ((ln >> 4) & 3) * 8 + j, col = (ln & 15) + 16 * t;
        w2f[i] = (short)f2bf(W2[k * 64 + col]);
    }
    sed[tid] = sedge[b0 + tid];
    __syncthreads();

    int d0 = sed[tid].y;
    bool flag = (tid == 0) || (sed[tid - 1].y != d0);
    unsigned long long mb = __ballot(flag);
    if (lane == 0) wsum[wv] = __popcll(mb);
    int incl = __popcll(mb & ((~0ull) >> (63 - lane)));
    __syncthreads();
    int w0 = wsum[0], w1 = wsum[1], w2s = wsum[2], w3 = wsum[3];
    int pre = (wv > 0 ? w0 : 0) + (wv > 1 ? w1 : 0) + (wv > 2 ? w2s : 0);
    int nseg = w0 + w1 + w2s + w3;
    int seg = pre + incl - 1;
    srow[tid] = (unsigned char)seg;
    if (flag) {
        int o0 = off[d0], o1 = off[d0 + 1];
        int interior = (o0 >= b0) && (o1 <= b0 + 256);
        slist[seg] = d0 | (interior ? (int)0x80000000 : 0);
    }
    int zc = min(nseg, 64) * 64;
    for (int i = tid; i < zc; i += 256) nm[i] = 0;
    __syncthreads();

    float b2v[4];
    #pragma unroll
    for (int t = 0; t < 4; ++t) b2v[t] = b2[(lane & 15) + 16 * t];

    AFrag af[4][2];
    #pragma unroll
    for (int g = 0; g < 4; ++g) {
        int E = wv * 64 + g * 16 + (lane & 15);
        int s = sed[E].x, dd = sed[E].y;
        #pragma unroll
        for (int ks = 0; ks < 2; ++ks) {
            uint4 Pq = *(const uint4*)&PB[(size_t)s * 64 + ks * 32 + kg * 8];
            uint4 Qq = *(const uint4*)&QB[(size_t)dd * 64 + ks * 32 + kg * 8];
            unsigned int pu[4] = {Pq.x, Pq.y, Pq.z, Pq.w};
            unsigned int qu[4] = {Qq.x, Qq.y, Qq.z, Qq.w};
            unsigned int outw[4];
            #pragma unroll
            for (int p = 0; p < 4; ++p) {
                float vlo = fmaxf(bflo(pu[p]) - bflo(qu[p]), 0.f);
                float vhi = fmaxf(bfhi(pu[p]) - bfhi(qu[p]), 0.f);
                outw[p] = cvtpk(vlo, vhi);
            }
            af[g][ks].u = make_uint4(outw[0], outw[1], outw[2], outw[3]);
        }
    }

    #pragma unroll
    for (int t = 0; t < 4; ++t) {
        bf16x8 bf0 = *(const bf16x8*)&w2f[((0 * 4 + t) * 64 + lane) * 8];
        bf16x8 bf1 = *(const bf16x8*)&w2f[((1 * 4 + t) * 64 + lane) * 8];
        f32x4 acc[4];
        #pragma unroll
        for (int g = 0; g < 4; ++g) {
            f32x4 c = {b2v[t], b2v[t], b2v[t], b2v[t]};
            c = __builtin_amdgcn_mfma_f32_16x16x32_bf16(af[g][0].v, bf0, c, 0, 0, 0);
            acc[g] = __builtin_amdgcn_mfma_f32_16x16x32_bf16(af[g][1].v, bf1, c, 0, 0, 0);
        }
        int ch = t * 16 + (lane & 15);
        #pragma unroll
        for (int g = 0; g < 4; ++g) {
            int eb = wv * 64 + g * 16 + kg * 4;
            uchar4 s4 = srow4[eb >> 2];
            unsigned char ss[4] = {s4.x, s4.y, s4.z, s4.w};
            if (ss[0] == ss[3]) {
                float m = fmaxf(fmaxf(acc[g][0], acc[g][1]), fmaxf(acc[g][2], acc[g][3]));
                unsigned int k = enc(m);
                if (ss[0] < 64) atomicMax(&nm[(int)ss[0] * 64 + ch], k);
                else atomicMax(&accB[(size_t)(slist[ss[0]] & 0x7fffffff) * 64 + ch], k);
            } else {
                #pragma unroll
                for (int r = 0; r < 4; ++r) {
                    unsigned int k = enc(acc[g][r]);
                    if (ss[r] < 64) atomicMax(&nm[(int)ss[r] * 64 + ch], k);
                    else atomicMax(&accB[(size_t)(slist[ss[r]] & 0x7fffffff) * 64 + ch], k);
                }
            }
        }
    }

    __syncthreads();
    int tot = min(nseg, 64) * 64;
    for (int i = tid; i < tot; i += 256) {
        int si = i >> 6, c = i & 63;
        unsigned int k = nm[i];
        int nd = slist[si];
        unsigned int* addr = &accB[(size_t)(nd & 0x7fffffff) * 64 + c];
        if (nd < 0) *addr = k;
        else atomicMax(addr, k);
    }
}

// ---------------- BatchNorm stats layer A (reads encoded accA) ----------------
template <int C>
__global__ __launch_bounds__(256) void bn_stats(const unsigned int* __restrict__ acc,
                                                float* __restrict__ partials) {
    const int total = NN * C;
    int tid = blockIdx.x * 256 + threadIdx.x;
    const int stride = gridDim.x * 256;
    float s = 0.f, q = 0.f;
    for (int i = tid; i < total; i += stride) {
        float v = dec(acc[i]);
        v = finitef(v) ? v : 0.f;
        s += v;
        q = fmaf(v, v, q);
    }
    __shared__ float ls[256], lq[256];
    ls[threadIdx.x] = s; lq[threadIdx.x] = q;
    __syncthreads();
    #pragma unroll
    for (int o = 128; o >= C; o >>= 1) {
        if (threadIdx.x < o) {
            ls[threadIdx.x] += ls[threadIdx.x + o];
            lq[threadIdx.x] += lq[threadIdx.x + o];
        }
        __syncthreads();
    }
    if (threadIdx.x < C) {
        partials[blockIdx.x * 2 * C + threadIdx.x]     = ls[threadIdx.x];
        partials[blockIdx.x * 2 * C + C + threadIdx.x] = lq[threadIdx.x];
    }
}

// ---------------- parallel final BN reduction: 1024 threads, chunked + tree ----------------
template <int C>
__global__ __launch_bounds__(1024) void bn_final(const float* __restrict__ partials, int nblocks,
                         const float* __restrict__ gamma, const float* __restrict__ beta,
                         float* __restrict__ ss) {
    __shared__ float lsum[1024], lsq[1024];
    const int NCH = 1024 / C;                 // chunks
    int tid = threadIdx.x;
    int c = tid & (C - 1);
    int chunk = tid / C;                      // 0..NCH-1
    float s = 0.f, q = 0.f;
    for (int b = chunk; b < nblocks; b += NCH) {
        s += partials[b * 2 * C + c];
        q += partials[b * 2 * C + C + c];
    }
    // layout [chunk][c] so tree over chunks keeps c in low bits
    lsum[chunk * C + c] = s; lsq[chunk * C + c] = q;
    __syncthreads();
    #pragma unroll
    for (int o = 512; o >= C; o >>= 1) {
        if (tid < o && o >= C) {
            lsum[tid] += lsum[tid + o];
            lsq[tid]  += lsq[tid + o];
        }
        __syncthreads();
    }
    if (tid < C) {
        float mu  = lsum[tid] / (float)NN;
        float var = fmaxf(lsq[tid] / (float)NN - mu * mu, 0.f);
        float inv = rsqrtf(var + 1e-5f);
        float sc  = gamma[tid] * inv;
        ss[tid]     = sc;
        ss[C + tid] = fmaf(-mu, sc, beta[tid]);
    }
}

// ---------------- fused BN-stats(64) + graph raw max/-min pool (encoded in/out) ----------------
__global__ __launch_bounds__(256) void stats_pool(const unsigned int* __restrict__ X,
        const int* __restrict__ batch, float* __restrict__ partials,
        unsigned int* __restrict__ gmax, unsigned int* __restrict__ gneg) {
    int tid = threadIdx.x;
    int c = tid & 63, sub = tid >> 6;
    int base0 = blockIdx.x * 256;
    float s = 0.f, q = 0.f;
    float rmax = 0.f, rneg = 0.f; int curg = -1;
    for (int nn = sub; nn < 256; nn += 4) {
        int n = base0 + nn;
        if (n >= NN) break;
        float v = dec(X[(size_t)n * 64 + c]);
        v = finitef(v) ? v : 0.f;
        s += v; q = fmaf(v, v, q);
        int g = batch[n];
        if (g != curg) {
            if (curg >= 0) {
                atomicMax(&gmax[curg * 64 + c], enc(rmax));
                atomicMax(&gneg[curg * 64 + c], enc(rneg));
            }
            curg = g; rmax = v; rneg = -v;
        } else {
            rmax = fmaxf(rmax, v); rneg = fmaxf(rneg, -v);
        }
    }
    if (curg >= 0) {
        atomicMax(&gmax[curg * 64 + c], enc(rmax));
        atomicMax(&gneg[curg * 64 + c], enc(rneg));
    }
    __shared__ float ls[256], lq[256];
    ls[tid] = s; lq[tid] = q;
    __syncthreads();
    if (tid < 128) { ls[tid] += ls[tid + 128]; lq[tid] += lq[tid + 128]; }
    __syncthreads();
    if (tid < 64) {
        ls[tid] += ls[tid + 64]; lq[tid] += lq[tid + 64];
        partials[blockIdx.x * 128 + tid]      = ls[tid];
        partials[blockIdx.x * 128 + 64 + tid] = lq[tid];
    }
}

// ---------------- final: BN affine+relu on pooled extrema, then 64x64x2 GEMM ----------------
__global__ void final_gemm(const unsigned int* __restrict__ gmax,
                           const unsigned int* __restrict__ gneg,
                           const float* __restrict__ ss, const float* __restrict__ Wc,
                           const float* __restrict__ bc, float* __restrict__ out) {
    int t = threadIdx.x;
    if (t >= NG * 2) return;
    int g = t >> 1, o = t & 1;
    float s = bc[o];
    for (int k = 0; k < 64; ++k) {
        float sc = ss[k], sh = ss[64 + k];
        float xm = dec(gmax[g * 64 + k]), xn = dec(gneg[g * 64 + k]);
        float x = (sc >= 0.f) ? xm : -xn;
        float v = finitef(x) ? fmaxf(fmaf(sc, x, sh), 0.f) : 0.f;   // empty graph -> 0
        s = fmaf(v, Wc[k * 2 + o], s);
    }
    out[t] = s;
}

extern "C" void kernel_launch(void* const* d_in, const int* in_sizes, int n_in,
                              void* d_out, int out_size, void* d_ws, size_t ws_size,
                              hipStream_t stream) {
    const float* pos   = (const float*)d_in[0];
    const int*   ei    = (const int*)d_in[1];
    const int*   batch = (const int*)d_in[2];
    const float* W1a = (const float*)d_in[3];
    const float* b1a = (const float*)d_in[4];
    const float* W2a = (const float*)d_in[5];
    const float* b2a = (const float*)d_in[6];
    const float* g1  = (const float*)d_in[7];
    const float* be1 = (const float*)d_in[8];
    const float* W1b = (const float*)d_in[9];
    const float* b1b = (const float*)d_in[10];
    const float* W2b = (const float*)d_in[11];
    const float* b2b = (const float*)d_in[12];
    const float* g2  = (const float*)d_in[13];
    const float* be2 = (const float*)d_in[14];
    const float* Wc  = (const float*)d_in[15];
    const float* bc  = (const float*)d_in[16];
    const int* srcp = ei;
    const int* dstp = ei + NE;

    char* base_p = (char*)d_ws;
    size_t ofs = 0;
    auto alloc = [&](size_t bytes) { char* p = base_p + ofs; ofs = (ofs + bytes + 255) & ~(size_t)255; return p; };
    int*   gmat  = (int*)alloc((size_t)NBLK1 * NBUK * 4);
    int*   tot   = (int*)alloc(NBUK * 4);
    int*   bbase = (int*)alloc((NBUK + 1) * 4);
    int*   off   = (int*)alloc((size_t)(NN + 1) * 4);
    int2*  sedge = (int2*)alloc((size_t)NE * 8);
    int2*  stmp  = (int2*)alloc((size_t)NE * 8);                     // dead after p2sort
    unsigned short* PA = (unsigned short*)alloc((size_t)NN * 32 * 2);
    unsigned short* QA = (unsigned short*)alloc((size_t)NN * 32 * 2);
    unsigned short* PB = PA;                                          // spans PA+QA
    unsigned short* QB = (unsigned short*)stmp;                       // aliases dead stmp
    unsigned int* X   = (unsigned int*)alloc((size_t)NN * 64 * 4);   // encoded accA then accB
    float* partA = (float*)alloc(256 * 64 * 4);
    float* partB = (float*)alloc((size_t)NBLK1 * 128 * 4);
    float* ssA   = (float*)alloc(64 * 4);
    float* ssB   = (float*)alloc(128 * 4);
    unsigned int* gmax = (unsigned int*)alloc(NG * 64 * 4);
    unsigned int* gneg = (unsigned int*)alloc(NG * 64 * 4);

    const int EB = NE / 256;   // 6250, exact

    hipMemsetAsync(X, 0x00, (size_t)NN * 32 * 4, stream);   // accA identity (enc: 0 = -inf)

    // CSR build (atomic-free bucket sort); also inits gmax/gneg and off[NN]
    p1count<<<NBLK1, 256, 0, stream>>>(dstp, gmat);
    scanA<<<NBUK, 512, 0, stream>>>(gmat, tot);
    scanB<<<1, 1024, 0, stream>>>(tot, bbase, off, gmax, gneg);
    p1scatter<<<NBLK1, 256, 0, stream>>>(srcp, dstp, gmat, bbase, stmp);
    p2sort<<<NBUK, 256, 0, stream>>>(stmp, bbase, sedge, off);

    // Layer A
    uA_kernel<<<(NN + 255) / 256, 256, 0, stream>>>(pos, W1a, b1a, PA, QA);
    edgeA<<<EB, 256, 0, stream>>>(PA, QA, sedge, off, W2a, b2a, X);
    bn_stats<32><<<256, 256, 0, stream>>>(X, partA);
    bn_final<32><<<1, 1024, 0, stream>>>(partA, 256, g1, be1, ssA);

    // Layer B
    uB_kernel<<<(NN + 255) / 256, 256, 0, stream>>>(X, ssA, pos, W1b, b1b, PB, QB);
    hipMemsetAsync(X, 0x00, (size_t)NN * 64 * 4, stream);   // accB identity
    edgeB<<<EB, 256, 0, stream>>>(PB, QB, sedge, off, W2b, b2b, X);
    stats_pool<<<(NN + 255) / 256, 256, 0, stream>>>(X, batch, partB, gmax, gneg);
    bn_final<64><<<1, 1024, 0, stream>>>(partB, NBLK1, g2, be2, ssB);
    final_gemm<<<1, 128, 0, stream>>>(gmax, gneg, ssB, Wc, bc, (float*)d_out);
}

// Round 9
// 204.952 us; speedup vs baseline: 31.2570x; 1.2816x over previous
//
#include <hip/hip_runtime.h>

#define NN 100000
#define NE 1600000
#define NG 64
#define BSZ 131           // nodes per bucket
#define NBUK 764          // ceil(NN/BSZ)  -> <= 768 = 256 CU x 3 blocks (one resident round)
#define NMR 132           // padded LDS rows per bucket
#define NBLK1 391         // ceil(NE/4096)
#define EPB 4096          // edges per pass-1 block

typedef __attribute__((ext_vector_type(8))) short bf16x8;
typedef __attribute__((ext_vector_type(4))) float f32x4;

union AFrag { bf16x8 v; uint4 u; };

__device__ __forceinline__ bool finitef(float v) {
    return (__float_as_uint(v) & 0x7F800000u) != 0x7F800000u;
}
__device__ __forceinline__ unsigned short f2bf(float f) {   // RNE, cold paths only
    unsigned int u = __float_as_uint(f);
    u += 0x7fffu + ((u >> 16) & 1u);
    return (unsigned short)(u >> 16);
}
__device__ __forceinline__ unsigned int cvtpk(float lo, float hi) {
    unsigned int r;
    asm("v_cvt_pk_bf16_f32 %0, %1, %2" : "=v"(r) : "v"(lo), "v"(hi));
    return r;
}
__device__ __forceinline__ float bflo(unsigned int q) { return __uint_as_float(q << 16); }
__device__ __forceinline__ float bfhi(unsigned int q) { return __uint_as_float(q & 0xffff0000u); }

// Order-preserving float<->uint bijection: max(float) == atomicMax(uint), identity = 0.
// dec(0) = NaN (no-edge marker), handled downstream by finitef -> 0.
__device__ __forceinline__ unsigned int enc(float f) {
    unsigned int u = __float_as_uint(f);
    return (u & 0x80000000u) ? ~u : (u | 0x80000000u);
}
__device__ __forceinline__ float dec(unsigned int k) {
    unsigned int u = (k & 0x80000000u) ? (k ^ 0x80000000u) : ~k;
    return __uint_as_float(u);
}

// ---------------- bucket partition (atomic-free 2-level) ----------------
__global__ __launch_bounds__(256) void p1count(const int* __restrict__ dst,
                                               int* __restrict__ gmat) {
    __shared__ int h[NBUK];
    int tid = threadIdx.x;
    for (int i = tid; i < NBUK; i += 256) h[i] = 0;
    __syncthreads();
    int e0 = blockIdx.x * EPB;
    #pragma unroll
    for (int i = 0; i < 16; ++i) {
        int e = e0 + tid + i * 256;
        if (e < NE) atomicAdd(&h[dst[e] / BSZ], 1);
    }
    __syncthreads();
    for (int i = tid; i < NBUK; i += 256) gmat[blockIdx.x * NBUK + i] = h[i];
}

__global__ __launch_bounds__(512) void scanA(int* __restrict__ gmat, int* __restrict__ tot) {
    __shared__ int ls[512];
    int b = blockIdx.x, tid = threadIdx.x;
    int v = (tid < NBLK1) ? gmat[tid * NBUK + b] : 0;
    ls[tid] = v;
    __syncthreads();
    for (int o = 1; o < 512; o <<= 1) {
        int t = (tid >= o) ? ls[tid - o] : 0;
        __syncthreads();
        ls[tid] += t;
        __syncthreads();
    }
    if (tid < NBLK1) gmat[tid * NBUK + b] = ls[tid] - v;   // exclusive over blocks
    if (tid == 511) tot[b] = ls[511];
}

__global__ __launch_bounds__(1024) void scanB(const int* __restrict__ tot,
        int* __restrict__ base,
        unsigned int* __restrict__ gmax, unsigned int* __restrict__ gneg) {
    __shared__ int ls[1024];
    int tid = threadIdx.x;
    int v = (tid < NBUK) ? tot[tid] : 0;
    ls[tid] = v;
    __syncthreads();
    for (int o = 1; o < 1024; o <<= 1) {
        int t = (tid >= o) ? ls[tid - o] : 0;
        __syncthreads();
        ls[tid] += t;
        __syncthreads();
    }
    if (tid < NBUK) base[tid] = ls[tid] - v;
    if (tid == 1023) base[NBUK] = ls[1023];
    for (int i = tid; i < NG * 64; i += 1024) { gmax[i] = 0u; gneg[i] = 0u; }
}

__global__ __launch_bounds__(256) void p1scatter(const int* __restrict__ src,
        const int* __restrict__ dst, const int* __restrict__ gmat,
        const int* __restrict__ base, int2* __restrict__ sedge) {
    __shared__ int cur[NBUK];
    int tid = threadIdx.x;
    for (int i = tid; i < NBUK; i += 256) cur[i] = base[i] + gmat[blockIdx.x * NBUK + i];
    __syncthreads();
    int e0 = blockIdx.x * EPB;
    #pragma unroll
    for (int i = 0; i < 16; ++i) {
        int e = e0 + tid + i * 256;
        if (e < NE) {
            int d = dst[e];
            int p = atomicAdd(&cur[d / BSZ], 1);
            sedge[p] = make_int2(src[e], d);
        }
    }
}

// ---------------- layer A node tables: P = pos@(W1h+W1t)+b1, Q = pos@W1t (bf16) ----------------
__global__ __launch_bounds__(256) void uA_kernel(const float* __restrict__ pos,
        const float* __restrict__ W1, const float* __restrict__ b1,
        unsigned short* __restrict__ PA, unsigned short* __restrict__ QA) {
    __shared__ float sWp[96], sWq[96], sb[32];
    if (threadIdx.x < 96) {
        float wt = W1[96 + threadIdx.x];
        sWq[threadIdx.x] = wt;
        sWp[threadIdx.x] = W1[threadIdx.x] + wt;
    }
    if (threadIdx.x < 32) sb[threadIdx.x] = b1[threadIdx.x];
    __syncthreads();
    int n = blockIdx.x * 256 + threadIdx.x;
    if (n >= NN) return;
    float p0 = pos[n * 3 + 0], p1 = pos[n * 3 + 1], p2 = pos[n * 3 + 2];
    float P[32], Q[32];
    #pragma unroll
    for (int c = 0; c < 32; ++c) {
        P[c] = fmaf(p2, sWp[64 + c], fmaf(p1, sWp[32 + c], fmaf(p0, sWp[c], sb[c])));
        Q[c] = fmaf(p2, sWq[64 + c], fmaf(p1, sWq[32 + c], p0 * sWq[c]));
    }
    uint4* po = (uint4*)(PA + (size_t)n * 32);
    uint4* qo = (uint4*)(QA + (size_t)n * 32);
    #pragma unroll
    for (int q = 0; q < 4; ++q) {
        po[q] = make_uint4(cvtpk(P[8*q],P[8*q+1]), cvtpk(P[8*q+2],P[8*q+3]),
                           cvtpk(P[8*q+4],P[8*q+5]), cvtpk(P[8*q+6],P[8*q+7]));
        qo[q] = make_uint4(cvtpk(Q[8*q],Q[8*q+1]), cvtpk(Q[8*q+2],Q[8*q+3]),
                           cvtpk(Q[8*q+4],Q[8*q+5]), cvtpk(Q[8*q+6],Q[8*q+7]));
    }
}

// ---------------- layer B node tables (BN+ReLU fused in; accA is encoded uints) ----------------
__global__ __launch_bounds__(256) void uB_kernel(const unsigned int* __restrict__ accA,
        const float* __restrict__ ssA, const float* __restrict__ pos,
        const float* __restrict__ W1, const float* __restrict__ b1,
        unsigned short* __restrict__ PB, unsigned short* __restrict__ QB) {
    __shared__ float sW[32 * 64];
    __shared__ float sWt[3 * 64];
    __shared__ float sb[64];
    for (int i = threadIdx.x; i < 32 * 64; i += 256) sW[i] = W1[i];
    if (threadIdx.x < 192) sWt[threadIdx.x] = W1[32 * 64 + threadIdx.x];
    if (threadIdx.x < 64) sb[threadIdx.x] = b1[threadIdx.x];
    __syncthreads();
    int n = blockIdx.x * 256 + threadIdx.x;
    if (n >= NN) return;
    float h[32];
    const uint4* a4 = (const uint4*)(accA + (size_t)n * 32);
    #pragma unroll
    for (int q = 0; q < 8; ++q) {
        uint4 v = a4[q];
        unsigned int vv[4] = {v.x, v.y, v.z, v.w};
        #pragma unroll
        for (int r = 0; r < 4; ++r) {
            int c = 4 * q + r;
            float x = dec(vv[r]);
            x = finitef(x) ? x : 0.f;
            h[c] = fmaxf(fmaf(x, ssA[c], ssA[32 + c]), 0.f);
        }
    }
    float p0 = pos[n * 3 + 0], p1 = pos[n * 3 + 1], p2 = pos[n * 3 + 2];
    float Q[64], P[64];
    #pragma unroll
    for (int c = 0; c < 64; ++c) {
        Q[c] = fmaf(p2, sWt[128 + c], fmaf(p1, sWt[64 + c], p0 * sWt[c]));
        P[c] = Q[c] + sb[c];
    }
    #pragma unroll
    for (int k = 0; k < 32; ++k) {
        float x = h[k];
        #pragma unroll
        for (int c = 0; c < 64; ++c) P[c] = fmaf(x, sW[k * 64 + c], P[c]);
    }
    uint4* po = (uint4*)(PB + (size_t)n * 64);
    uint4* qo = (uint4*)(QB + (size_t)n * 64);
    #pragma unroll
    for (int q = 0; q < 8; ++q) {
        po[q] = make_uint4(cvtpk(P[8*q],P[8*q+1]), cvtpk(P[8*q+2],P[8*q+3]),
                           cvtpk(P[8*q+4],P[8*q+5]), cvtpk(P[8*q+6],P[8*q+7]));
        qo[q] = make_uint4(cvtpk(Q[8*q],Q[8*q+1]), cvtpk(Q[8*q+2],Q[8*q+3]),
                           cvtpk(Q[8*q+4],Q[8*q+5]), cvtpk(Q[8*q+6],Q[8*q+7]));
    }
}

// ---------------- Layer A edges: bucket-exclusive block; MFMA + LDS-atomic node max;
//                  flush writes accA + BN partial sums ----------------
__global__ __launch_bounds__(256, 3) void edgeA(
        const unsigned short* __restrict__ PA, const unsigned short* __restrict__ QA,
        const int2* __restrict__ sedge, const int* __restrict__ bbase,
        const float* __restrict__ W2, const float* __restrict__ b2,
        unsigned int* __restrict__ accA, float* __restrict__ partials) {
    __shared__ __align__(16) short w2f[2 * 64 * 8];
    __shared__ int2   sed[256];
    __shared__ uchar4 srow4[64];
    __shared__ unsigned int nm[NMR * 32];
    __shared__ float  psum[256], psq[256];

    const int tid = threadIdx.x;
    const int b   = blockIdx.x;
    const int nb0 = b * BSZ;
    const int lane = tid & 63, wv = tid >> 6;
    const int kg = (lane >> 4);
    unsigned char* srow = (unsigned char*)srow4;

    #pragma unroll
    for (int ii = 0; ii < 4; ++ii) {
        int i = tid + ii * 256;
        int j = i & 7, ln = (i >> 3) & 63, t = (i >> 9) & 1;
        int k = ((ln >> 4) & 3) * 8 + j, col = (ln & 15) + 16 * t;
        w2f[i] = (short)f2bf(W2[k * 32 + col]);
    }
    for (int i = tid; i < NMR * 32; i += 256) nm[i] = 0;
    __syncthreads();

    float b2v[2];
    #pragma unroll
    for (int t = 0; t < 2; ++t) b2v[t] = b2[(lane & 15) + 16 * t];

    const int bs = bbase[b], be = bbase[b + 1];
    for (int e0 = bs; e0 < be; e0 += 256) {
        // per-wave staging: wave wv owns edges e0+wv*64 .. +63 (no cross-wave access, no syncs)
        int idx = e0 + tid;
        bool ok = idx < be;
        int2 ed = ok ? sedge[idx] : make_int2(nb0, nb0);
        sed[tid] = ed;
        srow[tid] = ok ? (unsigned char)(ed.y - nb0) : (unsigned char)255;

        AFrag af[4];
        #pragma unroll
        for (int g = 0; g < 4; ++g) {
            int E = wv * 64 + g * 16 + (lane & 15);
            int s = sed[E].x, dd = sed[E].y;
            uint4 Pq = *(const uint4*)&PA[(size_t)s * 32 + kg * 8];
            uint4 Qq = *(const uint4*)&QA[(size_t)dd * 32 + kg * 8];
            unsigned int pu[4] = {Pq.x, Pq.y, Pq.z, Pq.w};
            unsigned int qu[4] = {Qq.x, Qq.y, Qq.z, Qq.w};
            unsigned int outw[4];
            #pragma unroll
            for (int p = 0; p < 4; ++p) {
                float vlo = fmaxf(bflo(pu[p]) - bflo(qu[p]), 0.f);
                float vhi = fmaxf(bfhi(pu[p]) - bfhi(qu[p]), 0.f);
                outw[p] = cvtpk(vlo, vhi);
            }
            af[g].u = make_uint4(outw[0], outw[1], outw[2], outw[3]);
        }

        #pragma unroll
        for (int t = 0; t < 2; ++t) {
            bf16x8 bfr = *(const bf16x8*)&w2f[(t * 64 + lane) * 8];
            f32x4 acc[4];
            #pragma unroll
            for (int g = 0; g < 4; ++g) {
                f32x4 c = {b2v[t], b2v[t], b2v[t], b2v[t]};
                acc[g] = __builtin_amdgcn_mfma_f32_16x16x32_bf16(af[g].v, bfr, c, 0, 0, 0);
            }
            int ch = t * 16 + (lane & 15);
            #pragma unroll
            for (int g = 0; g < 4; ++g) {
                int eb = wv * 64 + g * 16 + kg * 4;
                uchar4 s4 = srow4[eb >> 2];
                unsigned char ss[4] = {s4.x, s4.y, s4.z, s4.w};
                #pragma unroll
                for (int r = 0; r < 4; ++r)
                    if (ss[r] != 255) atomicMax(&nm[(int)ss[r] * 32 + ch], enc(acc[g][r]));
            }
        }
    }

    __syncthreads();
    // flush: write accA (exclusive owner) + BN partial sums over this bucket's nodes
    {
        int c = tid & 31, sub = tid >> 5;            // 8 row-groups
        float s = 0.f, q = 0.f;
        for (int nl = sub; nl < BSZ; nl += 8) {
            int n = nb0 + nl;
            if (n >= NN) break;
            unsigned int k = nm[nl * 32 + c];
            accA[(size_t)n * 32 + c] = k;
            float v = dec(k);
            v = finitef(v) ? v : 0.f;
            s += v; q = fmaf(v, v, q);
        }
        psum[tid] = s; psq[tid] = q;
    }
    __syncthreads();
    if (tid < 128) { psum[tid] += psum[tid + 128]; psq[tid] += psq[tid + 128]; }
    __syncthreads();
    if (tid < 64)  { psum[tid] += psum[tid + 64];  psq[tid] += psq[tid + 64]; }
    __syncthreads();
    if (tid < 32) {
        float s = psum[tid] + psum[tid + 32];
        float q = psq[tid]  + psq[tid + 32];
        partials[b * 64 + tid]      = s;
        partials[b * 64 + 32 + tid] = q;
    }
}

// ---------------- Layer B edges: bucket-exclusive; flush = BN partials + graph pool.
//                  accB never hits global memory. ----------------
__global__ __launch_bounds__(256, 3) void edgeB(
        const unsigned short* __restrict__ PB, const unsigned short* __restrict__ QB,
        const int2* __restrict__ sedge, const int* __restrict__ bbase,
        const int* __restrict__ batch,
        const float* __restrict__ W2, const float* __restrict__ b2,
        float* __restrict__ partials,
        unsigned int* __restrict__ gmax, unsigned int* __restrict__ gneg) {
    __shared__ __align__(16) short w2f[2 * 4 * 64 * 8];
    __shared__ int2   sed[256];
    __shared__ uchar4 srow4[64];
    __shared__ unsigned int nm[NMR * 64];
    __shared__ float  psum[256], psq[256];

    const int tid = threadIdx.x;
    const int b   = blockIdx.x;
    const int nb0 = b * BSZ;
    const int lane = tid & 63, wv = tid >> 6;
    const int kg = (lane >> 4);
    unsigned char* srow = (unsigned char*)srow4;

    #pragma unroll
    for (int ii = 0; ii < 16; ++ii) {
        int i = tid + ii * 256;
        int j = i & 7, ln = (i >> 3) & 63, t = (i >> 9) & 3, ks = (i >> 11) & 1;
        int k = ks * 32 + ((ln >> 4) & 3) * 8 + j, col = (ln & 15) + 16 * t;
        w2f[i] = (short)f2bf(W2[k * 64 + col]);
    }
    for (int i = tid; i < NMR * 64; i += 256) nm[i] = 0;
    __syncthreads();

    float b2v[4];
    #pragma unroll
    for (int t = 0; t < 4; ++t) b2v[t] = b2[(lane & 15) + 16 * t];

    const int bs = bbase[b], be = bbase[b + 1];
    for (int e0 = bs; e0 < be; e0 += 256) {
        int idx = e0 + tid;
        bool ok = idx < be;
        int2 ed = ok ? sedge[idx] : make_int2(nb0, nb0);
        sed[tid] = ed;
        srow[tid] = ok ? (unsigned char)(ed.y - nb0) : (unsigned char)255;

        AFrag af[4][2];
        #pragma unroll
        for (int g = 0; g < 4; ++g) {
            int E = wv * 64 + g * 16 + (lane & 15);
            int s = sed[E].x, dd = sed[E].y;
            #pragma unroll
            for (int ks = 0; ks < 2; ++ks) {
                uint4 Pq = *(const uint4*)&PB[(size_t)s * 64 + ks * 32 + kg * 8];
                uint4 Qq = *(const uint4*)&QB[(size_t)dd * 64 + ks * 32 + kg * 8];
                unsigned int pu[4] = {Pq.x, Pq.y, Pq.z, Pq.w};
                unsigned int qu[4] = {Qq.x, Qq.y, Qq.z, Qq.w};
                unsigned int outw[4];
                #pragma unroll
                for (int p = 0; p < 4; ++p) {
                    float vlo = fmaxf(bflo(pu[p]) - bflo(qu[p]), 0.f);
                    float vhi = fmaxf(bfhi(pu[p]) - bfhi(qu[p]), 0.f);
                    outw[p] = cvtpk(vlo, vhi);
                }
                af[g][ks].u = make_uint4(outw[0], outw[1], outw[2], outw[3]);
            }
        }

        #pragma unroll
        for (int t = 0; t < 4; ++t) {
            bf16x8 bf0 = *(const bf16x8*)&w2f[((0 * 4 + t) * 64 + lane) * 8];
            bf16x8 bf1 = *(const bf16x8*)&w2f[((1 * 4 + t) * 64 + lane) * 8];
            f32x4 acc[4];
            #pragma unroll
            for (int g = 0; g < 4; ++g) {
                f32x4 c = {b2v[t], b2v[t], b2v[t], b2v[t]};
                c = __builtin_amdgcn_mfma_f32_16x16x32_bf16(af[g][0].v, bf0, c, 0, 0, 0);
                acc[g] = __builtin_amdgcn_mfma_f32_16x16x32_bf16(af[g][1].v, bf1, c, 0, 0, 0);
            }
            int ch = t * 16 + (lane & 15);
            #pragma unroll
            for (int g = 0; g < 4; ++g) {
                int eb = wv * 64 + g * 16 + kg * 4;
                uchar4 s4 = srow4[eb >> 2];
                unsigned char ss[4] = {s4.x, s4.y, s4.z, s4.w};
                #pragma unroll
                for (int r = 0; r < 4; ++r)
                    if (ss[r] != 255) atomicMax(&nm[(int)ss[r] * 64 + ch], enc(acc[g][r]));
            }
        }
    }

    __syncthreads();
    // flush: BN partial sums + graph raw max/-min pool (batch sorted -> run-max)
    {
        int c = tid & 63, sub = tid >> 6;            // 4 row-groups
        float s = 0.f, q = 0.f;
        float rmax = 0.f, rneg = 0.f; int curg = -1;
        for (int nl = sub; nl < BSZ; nl += 4) {
            int n = nb0 + nl;
            if (n >= NN) break;
            float v = dec(nm[nl * 64 + c]);
            v = finitef(v) ? v : 0.f;
            s += v; q = fmaf(v, v, q);
            int g = batch[n];
            if (g != curg) {
                if (curg >= 0) {
                    atomicMax(&gmax[curg * 64 + c], enc(rmax));
                    atomicMax(&gneg[curg * 64 + c], enc(rneg));
                }
                curg = g; rmax = v; rneg = -v;
            } else {
                rmax = fmaxf(rmax, v); rneg = fmaxf(rneg, -v);
            }
        }
        if (curg >= 0) {
            atomicMax(&gmax[curg * 64 + c], enc(rmax));
            atomicMax(&gneg[curg * 64 + c], enc(rneg));
        }
        psum[tid] = s; psq[tid] = q;
    }
    __syncthreads();
    if (tid < 128) { psum[tid] += psum[tid + 128]; psq[tid] += psq[tid + 128]; }
    __syncthreads();
    if (tid < 64) {
        float s = psum[tid] + psum[tid + 64];
        float q = psq[tid]  + psq[tid + 64];
        partials[b * 128 + tid]      = s;
        partials[b * 128 + 64 + tid] = q;
    }
}

// ---------------- parallel final BN reduction: 1024 threads, chunked + tree ----------------
template <int C>
__global__ __launch_bounds__(1024) void bn_final(const float* __restrict__ partials, int nblocks,
                         const float* __restrict__ gamma, const float* __restrict__ beta,
                         float* __restrict__ ss) {
    __shared__ float lsum[1024], lsq[1024];
    const int NCH = 1024 / C;
    int tid = threadIdx.x;
    int c = tid & (C - 1);
    int chunk = tid / C;
    float s = 0.f, q = 0.f;
    for (int b = chunk; b < nblocks; b += NCH) {
        s += partials[b * 2 * C + c];
        q += partials[b * 2 * C + C + c];
    }
    lsum[chunk * C + c] = s; lsq[chunk * C + c] = q;
    __syncthreads();
    #pragma unroll
    for (int o = 512; o >= C; o >>= 1) {
        if (tid < o && o >= C) {
            lsum[tid] += lsum[tid + o];
            lsq[tid]  += lsq[tid + o];
        }
        __syncthreads();
    }
    if (tid < C) {
        float mu  = lsum[tid] / (float)NN;
        float var = fmaxf(lsq[tid] / (float)NN - mu * mu, 0.f);
        float inv = rsqrtf(var + 1e-5f);
        float sc  = gamma[tid] * inv;
        ss[tid]     = sc;
        ss[C + tid] = fmaf(-mu, sc, beta[tid]);
    }
}

// ---------------- final: BN affine+relu on pooled extrema, then 64x64x2 GEMM ----------------
__global__ void final_gemm(const unsigned int* __restrict__ gmax,
                           const unsigned int* __restrict__ gneg,
                           const float* __restrict__ ss, const float* __restrict__ Wc,
                           const float* __restrict__ bc, float* __restrict__ out) {
    int t = threadIdx.x;
    if (t >= NG * 2) return;
    int g = t >> 1, o = t & 1;
    float s = bc[o];
    for (int k = 0; k < 64; ++k) {
        float sc = ss[k], sh = ss[64 + k];
        float xm = dec(gmax[g * 64 + k]), xn = dec(gneg[g * 64 + k]);
        float x = (sc >= 0.f) ? xm : -xn;
        float v = finitef(x) ? fmaxf(fmaf(sc, x, sh), 0.f) : 0.f;   // empty graph -> 0
        s = fmaf(v, Wc[k * 2 + o], s);
    }
    out[t] = s;
}

extern "C" void kernel_launch(void* const* d_in, const int* in_sizes, int n_in,
                              void* d_out, int out_size, void* d_ws, size_t ws_size,
                              hipStream_t stream) {
    const float* pos   = (const float*)d_in[0];
    const int*   ei    = (const int*)d_in[1];
    const int*   batch = (const int*)d_in[2];
    const float* W1a = (const float*)d_in[3];
    const float* b1a = (const float*)d_in[4];
    const float* W2a = (const float*)d_in[5];
    const float* b2a = (const float*)d_in[6];
    const float* g1  = (const float*)d_in[7];
    const float* be1 = (const float*)d_in[8];
    const float* W1b = (const float*)d_in[9];
    const float* b1b = (const float*)d_in[10];
    const float* W2b = (const float*)d_in[11];
    const float* b2b = (const float*)d_in[12];
    const float* g2  = (const float*)d_in[13];
    const float* be2 = (const float*)d_in[14];
    const float* Wc  = (const float*)d_in[15];
    const float* bc  = (const float*)d_in[16];
    const int* srcp = ei;
    const int* dstp = ei + NE;

    char* base_p = (char*)d_ws;
    size_t ofs = 0;
    auto alloc = [&](size_t bytes) { char* p = base_p + ofs; ofs = (ofs + bytes + 255) & ~(size_t)255; return p; };
    int*   gmat  = (int*)alloc((size_t)NBLK1 * NBUK * 4);
    int*   tot   = (int*)alloc(NBUK * 4);
    int*   bbase = (int*)alloc((NBUK + 1) * 4);
    int2*  sedge = (int2*)alloc((size_t)NE * 8);                      // bucket-partitioned, unsorted
    unsigned short* PA = (unsigned short*)alloc((size_t)NN * 32 * 2);
    unsigned short* QA = (unsigned short*)alloc((size_t)NN * 32 * 2);
    unsigned short* PB = PA;                                           // spans PA+QA (12.8 MB); edgeA done before uB writes
    unsigned short* QB = (unsigned short*)alloc((size_t)NN * 64 * 2);
    unsigned int* accA = (unsigned int*)alloc((size_t)NN * 32 * 4);   // encoded; written by edgeA flush (full coverage, no memset)
    float* partA = (float*)alloc((size_t)NBUK * 64 * 4);
    float* partB = (float*)alloc((size_t)NBUK * 128 * 4);
    float* ssA   = (float*)alloc(64 * 4);
    float* ssB   = (float*)alloc(128 * 4);
    unsigned int* gmax = (unsigned int*)alloc(NG * 64 * 4);
    unsigned int* gneg = (unsigned int*)alloc(NG * 64 * 4);

    // bucket partition (also inits gmax/gneg)
    p1count<<<NBLK1, 256, 0, stream>>>(dstp, gmat);
    scanA<<<NBUK, 512, 0, stream>>>(gmat, tot);
    scanB<<<1, 1024, 0, stream>>>(tot, bbase, gmax, gneg);
    p1scatter<<<NBLK1, 256, 0, stream>>>(srcp, dstp, gmat, bbase, sedge);

    // Layer A (edgeA flush writes accA + BN partials)
    uA_kernel<<<(NN + 255) / 256, 256, 0, stream>>>(pos, W1a, b1a, PA, QA);
    edgeA<<<NBUK, 256, 0, stream>>>(PA, QA, sedge, bbase, W2a, b2a, accA, partA);
    bn_final<32><<<1, 1024, 0, stream>>>(partA, NBUK, g1, be1, ssA);

    // Layer B (edgeB flush computes BN partials + graph pool; accB never materialized)
    uB_kernel<<<(NN + 255) / 256, 256, 0, stream>>>(accA, ssA, pos, W1b, b1b, PB, QB);
    edgeB<<<NBUK, 256, 0, stream>>>(PB, QB, sedge, bbase, batch, W2b, b2b, partB, gmax, gneg);
    bn_final<64><<<1, 1024, 0, stream>>>(partB, NBUK, g2, be2, ssB);
    final_gemm<<<1, 128, 0, stream>>>(gmax, gneg, ssB, Wc, bc, (float*)d_out);
}